// Round 17
// baseline (241.833 us; speedup 1.0000x reference)
//
#include <hip/hip_runtime.h>
#include <hip/hip_bf16.h>
#include <math.h>

typedef float f32x4 __attribute__((ext_vector_type(4)));
typedef short s16x8 __attribute__((ext_vector_type(8)));

// ---------------- problem constants ----------------
constexpr int Tt = 4096;
constexpr int NEn = 16;
constexpr float EPSf = 1.1920929e-07f;

__device__ __forceinline__ short f2b(float f) {
    union { __hip_bfloat16 h; short s; } u;
    u.h = __float2bfloat16(f);
    return u.s;
}
__device__ __forceinline__ float b2f(short s) {
    union { float f; unsigned u; } v;
    v.u = ((unsigned)(unsigned short)s) << 16;
    return v.f;
}

// ---------------- workspace layout (float elements, 16-float aligned) ----------------
constexpr size_t alg(size_t x) { return (x + 15) & ~(size_t)15; }
// f32 buffers (region [0, OFF_R2) is reused for attention partials after build)
constexpr size_t OFF_CQKV = 0;                                   // T*416 f32 (cq 0..255 | ckv 256..415)
constexpr size_t OFF_QCR  = alg(OFF_CQKV + (size_t)Tt * 416);    // T*768 bf16 now (region sized for f32)
constexpr size_t OFF_KVB  = alg(OFF_QCR  + (size_t)Tt * 768);    // T*1024 bf16 now
constexpr size_t OFF_R2   = alg(OFF_KVB  + (size_t)Tt * 1024);   // T*512 f32
constexpr size_t OFF_TOKE = alg(OFF_R2   + (size_t)Tt * 512);    // T*4 ints
constexpr size_t OFF_TOKW = alg(OFF_TOKE + (size_t)Tt * 4);      // T*4 f32
constexpr size_t OFF_EWT  = alg(OFF_TOKW + (size_t)Tt * 4);      // 16*4096 f32
constexpr size_t OFF_ECNT = alg(OFF_EWT  + (size_t)NEn * Tt);    // ints
constexpr size_t OFF_ETOK = alg(OFF_ECNT + 64);                  // 16*4096 ints
// attention partials ALIAS dead CQKV/QCR/KVB region (dead after k_build_qkv):
constexpr size_t OFF_PO   = 0;                                   // bf16 16*2048*4*64 = 4,194,304 float-slots
constexpr size_t OFF_PL   = (size_t)16 * 2048 * 4 * 64 / 2;      // f32 131,072
// bf16 buffers (element counts halved into float units)
constexpr size_t OFF_XNB   = alg(OFF_ETOK + (size_t)NEn * Tt);       // T*512 bf16
constexpr size_t OFF_CQNB  = alg(OFF_XNB   + (size_t)Tt * 512 / 2);  // T*256 bf16
constexpr size_t OFF_CKVNB = alg(OFF_CQNB  + (size_t)Tt * 256 / 2);  // T*128 bf16
constexpr size_t OFF_QB    = alg(OFF_CKVNB + (size_t)Tt * 128 / 2);  // 16*2048*96 bf16
constexpr size_t OFF_KB    = alg(OFF_QB    + (size_t)16 * 2048 * 96 / 2);
constexpr size_t OFF_VBT   = alg(OFF_KB    + (size_t)16 * 2048 * 96 / 2); // 16*64*2048 bf16
constexpr size_t OFF_XN2B  = alg(OFF_VBT   + (size_t)16 * 64 * 2048 / 2);
constexpr size_t OFF_GACT  = alg(OFF_XN2B  + (size_t)Tt * 512 / 2);  // T*256 bf16
constexpr size_t OFF_EACT  = alg(OFF_GACT  + (size_t)Tt * 256 / 2);  // 16384*256 bf16
// transposed bf16 weights [N][K]
constexpr size_t OFF_WQKVT = alg(OFF_EACT  + (size_t)16384 * 256 / 2); // 416*512
constexpr size_t OFF_WUQT  = alg(OFF_WQKVT + (size_t)416 * 512 / 2);
constexpr size_t OFF_WUKVT = alg(OFF_WUQT  + (size_t)768 * 256 / 2);
constexpr size_t OFF_WOT   = alg(OFF_WUKVT + (size_t)1024 * 128 / 2);
constexpr size_t OFF_SHWGT = alg(OFF_WOT   + (size_t)512 * 512 / 2);
constexpr size_t OFF_SHWUT = alg(OFF_SHWGT + (size_t)256 * 512 / 2);
constexpr size_t OFF_SHWDT = alg(OFF_SHWUT + (size_t)256 * 512 / 2);
constexpr size_t OFF_RWGT  = alg(OFF_SHWDT + (size_t)512 * 256 / 2);
constexpr size_t OFF_RWUT  = alg(OFF_RWGT  + (size_t)16 * 256 * 512 / 2);
constexpr size_t OFF_RWDT  = alg(OFF_RWUT  + (size_t)16 * 256 * 512 / 2);

// ---------------- fused convert + transpose (all weights, one launch) ----------------
struct CvtTab {
    const float* src[11];
    short* dst[11];
    int K[11], N[11], end[11];
};
__global__ __launch_bounds__(256)
void k_cvt_all(CvtTab tab) {
    __shared__ float t[32][33];
    int bid = blockIdx.x;
    int i = 0;
    while (bid >= tab.end[i]) ++i;
    int tloc = bid - (i ? tab.end[i - 1] : 0);
    int K = tab.K[i], N = tab.N[i];
    int ntiles = N >> 5, perE = ntiles * (K >> 5);
    int e = tloc / perE, rem = tloc - e * perE;
    int k0 = (rem / ntiles) << 5, n0 = (rem % ntiles) << 5;
    size_t eo = (size_t)e * K * N;
    const float* src = tab.src[i];
    short* dst = tab.dst[i];
    int c = threadIdx.x & 31, r = threadIdx.x >> 5;
#pragma unroll
    for (int q = 0; q < 4; ++q)
        t[r + 8 * q][c] = src[eo + (size_t)(k0 + r + 8 * q) * N + n0 + c];
    __syncthreads();
#pragma unroll
    for (int q = 0; q < 4; ++q)
        dst[eo + (size_t)(n0 + r + 8 * q) * K + k0 + c] = f2b(t[c][r + 8 * q]);
}

// ---------------- RMSNorm f32 in -> bf16 out (also zeroes ecnt for later scatter) ---------------
__global__ void k_rms(const float* __restrict__ in, int inStride, const float* __restrict__ w,
                      short* __restrict__ outB, int outStride, int D, int* __restrict__ ecnt) {
    int row = blockIdx.x, tid = threadIdx.x;
    if (row == 0 && tid < 16) ecnt[tid] = 0;
    __shared__ float xs[512];
    __shared__ float red[256];
    const float* ip = in + (size_t)row * inStride;
    float ss = 0.f;
    for (int i = tid; i < D; i += 256) { float v = ip[i]; xs[i] = v; ss += v * v; }
    red[tid] = ss; __syncthreads();
    for (int s = 128; s > 0; s >>= 1) { if (tid < s) red[tid] += red[tid + s]; __syncthreads(); }
    float sc = rsqrtf(red[0] / (float)D + EPSf);
    for (int i = tid; i < D; i += 256) outB[(size_t)row * outStride + i] = f2b(xs[i] * sc * w[i]);
}

// ---------------- fused latent RMSNorm pair over cqkv[4096][416] ----------------
__global__ void k_rms2(const float* __restrict__ cqkv, const float* __restrict__ wq, short* __restrict__ cqnb,
                       const float* __restrict__ wkv, short* __restrict__ ckvnb) {
    int row = blockIdx.x, tid = threadIdx.x;
    __shared__ float xs[256];
    __shared__ float red[256];
    const float* ip; const float* w; short* ob; int D, outStride, r;
    if (row < Tt) { r = row;      ip = cqkv + (size_t)r * 416;       w = wq;  ob = cqnb;  D = 256; outStride = 256; }
    else          { r = row - Tt; ip = cqkv + (size_t)r * 416 + 256; w = wkv; ob = ckvnb; D = 128; outStride = 128; }
    float ss = 0.f;
    for (int i = tid; i < D; i += 256) { float v = ip[i]; xs[i] = v; ss += v * v; }
    red[tid] = ss; __syncthreads();
    for (int s = 128; s > 0; s >>= 1) { if (tid < s) red[tid] += red[tid + s]; __syncthreads(); }
    float sc = rsqrtf(red[0] / (float)D + EPSf);
    for (int i = tid; i < D; i += 256) ob[(size_t)r * outStride + i] = f2b(xs[i] * sc * w[i]);
}

// ---------------- fused post-RMSNorm + router ----------------
__global__ __launch_bounds__(256)
void k_rms_router(const float* __restrict__ r2, const float* __restrict__ wpost,
                  const float* __restrict__ wg,
                  short* __restrict__ xn2b, int4* __restrict__ toke, float4* __restrict__ tokw) {
    int t = blockIdx.x, tid = threadIdx.x;
    __shared__ float xs[512];
    __shared__ float red[256];
    __shared__ float part[16][17];
    __shared__ float sc[16];
    const float* ip = r2 + (size_t)t * 512;
    float ss = 0.f;
    for (int i = tid; i < 512; i += 256) { float v = ip[i]; xs[i] = v; ss += v * v; }
    red[tid] = ss; __syncthreads();
    for (int s = 128; s > 0; s >>= 1) { if (tid < s) red[tid] += red[tid + s]; __syncthreads(); }
    float scale = rsqrtf(red[0] / 512.f + EPSf);
    for (int i = tid; i < 512; i += 256) {
        float v = xs[i] * scale * wpost[i];
        xs[i] = v;
        xn2b[(size_t)t * 512 + i] = f2b(v);
    }
    __syncthreads();
    {
        int e = tid & 15, ch = tid >> 4;
        const float* wp = wg + (size_t)ch * 32 * 16 + e;
        float s = 0.f;
#pragma unroll 8
        for (int k = 0; k < 32; ++k) s = fmaf(xs[ch * 32 + k], wp[(size_t)k * 16], s);
        part[ch][e] = s;
    }
    __syncthreads();
    if (tid < 16) {
        float s = 0.f;
#pragma unroll
        for (int c = 0; c < 16; ++c) s += part[c][tid];
        sc[tid] = 1.f / (1.f + expf(-s));
    }
    __syncthreads();
    if (tid < 64) {
        int lane = tid, e = lane & 15;
        float scv = sc[e];
        unsigned sel = 0;
        float tw[4]; int ti[4];
#pragma unroll
        for (int kk = 0; kk < 4; ++kk) {
            float cand = ((sel >> e) & 1u) ? -1e30f : scv;
            float mx = cand;
            mx = fmaxf(mx, __shfl_xor(mx, 1));
            mx = fmaxf(mx, __shfl_xor(mx, 2));
            mx = fmaxf(mx, __shfl_xor(mx, 4));
            mx = fmaxf(mx, __shfl_xor(mx, 8));
            unsigned long long msk = __ballot(cand == mx);
            int bi = (__ffsll(msk) - 1) & 15;
            tw[kk] = mx; ti[kk] = bi;
            sel |= 1u << bi;
        }
        if (lane == 0) {
            float inv = 1.f / (tw[0] + tw[1] + tw[2] + tw[3]);
            toke[t] = make_int4(ti[0], ti[1], ti[2], ti[3]);
            tokw[t] = make_float4(tw[0] * inv, tw[1] * inv, tw[2] * inv, tw[3] * inv);
        }
    }
}

// ---------------- MFMA GEMM (64x64 tile, 8 waves): EPI 0 = f32 out, 1 = f32+residual, 2 = bf16 out
template <int EPI>
__global__ __launch_bounds__(512)
void k_mgemm(const short* __restrict__ A, const short* __restrict__ BT,
             void* __restrict__ Cv, const float* __restrict__ add, int N, int K) {
    __shared__ __align__(16) short As[64 * 64];
    __shared__ __align__(16) short Bs[64 * 64];
    int tid = threadIdx.x;
    int w = tid >> 6, l = tid & 63, g = l >> 4, li = l & 15;
    int wm = w >> 1, wn = w & 1;
    int m0 = blockIdx.y * 64, n0 = blockIdx.x * 64;
    f32x4 acc[2] = {};
    for (int k0 = 0; k0 < K; k0 += 64) {
        __syncthreads();
        {
            int row = tid >> 3, ch = tid & 7;
            *(int4*)&As[row * 64 + ((ch ^ (row & 7)) * 8)] =
                *(const int4*)(A + (size_t)(m0 + row) * K + k0 + 8 * ch);
            int4 v = {0, 0, 0, 0};
            if (n0 + row < N) v = *(const int4*)(BT + (size_t)(n0 + row) * K + k0 + 8 * ch);
            *(int4*)&Bs[row * 64 + ((ch ^ (row & 7)) * 8)] = v;
        }
        __syncthreads();
#pragma unroll
        for (int kc = 0; kc < 2; ++kc) {
            int row = wm * 16 + li;
            s16x8 af = *(const s16x8*)&As[row * 64 + (((4 * kc + g) ^ (li & 7)) * 8)];
#pragma unroll
            for (int nt = 0; nt < 2; ++nt) {
                int n = wn * 32 + nt * 16 + li;
                s16x8 bf = *(const s16x8*)&Bs[n * 64 + (((4 * kc + g) ^ (li & 7)) * 8)];
                acc[nt] = __builtin_amdgcn_mfma_f32_16x16x32_bf16(af, bf, acc[nt], 0, 0, 0);
            }
        }
    }
#pragma unroll
    for (int nt = 0; nt < 2; ++nt)
#pragma unroll
        for (int r = 0; r < 4; ++r) {
            int gm = m0 + wm * 16 + 4 * g + r;
            int gn = n0 + wn * 32 + nt * 16 + li;
            if (gn < N) {
                float v = acc[nt][r];
                if (EPI == 1) v += add[(size_t)gm * N + gn];
                if (EPI == 2) ((short*)Cv)[(size_t)gm * N + gn] = f2b(v);
                else          ((float*)Cv)[(size_t)gm * N + gn] = v;
            }
        }
}

// ---------------- wo projection fused with attention partial combine ----------------
__global__ __launch_bounds__(512)
void k_wo_gemm(const short* __restrict__ po, const float* __restrict__ pl,
               const short* __restrict__ BT, float* __restrict__ C,
               const float* __restrict__ add) {
    constexpr int N = 512, K = 512;
    __shared__ __align__(16) short As[64 * 64];
    __shared__ __align__(16) short Bs[64 * 64];
    int tid = threadIdx.x;
    int w = tid >> 6, l = tid & 63, g = l >> 4, li = l & 15;
    int wm = w >> 1, wn = w & 1;
    int m0 = blockIdx.y * 64, n0 = blockIdx.x * 64;
    int row = tid >> 3, ch = tid & 7;
    int t = m0 + row;
    int b = t >> 11, q = t & 2047;
    f32x4 acc[2] = {};
    for (int k0 = 0; k0 < K; k0 += 64) {
        int h = k0 >> 6;
        int bhq = (b * 8 + h) * 2048 + q;
        size_t pb = (size_t)bhq * 256 + 8 * ch;
        float4 l4 = *(const float4*)(pl + (size_t)bhq * 4);
        float inv = 1.f / (l4.x + l4.y + l4.z + l4.w);
        union { int4 v; short s[8]; } p0, p1, p2, p3, ov;
        p0.v = *(const int4*)(po + pb);
        p1.v = *(const int4*)(po + pb + 64);
        p2.v = *(const int4*)(po + pb + 128);
        p3.v = *(const int4*)(po + pb + 192);
#pragma unroll
        for (int i = 0; i < 8; ++i) {
            float os = b2f(p0.s[i]) + b2f(p1.s[i]) + b2f(p2.s[i]) + b2f(p3.s[i]);
            ov.s[i] = f2b(os * inv);
        }
        int4 bv = *(const int4*)(BT + (size_t)(n0 + row) * K + k0 + 8 * ch);
        __syncthreads();
        *(int4*)&As[row * 64 + ((ch ^ (row & 7)) * 8)] = ov.v;
        *(int4*)&Bs[row * 64 + ((ch ^ (row & 7)) * 8)] = bv;
        __syncthreads();
#pragma unroll
        for (int kc = 0; kc < 2; ++kc) {
            int rr = wm * 16 + li;
            s16x8 af = *(const s16x8*)&As[rr * 64 + (((4 * kc + g) ^ (li & 7)) * 8)];
#pragma unroll
            for (int nt = 0; nt < 2; ++nt) {
                int n = wn * 32 + nt * 16 + li;
                s16x8 bf = *(const s16x8*)&Bs[n * 64 + (((4 * kc + g) ^ (li & 7)) * 8)];
                acc[nt] = __builtin_amdgcn_mfma_f32_16x16x32_bf16(af, bf, acc[nt], 0, 0, 0);
            }
        }
    }
#pragma unroll
    for (int nt = 0; nt < 2; ++nt)
#pragma unroll
        for (int r = 0; r < 4; ++r) {
            int gm = m0 + wm * 16 + 4 * g + r;
            int gn = n0 + wn * 32 + nt * 16 + li;
            C[(size_t)gm * N + gn] = acc[nt][r] + add[(size_t)gm * N + gn];
        }
}

// ---------------- shared expert (64x64 tile, 8 waves): gact = silu(x@wg)*(x@wu) ----------------
__global__ __launch_bounds__(512)
void k_shexp(const short* __restrict__ X, const short* __restrict__ WGt, const short* __restrict__ WUt,
             short* __restrict__ gact) {
    __shared__ __align__(16) short As[64 * 64];
    __shared__ __align__(16) short Bg[64 * 64];
    __shared__ __align__(16) short Bu[64 * 64];
    int tid = threadIdx.x;
    int w = tid >> 6, l = tid & 63, g = l >> 4, li = l & 15;
    int wm = w >> 1, wn = w & 1;
    int m0 = blockIdx.x * 64, n0 = blockIdx.y * 64;
    f32x4 ag[2] = {}, au[2] = {};
    for (int k0 = 0; k0 < 512; k0 += 64) {
        __syncthreads();
        {
            int row = tid >> 3, ch = tid & 7;
            *(int4*)&As[row * 64 + ((ch ^ (row & 7)) * 8)] =
                *(const int4*)(X + (size_t)(m0 + row) * 512 + k0 + 8 * ch);
            *(int4*)&Bg[row * 64 + ((ch ^ (row & 7)) * 8)] =
                *(const int4*)(WGt + (size_t)(n0 + row) * 512 + k0 + 8 * ch);
            *(int4*)&Bu[row * 64 + ((ch ^ (row & 7)) * 8)] =
                *(const int4*)(WUt + (size_t)(n0 + row) * 512 + k0 + 8 * ch);
        }
        __syncthreads();
#pragma unroll
        for (int kc = 0; kc < 2; ++kc) {
            int row = wm * 16 + li;
            s16x8 af = *(const s16x8*)&As[row * 64 + (((4 * kc + g) ^ (li & 7)) * 8)];
#pragma unroll
            for (int nt = 0; nt < 2; ++nt) {
                int n = wn * 32 + nt * 16 + li;
                s16x8 bg = *(const s16x8*)&Bg[n * 64 + (((4 * kc + g) ^ (li & 7)) * 8)];
                s16x8 bu = *(const s16x8*)&Bu[n * 64 + (((4 * kc + g) ^ (li & 7)) * 8)];
                ag[nt] = __builtin_amdgcn_mfma_f32_16x16x32_bf16(af, bg, ag[nt], 0, 0, 0);
                au[nt] = __builtin_amdgcn_mfma_f32_16x16x32_bf16(af, bu, au[nt], 0, 0, 0);
            }
        }
    }
#pragma unroll
    for (int nt = 0; nt < 2; ++nt)
#pragma unroll
        for (int r = 0; r < 4; ++r) {
            int gm = m0 + wm * 16 + 4 * g + r;
            int gn = n0 + wn * 32 + nt * 16 + li;
            float gv = ag[nt][r], uv = au[nt][r];
            gact[(size_t)gm * 256 + gn] = f2b(gv / (1.f + __expf(-gv)) * uv);
        }
}

// ---------------- fused q/k/v build (bf16 inputs). Q pre-scaled by log2(e)/sqrt(96). -------------
__global__ void k_build_qkv(const short* __restrict__ qcrb, const short* __restrict__ kvbb,
                            const float* __restrict__ cqkv,
                            short* __restrict__ qb, short* __restrict__ kb, short* __restrict__ vbt) {
    const float scale = 0.14724389f;  // log2(e)/sqrt(96)
    int gid = blockIdx.x * 256 + threadIdx.x;
    const int NQ = 16 * 2048 * 96;
    if (gid < NQ) {
        int d = gid % 96;
        int rs = gid / 96;
        int srow = rs & 2047;
        int bh = rs >> 11;
        int b = bh >> 3, h = bh & 7;
        int t = b * 2048 + srow;
        const short* src = qcrb + (size_t)t * 768 + h * 96;
        float val;
        if (d < 64) {
            val = b2f(src[d]);
        } else {
            int d2 = d - 64;
            int fi = d2 & 15;
            float ang = (float)srow * __expf(-((float)(2 * fi) / 32.f) * 9.210340371976184f);
            float s, c; __sincosf(ang, &s, &c);
            float x = b2f(src[64 + d2]);
            float r = (d2 < 16) ? -b2f(src[64 + d2 + 16]) : b2f(src[64 + d2 - 16]);
            val = x * c + r * s;
        }
        qb[gid] = f2b(val * scale);
    } else if (gid < 2 * NQ) {
        int g2 = gid - NQ;
        int d = g2 % 96;
        int rs = g2 / 96;
        int srow = rs & 2047;
        int bh = rs >> 11;
        int b = bh >> 3, h = bh & 7;
        int t = b * 2048 + srow;
        if (d < 64) {
            kb[g2] = kvbb[(size_t)t * 1024 + h * 128 + d];
        } else {
            int d2 = d - 64;
            int fi = d2 & 15;
            float ang = (float)srow * __expf(-((float)(2 * fi) / 32.f) * 9.210340371976184f);
            float s, c; __sincosf(ang, &s, &c);
            float x = cqkv[(size_t)t * 416 + 384 + d2];
            float r = (d2 < 16) ? -cqkv[(size_t)t * 416 + 384 + d2 + 16]
                                :  cqkv[(size_t)t * 416 + 384 + d2 - 16];
            kb[g2] = f2b(x * c + r * s);
        }
    } else {
        int g2 = gid - 2 * NQ;   // 16*64*2048
        int key = g2 & 2047;
        int dim = (g2 >> 11) & 63;
        int bh = g2 >> 17;
        int b = bh >> 3, h = bh & 7;
        vbt[g2] = kvbb[(size_t)(b * 2048 + key) * 1024 + h * 128 + 64 + dim];
    }
}

// ---------------- K-split(4) MFMA flash attention, 32 q/wave, 128-key super-tiles ----------------
// 2 x 64-key halves computed per barrier pair (halves barrier count). MFMA ones-row denominator.
__global__ __launch_bounds__(256)
void k_attn(const short* __restrict__ qb, const short* __restrict__ kb,
            const short* __restrict__ vbt, short* __restrict__ po, float* __restrict__ pl) {
    __shared__ __align__(16) short Ks[128 * 100];   // 25.6 KB
    __shared__ __align__(16) short Vs[80 * 128];    // 20.5 KB (rows 64..79 = ones/zero)
    int tid = threadIdx.x;
    int w = tid >> 6, l = tid & 63, g = l >> 4, li = l & 15;
    int blk = blockIdx.x;
    int bh = blk >> 6, rem = blk & 63;
    int qt = rem >> 2, ks = rem & 3;
    int qc0 = qt * 128 + w * 32;

    {
        const short one = 0x3F80;  // bf16 1.0
        for (int i = tid; i < 16 * 128; i += 256)
            Vs[64 * 128 + i] = (i < 128) ? one : (short)0;
    }

    s16x8 qf[2][3];
#pragma unroll
    for (int j = 0; j < 2; ++j) {
        const short* qp = qb + (size_t)(bh * 2048 + qc0 + j * 16 + li) * 96;
#pragma unroll
        for (int c = 0; c < 3; ++c) qf[j][c] = *(const s16x8*)(qp + 32 * c + 8 * g);
    }

    f32x4 o[2][5] = {};
    const short* kbase = kb + (size_t)bh * 2048 * 96;
    const short* vbase = vbt + (size_t)bh * 64 * 2048;

    for (int t = 0; t < 4; ++t) {
        int koff = ks * 512 + t * 128;
        __syncthreads();
#pragma unroll
        for (int p = 0; p < 6; ++p) {           // 128 keys x 12 int4 chunks
            int flat = p * 256 + tid;
            int key = flat / 12, u = flat % 12;
            *(int4*)&Ks[key * 100 + 8 * u] = *(const int4*)(kbase + (size_t)(koff + key) * 96 + 8 * u);
        }
#pragma unroll
        for (int p = 0; p < 4; ++p) {           // 64 dims x 16 kc8 chunks
            int flat = p * 256 + tid;
            int dim = flat >> 4, kc8 = flat & 15;
            int4 v = *(const int4*)(vbase + (size_t)dim * 2048 + koff + 8 * kc8);
            int sw = dim & 15;
            *(int2*)&Vs[dim * 128 + (((2 * kc8) ^ sw) * 4)]     = make_int2(v.x, v.y);
            *(int2*)&Vs[dim * 128 + (((2 * kc8 + 1) ^ sw) * 4)] = make_int2(v.z, v.w);
        }
        __syncthreads();

#pragma unroll
        for (int h = 0; h < 2; ++h) {
            // S^T[key][q] = K · Q^T on keys [64h, 64h+64)
            f32x4 s[2][4];
#pragma unroll
            for (int kt = 0; kt < 4; ++kt) {
                f32x4 a0 = {}, a1 = {};
#pragma unroll
                for (int c = 0; c < 3; ++c) {
                    s16x8 kf = *(const s16x8*)&Ks[(64 * h + kt * 16 + li) * 100 + 32 * c + 8 * g];
                    a0 = __builtin_amdgcn_mfma_f32_16x16x32_bf16(kf, qf[0][c], a0, 0, 0, 0);
                    a1 = __builtin_amdgcn_mfma_f32_16x16x32_bf16(kf, qf[1][c], a1, 0, 0, 0);
                }
                s[0][kt] = a0; s[1][kt] = a1;
            }
#pragma unroll
            for (int j = 0; j < 2; ++j)
#pragma unroll
                for (int kt = 0; kt < 4; ++kt)
#pragma unroll
                    for (int r = 0; r < 4; ++r) s[j][kt][r] = exp2f(s[j][kt][r]);
            s16x8 pf[2][2];
#pragma unroll
            for (int j = 0; j < 2; ++j)
#pragma unroll
                for (int kcl = 0; kcl < 2; ++kcl) {
                    s16x8 tt;
#pragma unroll
                    for (int r = 0; r < 4; ++r) { tt[r] = f2b(s[j][2 * kcl][r]); tt[4 + r] = f2b(s[j][2 * kcl + 1][r]); }
                    pf[j][kcl] = tt;
                }
            // O^T += V^T · P^T on k-slots {2h, 2h+1} of the 128-key tile
#pragma unroll
            for (int dt = 0; dt < 5; ++dt) {
                int dim = dt * 16 + li;
#pragma unroll
                for (int kcl = 0; kcl < 2; ++kcl) {
                    int kc = 2 * h + kcl;
                    int2 a0 = *(const int2*)&Vs[dim * 128 + (((8 * kc + g) ^ li) * 4)];
                    int2 a1 = *(const int2*)&Vs[dim * 128 + (((8 * kc + 4 + g) ^ li) * 4)];
                    union { s16x8 v; int i[4]; } vf;
                    vf.i[0] = a0.x; vf.i[1] = a0.y; vf.i[2] = a1.x; vf.i[3] = a1.y;
                    o[0][dt] = __builtin_amdgcn_mfma_f32_16x16x32_bf16(vf.v, pf[0][kcl], o[0][dt], 0, 0, 0);
                    o[1][dt] = __builtin_amdgcn_mfma_f32_16x16x32_bf16(vf.v, pf[1][kcl], o[1][dt], 0, 0, 0);
                }
            }
        }
    }
#pragma unroll
    for (int j = 0; j < 2; ++j) {
        int qcol = qc0 + j * 16 + li;
        size_t qbase = ((size_t)(bh * 2048 + qcol) * 4 + ks) * 64;
#pragma unroll
        for (int dt = 0; dt < 4; ++dt) {
            union { short s[4]; int2 v; } pk;
#pragma unroll
            for (int r = 0; r < 4; ++r) pk.s[r] = f2b(o[j][dt][r]);
            *(int2*)(po + qbase + dt * 16 + 4 * g) = pk.v;
        }
        if (g == 0) pl[(size_t)(bh * 2048 + qcol) * 4 + ks] = o[j][4][0];
    }
}

// ---------------- scatter: block-aggregated expert list build ----------------
__global__ __launch_bounds__(256)
void k_scatter(const int4* __restrict__ toke, const float4* __restrict__ tokw,
               float* __restrict__ ewt, int* __restrict__ ecnt, int* __restrict__ etok) {
    __shared__ int lcnt[16];
    __shared__ int lbase[16];
    int tid = threadIdx.x;
    int t = blockIdx.x * 256 + tid;
    if (tid < 16) lcnt[tid] = 0;
    __syncthreads();
    int4 e4 = toke[t];
    float4 w4 = tokw[t];
    int es[4] = { e4.x, e4.y, e4.z, e4.w };
    float wv[4] = { w4.x, w4.y, w4.z, w4.w };
    int ls[4];
#pragma unroll
    for (int kk = 0; kk < 4; ++kk) ls[kk] = atomicAdd(&lcnt[es[kk]], 1);
    __syncthreads();
    if (tid < 16) lbase[tid] = atomicAdd(&ecnt[tid], lcnt[tid]);
    __syncthreads();
#pragma unroll
    for (int kk = 0; kk < 4; ++kk) {
        int slot = lbase[es[kk]] + ls[kk];
        etok[es[kk] * 4096 + slot] = t * 4 + kk;
        ewt[es[kk] * 4096 + slot] = wv[kk];
    }
}

// ---------------- MoE stage 1 (MFMA, 8 waves, inline tile-scan): eact = silu(x@wg)*(x@wu) --------
__global__ __launch_bounds__(512)
void k_moe1m(const short* __restrict__ X, const short* __restrict__ WGt, const short* __restrict__ WUt,
             const int* __restrict__ ecnt, const int* __restrict__ etok, short* __restrict__ eact) {
    __shared__ int ecs[16];
    __shared__ __align__(16) short As[128 * 64];
    __shared__ __align__(16) short Bg[64 * 64];
    __shared__ __align__(16) short Bu[64 * 64];
    __shared__ int toks[128];
    int tid = threadIdx.x;
    if (tid < 16) ecs[tid] = ecnt[tid];
    __syncthreads();
    int bid = blockIdx.x, e = 0;
    for (; e < 16; ++e) { int n = (ecs[e] + 127) >> 7; if (bid < n) break; bid -= n; }
    if (e >= 16) return;
    int base = bid << 7;
    int rows = min(128, ecs[e] - base);
    int n0 = blockIdx.y * 64;
    if (tid < 128) toks[tid] = (tid < rows) ? etok[e * 4096 + base + tid] : -1;
    __syncthreads();
    int w = tid >> 6, l = tid & 63, g = l >> 4, li = l & 15;
    int wm = w >> 1, wn = w & 1;
    const short* wgp = WGt + (size_t)e * 256 * 512;
    const short* wup = WUt + (size_t)e * 256 * 512;
    f32x4 ag[2][2] = {}, au[2][2] = {};
    for (int k0 = 0; k0 < 512; k0 += 64) {
        __syncthreads();
#pragma unroll
        for (int p = 0; p < 2; ++p) {
            int flat = p * 512 + tid;
            int row = flat >> 3, ch = flat & 7;
            int tk = toks[row];
            int4 v = {0, 0, 0, 0};
            if (tk >= 0) v = *(const int4*)(X + (size_t)(tk >> 2) * 512 + k0 + 8 * ch);
            *(int4*)&As[row * 64 + ((ch ^ (row & 7)) * 8)] = v;
        }
        {
            int n = tid >> 3, ch = tid & 7;
            *(int4*)&Bg[n * 64 + ((ch ^ (n & 7)) * 8)] = *(const int4*)(wgp + (size_t)(n0 + n) * 512 + k0 + 8 * ch);
            *(int4*)&Bu[n * 64 + ((ch ^ (n & 7)) * 8)] = *(const int4*)(wup + (size_t)(n0 + n) * 512 + k0 + 8 * ch);
        }
        __syncthreads();
#pragma unroll
        for (int kc = 0; kc < 2; ++kc) {
            s16x8 af[2], bg[2], bu[2];
#pragma unroll
            for (int mt = 0; mt < 2; ++mt) {
                int row = wm * 32 + mt * 16 + li;
                af[mt] = *(const s16x8*)&As[row * 64 + (((4 * kc + g) ^ (li & 7)) * 8)];
            }
#pragma unroll
            for (int nt = 0; nt < 2; ++nt) {
                int n = wn * 32 + nt * 16 + li;
                bg[nt] = *(const s16x8*)&Bg[n * 64 + (((4 * kc + g) ^ (li & 7)) * 8)];
                bu[nt] = *(const s16x8*)&Bu[n * 64 + (((4 * kc + g) ^ (li & 7)) * 8)];
            }
#pragma unroll
            for (int mt = 0; mt < 2; ++mt)
#pragma unroll
                for (int nt = 0; nt < 2; ++nt) {
                    ag[mt][nt] = __builtin_amdgcn_mfma_f32_16x16x32_bf16(af[mt], bg[nt], ag[mt][nt], 0, 0, 0);
                    au[mt][nt] = __builtin_amdgcn_mfma_f32_16x16x32_bf16(af[mt], bu[nt], au[mt][nt], 0, 0, 0);
                }
        }
    }
#pragma unroll
    for (int mt = 0; mt < 2; ++mt)
#pragma unroll
        for (int nt = 0; nt < 2; ++nt)
#pragma unroll
            for (int r = 0; r < 4; ++r) {
                int local = wm * 32 + mt * 16 + 4 * g + r;
                if (local < rows) {
                    int entry = toks[local];
                    int gn = n0 + wn * 32 + nt * 16 + li;
                    float gv = ag[mt][nt][r], uv = au[mt][nt][r];
                    eact[(size_t)entry * 256 + gn] = f2b(gv / (1.f + __expf(-gv)) * uv);
                }
            }
}

// ---------------- MoE stage 2 (MFMA, 8 waves, inline tile-scan): out += w * (eact @ wd) ----------
__global__ __launch_bounds__(512)
void k_moe2m(const short* __restrict__ EA, const short* __restrict__ WDt,
             const int* __restrict__ ecnt, const int* __restrict__ etok,
             const float* __restrict__ ewt, float* __restrict__ oacc) {
    __shared__ int ecs[16];
    __shared__ __align__(16) short As[128 * 64];
    __shared__ __align__(16) short Bs[64 * 64];
    __shared__ int toks[128];
    __shared__ float wts[128];
    int tid = threadIdx.x;
    if (tid < 16) ecs[tid] = ecnt[tid];
    __syncthreads();
    int bid = blockIdx.x, e = 0;
    for (; e < 16; ++e) { int n = (ecs[e] + 127) >> 7; if (bid < n) break; bid -= n; }
    if (e >= 16) return;
    int base = bid << 7;
    int rows = min(128, ecs[e] - base);
    int n0 = blockIdx.y * 64;
    if (tid < 128) {
        toks[tid] = (tid < rows) ? etok[e * 4096 + base + tid] : -1;
        wts[tid]  = (tid < rows) ? ewt[e * 4096 + base + tid] : 0.f;
    }
    __syncthreads();
    int w = tid >> 6, l = tid & 63, g = l >> 4, li = l & 15;
    int wm = w >> 1, wn = w & 1;
    const short* wdp = WDt + (size_t)e * 512 * 256;
    f32x4 acc[2][2] = {};
    for (int k0 = 0; k0 < 256; k0 += 64) {
        __syncthreads();
#pragma unroll
        for (int p = 0; p < 2; ++p) {
            int flat = p * 512 + tid;
            int row = flat >> 3, ch = flat & 7;
            int tk = toks[row];
            int4 v = {0, 0, 0, 0};
            if (tk >= 0) v = *(const int4*)(EA + (size_t)tk * 256 + k0 + 8 * ch);
            *(int4*)&As[row * 64 + ((ch ^ (row & 7)) * 8)] = v;
        }
        {
            int n = tid >> 3, ch = tid & 7;
            *(int4*)&Bs[n * 64 + ((ch ^ (n & 7)) * 8)] = *(const int4*)(wdp + (size_t)(n0 + n) * 256 + k0 + 8 * ch);
        }
        __syncthreads();
#pragma unroll
        for (int kc = 0; kc < 2; ++kc) {
            s16x8 af[2], bf[2];
#pragma unroll
            for (int mt = 0; mt < 2; ++mt) {
                int row = wm * 32 + mt * 16 + li;
                af[mt] = *(const s16x8*)&As[row * 64 + (((4 * kc + g) ^ (li & 7)) * 8)];
            }
#pragma unroll
            for (int nt = 0; nt < 2; ++nt) {
                int n = wn * 32 + nt * 16 + li;
                bf[nt] = *(const s16x8*)&Bs[n * 64 + (((4 * kc + g) ^ (li & 7)) * 8)];
            }
#pragma unroll
            for (int mt = 0; mt < 2; ++mt)
#pragma unroll
                for (int nt = 0; nt < 2; ++nt)
                    acc[mt][nt] = __builtin_amdgcn_mfma_f32_16x16x32_bf16(af[mt], bf[nt], acc[mt][nt], 0, 0, 0);
        }
    }
#pragma unroll
    for (int mt = 0; mt < 2; ++mt)
#pragma unroll
        for (int nt = 0; nt < 2; ++nt)
#pragma unroll
            for (int r = 0; r < 4; ++r) {
                int local = wm * 32 + mt * 16 + 4 * g + r;
                if (local < rows) {
                    int tok = toks[local] >> 2;
                    int gn = n0 + wn * 32 + nt * 16 + li;
                    atomicAdd(&oacc[(size_t)tok * 512 + gn], acc[mt][nt][r] * wts[local]);
                }
            }
}

// ---------------- host launcher ----------------
extern "C" void kernel_launch(void* const* d_in, const int* in_sizes, int n_in,
                              void* d_out, int out_size, void* d_ws, size_t ws_size,
                              hipStream_t stream) {
    const float* hs       = (const float*)d_in[0];
    const float* w_innorm = (const float*)d_in[1];
    const float* w_dq     = (const float*)d_in[2];
    const float* w_qnorm  = (const float*)d_in[3];
    const float* w_uq     = (const float*)d_in[4];
    const float* w_dkv    = (const float*)d_in[5];
    const float* w_kvnorm = (const float*)d_in[6];
    const float* w_ukv    = (const float*)d_in[7];
    const float* w_o      = (const float*)d_in[8];
    const float* w_post   = (const float*)d_in[9];
    const float* w_gate   = (const float*)d_in[10];
    const float* sh_wg    = (const float*)d_in[11];
    const float* sh_wu    = (const float*)d_in[12];
    const float* sh_wd    = (const float*)d_in[13];
    const float* r_wg     = (const float*)d_in[14];
    const float* r_wu     = (const float*)d_in[15];
    const float* r_wd     = (const float*)d_in[16];

    float* ws   = (float*)d_ws;
    float* cqkv = ws + OFF_CQKV;
    short* qcrb = (short*)(ws + OFF_QCR);
    short* kvbb = (short*)(ws + OFF_KVB);
    float* r2   = ws + OFF_R2;
    short* po   = (short*)(ws + OFF_PO);
    float* pl   = ws + OFF_PL;
    int4*  toke = (int4*)(ws + OFF_TOKE);
    float4* tokw = (float4*)(ws + OFF_TOKW);
    float* ewt  = ws + OFF_EWT;
    int*   ecnt = (int*)(ws + OFF_ECNT);
    int*   etok = (int*)(ws + OFF_ETOK);
    short* xnb   = (short*)(ws + OFF_XNB);
    short* cqnb  = (short*)(ws + OFF_CQNB);
    short* ckvnb = (short*)(ws + OFF_CKVNB);
    short* qb    = (short*)(ws + OFF_QB);
    short* kb    = (short*)(ws + OFF_KB);
    short* vbt   = (short*)(ws + OFF_VBT);
    short* xn2b  = (short*)(ws + OFF_XN2B);
    short* gact  = (short*)(ws + OFF_GACT);
    short* eact  = (short*)(ws + OFF_EACT);
    short* wqkvT = (short*)(ws + OFF_WQKVT);
    short* wuqT  = (short*)(ws + OFF_WUQT);
    short* wukvT = (short*)(ws + OFF_WUKVT);
    short* woT   = (short*)(ws + OFF_WOT);
    short* shwgT = (short*)(ws + OFF_SHWGT);
    short* shwuT = (short*)(ws + OFF_SHWUT);
    short* shwdT = (short*)(ws + OFF_SHWDT);
    short* rwgT  = (short*)(ws + OFF_RWGT);
    short* rwuT  = (short*)(ws + OFF_RWUT);
    short* rwdT  = (short*)(ws + OFF_RWDT);

    float* outF = (float*)d_out;

    // 0. fused weight convert+transpose (bf16 [N][K])
    CvtTab tab;
    const float* srcs[11] = { w_dq, w_dkv, w_uq, w_ukv, w_o, sh_wg, sh_wu, sh_wd, r_wg, r_wu, r_wd };
    short* dsts[11] = { wqkvT, wqkvT + (size_t)256 * 512, wuqT, wukvT, woT, shwgT, shwuT, shwdT, rwgT, rwuT, rwdT };
    int Ks_[11] = { 512, 512, 256, 128, 512, 512, 512, 256, 512, 512, 256 };
    int Ns_[11] = { 256, 160, 768, 1024, 512, 256, 256, 512, 256, 256, 512 };
    int Es_[11] = { 1, 1, 1, 1, 1, 1, 1, 1, 16, 16, 16 };
    int cum = 0;
    for (int i = 0; i < 11; ++i) {
        tab.src[i] = srcs[i]; tab.dst[i] = dsts[i];
        tab.K[i] = Ks_[i]; tab.N[i] = Ns_[i];
        cum += Es_[i] * (Ks_[i] >> 5) * (Ns_[i] >> 5);
        tab.end[i] = cum;
    }
    k_cvt_all<<<cum, 256, 0, stream>>>(tab);

    // 1. input RMSNorm -> bf16 (also zeroes ecnt)
    k_rms<<<Tt, 256, 0, stream>>>(hs, 512, w_innorm, xnb, 512, 512, ecnt);
    // 2. fused down-projection (dq|dkv), N=416, f32 out
    k_mgemm<0><<<dim3(7, 64), 512, 0, stream>>>(xnb, wqkvT, (void*)cqkv, nullptr, 416, 512);
    // 3. fused latent norms -> bf16
    k_rms2<<<2 * Tt, 256, 0, stream>>>(cqkv, w_qnorm, cqnb, w_kvnorm, ckvnb);
    // 4. up-projections -> bf16 directly
    k_mgemm<2><<<dim3(12, 64), 512, 0, stream>>>(cqnb, wuqT, (void*)qcrb, nullptr, 768, 256);
    k_mgemm<2><<<dim3(16, 64), 512, 0, stream>>>(ckvnb, wukvT, (void*)kvbb, nullptr, 1024, 128);
    // 5. fused q/k/v build (RoPE, Q pre-scaled incl log2e; bf16 inputs)
    k_build_qkv<<<(2 * 16 * 2048 * 96 + 16 * 64 * 2048) / 256, 256, 0, stream>>>(qcrb, kvbb, cqkv, qb, kb, vbt);
    // 6. K-split(4) MFMA flash attention (32 q/wave, 128-key super-tiles)
    k_attn<<<1024, 256, 0, stream>>>(qb, kb, vbt, po, pl);
    // 7. wo projection fused with partial combine + residual
    k_wo_gemm<<<dim3(8, 64), 512, 0, stream>>>(po, pl, woT, r2, hs);
    // 8. fused post-norm + router
    k_rms_router<<<Tt, 256, 0, stream>>>(r2, w_post, w_gate, xn2b, toke, tokw);
    // 9. shared expert then down-proj + residual into d_out
    k_shexp<<<dim3(64, 4), 512, 0, stream>>>(xn2b, shwgT, shwuT, gact);
    k_mgemm<1><<<dim3(8, 64), 512, 0, stream>>>(gact, shwdT, (void*)outF, r2, 512, 256);
    // 10. scatter + MoE (inline tile-scan)
    k_scatter<<<16, 256, 0, stream>>>(toke, tokw, ewt, ecnt, etok);
    k_moe1m<<<dim3(144, 4), 512, 0, stream>>>(xn2b, rwgT, rwuT, ecnt, etok, eact);
    k_moe2m<<<dim3(144, 8), 512, 0, stream>>>(eact, rwdT, ecnt, etok, ewt, outF);
}

// Round 18
// 227.631 us; speedup vs baseline: 1.0624x; 1.0624x over previous
//
#include <hip/hip_runtime.h>
#include <hip/hip_bf16.h>
#include <math.h>

typedef float f32x4 __attribute__((ext_vector_type(4)));
typedef short s16x8 __attribute__((ext_vector_type(8)));

// ---------------- problem constants ----------------
constexpr int Tt = 4096;
constexpr int NEn = 16;
constexpr float EPSf = 1.1920929e-07f;

__device__ __forceinline__ short f2b(float f) {
    union { __hip_bfloat16 h; short s; } u;
    u.h = __float2bfloat16(f);
    return u.s;
}
__device__ __forceinline__ float b2f(short s) {
    union { float f; unsigned u; } v;
    v.u = ((unsigned)(unsigned short)s) << 16;
    return v.f;
}

// ---------------- workspace layout (float elements, 16-float aligned) ----------------
constexpr size_t alg(size_t x) { return (x + 15) & ~(size_t)15; }
// f32 buffers (region [0, OFF_R2) is reused for attention partials after build)
constexpr size_t OFF_CQKV = 0;                                   // T*416 f32 (cq 0..255 | ckv 256..415)
constexpr size_t OFF_QCR  = alg(OFF_CQKV + (size_t)Tt * 416);    // T*768 bf16 now (region sized for f32)
constexpr size_t OFF_KVB  = alg(OFF_QCR  + (size_t)Tt * 768);    // T*1024 bf16 now
constexpr size_t OFF_R2   = alg(OFF_KVB  + (size_t)Tt * 1024);   // T*512 f32
constexpr size_t OFF_TOKE = alg(OFF_R2   + (size_t)Tt * 512);    // T*4 ints
constexpr size_t OFF_TOKW = alg(OFF_TOKE + (size_t)Tt * 4);      // T*4 f32
constexpr size_t OFF_EWT  = alg(OFF_TOKW + (size_t)Tt * 4);      // 16*4096 f32
constexpr size_t OFF_ECNT = alg(OFF_EWT  + (size_t)NEn * Tt);    // ints
constexpr size_t OFF_ETOK = alg(OFF_ECNT + 64);                  // 16*4096 ints
// attention partials ALIAS dead CQKV/QCR/KVB region (dead after k_build_qkv):
constexpr size_t OFF_PO   = 0;                                   // bf16 16*2048*4*64 = 4,194,304 float-slots
constexpr size_t OFF_PL   = (size_t)16 * 2048 * 4 * 64 / 2;      // f32 131,072
// bf16 buffers (element counts halved into float units)
constexpr size_t OFF_XNB   = alg(OFF_ETOK + (size_t)NEn * Tt);       // T*512 bf16
constexpr size_t OFF_CQNB  = alg(OFF_XNB   + (size_t)Tt * 512 / 2);  // T*256 bf16
constexpr size_t OFF_CKVNB = alg(OFF_CQNB  + (size_t)Tt * 256 / 2);  // T*128 bf16
constexpr size_t OFF_QB    = alg(OFF_CKVNB + (size_t)Tt * 128 / 2);  // 16*2048*96 bf16
constexpr size_t OFF_KB    = alg(OFF_QB    + (size_t)16 * 2048 * 96 / 2);
constexpr size_t OFF_VBT   = alg(OFF_KB    + (size_t)16 * 2048 * 96 / 2); // 16*64*2048 bf16
constexpr size_t OFF_XN2B  = alg(OFF_VBT   + (size_t)16 * 64 * 2048 / 2);
constexpr size_t OFF_GACT  = alg(OFF_XN2B  + (size_t)Tt * 512 / 2);  // T*256 bf16
constexpr size_t OFF_EACT  = alg(OFF_GACT  + (size_t)Tt * 256 / 2);  // 16384*256 bf16
// transposed bf16 weights [N][K]
constexpr size_t OFF_WQKVT = alg(OFF_EACT  + (size_t)16384 * 256 / 2); // 416*512
constexpr size_t OFF_WUQT  = alg(OFF_WQKVT + (size_t)416 * 512 / 2);
constexpr size_t OFF_WUKVT = alg(OFF_WUQT  + (size_t)768 * 256 / 2);
constexpr size_t OFF_WOT   = alg(OFF_WUKVT + (size_t)1024 * 128 / 2);
constexpr size_t OFF_SHWGT = alg(OFF_WOT   + (size_t)512 * 512 / 2);
constexpr size_t OFF_SHWUT = alg(OFF_SHWGT + (size_t)256 * 512 / 2);
constexpr size_t OFF_SHWDT = alg(OFF_SHWUT + (size_t)256 * 512 / 2);
constexpr size_t OFF_RWGT  = alg(OFF_SHWDT + (size_t)512 * 256 / 2);
constexpr size_t OFF_RWUT  = alg(OFF_RWGT  + (size_t)16 * 256 * 512 / 2);
constexpr size_t OFF_RWDT  = alg(OFF_RWUT  + (size_t)16 * 256 * 512 / 2);

// ---------------- fused convert + transpose (all weights, one launch) ----------------
struct CvtTab {
    const float* src[11];
    short* dst[11];
    int K[11], N[11], end[11];
};
__global__ __launch_bounds__(256)
void k_cvt_all(CvtTab tab) {
    __shared__ float t[32][33];
    int bid = blockIdx.x;
    int i = 0;
    while (bid >= tab.end[i]) ++i;
    int tloc = bid - (i ? tab.end[i - 1] : 0);
    int K = tab.K[i], N = tab.N[i];
    int ntiles = N >> 5, perE = ntiles * (K >> 5);
    int e = tloc / perE, rem = tloc - e * perE;
    int k0 = (rem / ntiles) << 5, n0 = (rem % ntiles) << 5;
    size_t eo = (size_t)e * K * N;
    const float* src = tab.src[i];
    short* dst = tab.dst[i];
    int c = threadIdx.x & 31, r = threadIdx.x >> 5;
#pragma unroll
    for (int q = 0; q < 4; ++q)
        t[r + 8 * q][c] = src[eo + (size_t)(k0 + r + 8 * q) * N + n0 + c];
    __syncthreads();
#pragma unroll
    for (int q = 0; q < 4; ++q)
        dst[eo + (size_t)(n0 + r + 8 * q) * K + k0 + c] = f2b(t[c][r + 8 * q]);
}

// ---------------- RMSNorm f32 in -> bf16 out (also zeroes ecnt for later scatter) ---------------
__global__ void k_rms(const float* __restrict__ in, int inStride, const float* __restrict__ w,
                      short* __restrict__ outB, int outStride, int D, int* __restrict__ ecnt) {
    int row = blockIdx.x, tid = threadIdx.x;
    if (row == 0 && tid < 16) ecnt[tid] = 0;
    __shared__ float xs[512];
    __shared__ float red[256];
    const float* ip = in + (size_t)row * inStride;
    float ss = 0.f;
    for (int i = tid; i < D; i += 256) { float v = ip[i]; xs[i] = v; ss += v * v; }
    red[tid] = ss; __syncthreads();
    for (int s = 128; s > 0; s >>= 1) { if (tid < s) red[tid] += red[tid + s]; __syncthreads(); }
    float sc = rsqrtf(red[0] / (float)D + EPSf);
    for (int i = tid; i < D; i += 256) outB[(size_t)row * outStride + i] = f2b(xs[i] * sc * w[i]);
}

// ---------------- fused latent RMSNorm pair over cqkv[4096][416] ----------------
__global__ void k_rms2(const float* __restrict__ cqkv, const float* __restrict__ wq, short* __restrict__ cqnb,
                       const float* __restrict__ wkv, short* __restrict__ ckvnb) {
    int row = blockIdx.x, tid = threadIdx.x;
    __shared__ float xs[256];
    __shared__ float red[256];
    const float* ip; const float* w; short* ob; int D, outStride, r;
    if (row < Tt) { r = row;      ip = cqkv + (size_t)r * 416;       w = wq;  ob = cqnb;  D = 256; outStride = 256; }
    else          { r = row - Tt; ip = cqkv + (size_t)r * 416 + 256; w = wkv; ob = ckvnb; D = 128; outStride = 128; }
    float ss = 0.f;
    for (int i = tid; i < D; i += 256) { float v = ip[i]; xs[i] = v; ss += v * v; }
    red[tid] = ss; __syncthreads();
    for (int s = 128; s > 0; s >>= 1) { if (tid < s) red[tid] += red[tid + s]; __syncthreads(); }
    float sc = rsqrtf(red[0] / (float)D + EPSf);
    for (int i = tid; i < D; i += 256) ob[(size_t)r * outStride + i] = f2b(xs[i] * sc * w[i]);
}

// ---------------- fused post-RMSNorm + router ----------------
__global__ __launch_bounds__(256)
void k_rms_router(const float* __restrict__ r2, const float* __restrict__ wpost,
                  const float* __restrict__ wg,
                  short* __restrict__ xn2b, int4* __restrict__ toke, float4* __restrict__ tokw) {
    int t = blockIdx.x, tid = threadIdx.x;
    __shared__ float xs[512];
    __shared__ float red[256];
    __shared__ float part[16][17];
    __shared__ float sc[16];
    const float* ip = r2 + (size_t)t * 512;
    float ss = 0.f;
    for (int i = tid; i < 512; i += 256) { float v = ip[i]; xs[i] = v; ss += v * v; }
    red[tid] = ss; __syncthreads();
    for (int s = 128; s > 0; s >>= 1) { if (tid < s) red[tid] += red[tid + s]; __syncthreads(); }
    float scale = rsqrtf(red[0] / 512.f + EPSf);
    for (int i = tid; i < 512; i += 256) {
        float v = xs[i] * scale * wpost[i];
        xs[i] = v;
        xn2b[(size_t)t * 512 + i] = f2b(v);
    }
    __syncthreads();
    {
        int e = tid & 15, ch = tid >> 4;
        const float* wp = wg + (size_t)ch * 32 * 16 + e;
        float s = 0.f;
#pragma unroll 8
        for (int k = 0; k < 32; ++k) s = fmaf(xs[ch * 32 + k], wp[(size_t)k * 16], s);
        part[ch][e] = s;
    }
    __syncthreads();
    if (tid < 16) {
        float s = 0.f;
#pragma unroll
        for (int c = 0; c < 16; ++c) s += part[c][tid];
        sc[tid] = 1.f / (1.f + expf(-s));
    }
    __syncthreads();
    if (tid < 64) {
        int lane = tid, e = lane & 15;
        float scv = sc[e];
        unsigned sel = 0;
        float tw[4]; int ti[4];
#pragma unroll
        for (int kk = 0; kk < 4; ++kk) {
            float cand = ((sel >> e) & 1u) ? -1e30f : scv;
            float mx = cand;
            mx = fmaxf(mx, __shfl_xor(mx, 1));
            mx = fmaxf(mx, __shfl_xor(mx, 2));
            mx = fmaxf(mx, __shfl_xor(mx, 4));
            mx = fmaxf(mx, __shfl_xor(mx, 8));
            unsigned long long msk = __ballot(cand == mx);
            int bi = (__ffsll(msk) - 1) & 15;
            tw[kk] = mx; ti[kk] = bi;
            sel |= 1u << bi;
        }
        if (lane == 0) {
            float inv = 1.f / (tw[0] + tw[1] + tw[2] + tw[3]);
            toke[t] = make_int4(ti[0], ti[1], ti[2], ti[3]);
            tokw[t] = make_float4(tw[0] * inv, tw[1] * inv, tw[2] * inv, tw[3] * inv);
        }
    }
}

// ---------------- MFMA GEMM (64x64 tile, 8 waves): EPI 0 = f32 out, 1 = f32+residual, 2 = bf16 out
template <int EPI>
__global__ __launch_bounds__(512)
void k_mgemm(const short* __restrict__ A, const short* __restrict__ BT,
             void* __restrict__ Cv, const float* __restrict__ add, int N, int K) {
    __shared__ __align__(16) short As[64 * 64];
    __shared__ __align__(16) short Bs[64 * 64];
    int tid = threadIdx.x;
    int w = tid >> 6, l = tid & 63, g = l >> 4, li = l & 15;
    int wm = w >> 1, wn = w & 1;
    int m0 = blockIdx.y * 64, n0 = blockIdx.x * 64;
    f32x4 acc[2] = {};
    for (int k0 = 0; k0 < K; k0 += 64) {
        __syncthreads();
        {
            int row = tid >> 3, ch = tid & 7;
            *(int4*)&As[row * 64 + ((ch ^ (row & 7)) * 8)] =
                *(const int4*)(A + (size_t)(m0 + row) * K + k0 + 8 * ch);
            int4 v = {0, 0, 0, 0};
            if (n0 + row < N) v = *(const int4*)(BT + (size_t)(n0 + row) * K + k0 + 8 * ch);
            *(int4*)&Bs[row * 64 + ((ch ^ (row & 7)) * 8)] = v;
        }
        __syncthreads();
#pragma unroll
        for (int kc = 0; kc < 2; ++kc) {
            int row = wm * 16 + li;
            s16x8 af = *(const s16x8*)&As[row * 64 + (((4 * kc + g) ^ (li & 7)) * 8)];
#pragma unroll
            for (int nt = 0; nt < 2; ++nt) {
                int n = wn * 32 + nt * 16 + li;
                s16x8 bf = *(const s16x8*)&Bs[n * 64 + (((4 * kc + g) ^ (li & 7)) * 8)];
                acc[nt] = __builtin_amdgcn_mfma_f32_16x16x32_bf16(af, bf, acc[nt], 0, 0, 0);
            }
        }
    }
#pragma unroll
    for (int nt = 0; nt < 2; ++nt)
#pragma unroll
        for (int r = 0; r < 4; ++r) {
            int gm = m0 + wm * 16 + 4 * g + r;
            int gn = n0 + wn * 32 + nt * 16 + li;
            if (gn < N) {
                float v = acc[nt][r];
                if (EPI == 1) v += add[(size_t)gm * N + gn];
                if (EPI == 2) ((short*)Cv)[(size_t)gm * N + gn] = f2b(v);
                else          ((float*)Cv)[(size_t)gm * N + gn] = v;
            }
        }
}

// ---------------- wo projection fused with attention partial combine ----------------
__global__ __launch_bounds__(512)
void k_wo_gemm(const short* __restrict__ po, const float* __restrict__ pl,
               const short* __restrict__ BT, float* __restrict__ C,
               const float* __restrict__ add) {
    constexpr int N = 512, K = 512;
    __shared__ __align__(16) short As[64 * 64];
    __shared__ __align__(16) short Bs[64 * 64];
    int tid = threadIdx.x;
    int w = tid >> 6, l = tid & 63, g = l >> 4, li = l & 15;
    int wm = w >> 1, wn = w & 1;
    int m0 = blockIdx.y * 64, n0 = blockIdx.x * 64;
    int row = tid >> 3, ch = tid & 7;
    int t = m0 + row;
    int b = t >> 11, q = t & 2047;
    f32x4 acc[2] = {};
    for (int k0 = 0; k0 < K; k0 += 64) {
        int h = k0 >> 6;
        int bhq = (b * 8 + h) * 2048 + q;
        size_t pb = (size_t)bhq * 256 + 8 * ch;
        float4 l4 = *(const float4*)(pl + (size_t)bhq * 4);
        float inv = 1.f / (l4.x + l4.y + l4.z + l4.w);
        union { int4 v; short s[8]; } p0, p1, p2, p3, ov;
        p0.v = *(const int4*)(po + pb);
        p1.v = *(const int4*)(po + pb + 64);
        p2.v = *(const int4*)(po + pb + 128);
        p3.v = *(const int4*)(po + pb + 192);
#pragma unroll
        for (int i = 0; i < 8; ++i) {
            float os = b2f(p0.s[i]) + b2f(p1.s[i]) + b2f(p2.s[i]) + b2f(p3.s[i]);
            ov.s[i] = f2b(os * inv);
        }
        int4 bv = *(const int4*)(BT + (size_t)(n0 + row) * K + k0 + 8 * ch);
        __syncthreads();
        *(int4*)&As[row * 64 + ((ch ^ (row & 7)) * 8)] = ov.v;
        *(int4*)&Bs[row * 64 + ((ch ^ (row & 7)) * 8)] = bv;
        __syncthreads();
#pragma unroll
        for (int kc = 0; kc < 2; ++kc) {
            int rr = wm * 16 + li;
            s16x8 af = *(const s16x8*)&As[rr * 64 + (((4 * kc + g) ^ (li & 7)) * 8)];
#pragma unroll
            for (int nt = 0; nt < 2; ++nt) {
                int n = wn * 32 + nt * 16 + li;
                s16x8 bf = *(const s16x8*)&Bs[n * 64 + (((4 * kc + g) ^ (li & 7)) * 8)];
                acc[nt] = __builtin_amdgcn_mfma_f32_16x16x32_bf16(af, bf, acc[nt], 0, 0, 0);
            }
        }
    }
#pragma unroll
    for (int nt = 0; nt < 2; ++nt)
#pragma unroll
        for (int r = 0; r < 4; ++r) {
            int gm = m0 + wm * 16 + 4 * g + r;
            int gn = n0 + wn * 32 + nt * 16 + li;
            C[(size_t)gm * N + gn] = acc[nt][r] + add[(size_t)gm * N + gn];
        }
}

// ---------------- shared expert (64x64 tile, 8 waves): gact = silu(x@wg)*(x@wu) ----------------
__global__ __launch_bounds__(512)
void k_shexp(const short* __restrict__ X, const short* __restrict__ WGt, const short* __restrict__ WUt,
             short* __restrict__ gact) {
    __shared__ __align__(16) short As[64 * 64];
    __shared__ __align__(16) short Bg[64 * 64];
    __shared__ __align__(16) short Bu[64 * 64];
    int tid = threadIdx.x;
    int w = tid >> 6, l = tid & 63, g = l >> 4, li = l & 15;
    int wm = w >> 1, wn = w & 1;
    int m0 = blockIdx.x * 64, n0 = blockIdx.y * 64;
    f32x4 ag[2] = {}, au[2] = {};
    for (int k0 = 0; k0 < 512; k0 += 64) {
        __syncthreads();
        {
            int row = tid >> 3, ch = tid & 7;
            *(int4*)&As[row * 64 + ((ch ^ (row & 7)) * 8)] =
                *(const int4*)(X + (size_t)(m0 + row) * 512 + k0 + 8 * ch);
            *(int4*)&Bg[row * 64 + ((ch ^ (row & 7)) * 8)] =
                *(const int4*)(WGt + (size_t)(n0 + row) * 512 + k0 + 8 * ch);
            *(int4*)&Bu[row * 64 + ((ch ^ (row & 7)) * 8)] =
                *(const int4*)(WUt + (size_t)(n0 + row) * 512 + k0 + 8 * ch);
        }
        __syncthreads();
#pragma unroll
        for (int kc = 0; kc < 2; ++kc) {
            int row = wm * 16 + li;
            s16x8 af = *(const s16x8*)&As[row * 64 + (((4 * kc + g) ^ (li & 7)) * 8)];
#pragma unroll
            for (int nt = 0; nt < 2; ++nt) {
                int n = wn * 32 + nt * 16 + li;
                s16x8 bg = *(const s16x8*)&Bg[n * 64 + (((4 * kc + g) ^ (li & 7)) * 8)];
                s16x8 bu = *(const s16x8*)&Bu[n * 64 + (((4 * kc + g) ^ (li & 7)) * 8)];
                ag[nt] = __builtin_amdgcn_mfma_f32_16x16x32_bf16(af, bg, ag[nt], 0, 0, 0);
                au[nt] = __builtin_amdgcn_mfma_f32_16x16x32_bf16(af, bu, au[nt], 0, 0, 0);
            }
        }
    }
#pragma unroll
    for (int nt = 0; nt < 2; ++nt)
#pragma unroll
        for (int r = 0; r < 4; ++r) {
            int gm = m0 + wm * 16 + 4 * g + r;
            int gn = n0 + wn * 32 + nt * 16 + li;
            float gv = ag[nt][r], uv = au[nt][r];
            gact[(size_t)gm * 256 + gn] = f2b(gv / (1.f + __expf(-gv)) * uv);
        }
}

// ---------------- fused q/k/v build (bf16 inputs). Q pre-scaled by log2(e)/sqrt(96). -------------
__global__ void k_build_qkv(const short* __restrict__ qcrb, const short* __restrict__ kvbb,
                            const float* __restrict__ cqkv,
                            short* __restrict__ qb, short* __restrict__ kb, short* __restrict__ vbt) {
    const float scale = 0.14724389f;  // log2(e)/sqrt(96)
    int gid = blockIdx.x * 256 + threadIdx.x;
    const int NQ = 16 * 2048 * 96;
    if (gid < NQ) {
        int d = gid % 96;
        int rs = gid / 96;
        int srow = rs & 2047;
        int bh = rs >> 11;
        int b = bh >> 3, h = bh & 7;
        int t = b * 2048 + srow;
        const short* src = qcrb + (size_t)t * 768 + h * 96;
        float val;
        if (d < 64) {
            val = b2f(src[d]);
        } else {
            int d2 = d - 64;
            int fi = d2 & 15;
            float ang = (float)srow * __expf(-((float)(2 * fi) / 32.f) * 9.210340371976184f);
            float s, c; __sincosf(ang, &s, &c);
            float x = b2f(src[64 + d2]);
            float r = (d2 < 16) ? -b2f(src[64 + d2 + 16]) : b2f(src[64 + d2 - 16]);
            val = x * c + r * s;
        }
        qb[gid] = f2b(val * scale);
    } else if (gid < 2 * NQ) {
        int g2 = gid - NQ;
        int d = g2 % 96;
        int rs = g2 / 96;
        int srow = rs & 2047;
        int bh = rs >> 11;
        int b = bh >> 3, h = bh & 7;
        int t = b * 2048 + srow;
        if (d < 64) {
            kb[g2] = kvbb[(size_t)t * 1024 + h * 128 + d];
        } else {
            int d2 = d - 64;
            int fi = d2 & 15;
            float ang = (float)srow * __expf(-((float)(2 * fi) / 32.f) * 9.210340371976184f);
            float s, c; __sincosf(ang, &s, &c);
            float x = cqkv[(size_t)t * 416 + 384 + d2];
            float r = (d2 < 16) ? -cqkv[(size_t)t * 416 + 384 + d2 + 16]
                                :  cqkv[(size_t)t * 416 + 384 + d2 - 16];
            kb[g2] = f2b(x * c + r * s);
        }
    } else {
        int g2 = gid - 2 * NQ;   // 16*64*2048
        int key = g2 & 2047;
        int dim = (g2 >> 11) & 63;
        int bh = g2 >> 17;
        int b = bh >> 3, h = bh & 7;
        vbt[g2] = kvbb[(size_t)(b * 2048 + key) * 1024 + h * 128 + 64 + dim];
    }
}

// ---------------- K-split(4) MFMA flash attention, 32 q/wave, MFMA denominator ----------------
__global__ __launch_bounds__(256)
void k_attn(const short* __restrict__ qb, const short* __restrict__ kb,
            const short* __restrict__ vbt, short* __restrict__ po, float* __restrict__ pl) {
    __shared__ __align__(16) short Ks[64 * 100];
    __shared__ __align__(16) short Vs[80 * 64];
    int tid = threadIdx.x;
    int w = tid >> 6, l = tid & 63, g = l >> 4, li = l & 15;
    int blk = blockIdx.x;
    int bh = blk >> 6, rem = blk & 63;
    int qt = rem >> 2, ks = rem & 3;
    int qc0 = qt * 128 + w * 32;

    {
        const short one = 0x3F80;  // bf16 1.0
        for (int i = tid; i < 16 * 64; i += 256)
            Vs[64 * 64 + i] = (i < 64) ? one : (short)0;
    }

    s16x8 qf[2][3];
#pragma unroll
    for (int j = 0; j < 2; ++j) {
        const short* qp = qb + (size_t)(bh * 2048 + qc0 + j * 16 + li) * 96;
#pragma unroll
        for (int c = 0; c < 3; ++c) qf[j][c] = *(const s16x8*)(qp + 32 * c + 8 * g);
    }

    f32x4 o[2][5] = {};
    const short* kbase = kb + (size_t)bh * 2048 * 96;
    const short* vbase = vbt + (size_t)bh * 64 * 2048;

    for (int t = 0; t < 8; ++t) {
        int koff = ks * 512 + t * 64;
        __syncthreads();
#pragma unroll
        for (int p = 0; p < 3; ++p) {
            int flat = p * 256 + tid;
            int key = flat / 12, u = flat % 12;
            *(int4*)&Ks[key * 100 + 8 * u] = *(const int4*)(kbase + (size_t)(koff + key) * 96 + 8 * u);
        }
#pragma unroll
        for (int p = 0; p < 2; ++p) {
            int flat = p * 256 + tid;
            int dim = flat >> 3, kc8 = flat & 7;
            int4 v = *(const int4*)(vbase + (size_t)dim * 2048 + koff + 8 * kc8);
            int sw = dim & 15;
            *(int2*)&Vs[dim * 64 + (((2 * kc8) ^ sw) * 4)]     = make_int2(v.x, v.y);
            *(int2*)&Vs[dim * 64 + (((2 * kc8 + 1) ^ sw) * 4)] = make_int2(v.z, v.w);
        }
        __syncthreads();

        f32x4 s[2][4];
#pragma unroll
        for (int kt = 0; kt < 4; ++kt) {
            f32x4 a0 = {}, a1 = {};
#pragma unroll
            for (int c = 0; c < 3; ++c) {
                s16x8 kf = *(const s16x8*)&Ks[(kt * 16 + li) * 100 + 32 * c + 8 * g];
                a0 = __builtin_amdgcn_mfma_f32_16x16x32_bf16(kf, qf[0][c], a0, 0, 0, 0);
                a1 = __builtin_amdgcn_mfma_f32_16x16x32_bf16(kf, qf[1][c], a1, 0, 0, 0);
            }
            s[0][kt] = a0; s[1][kt] = a1;
        }
#pragma unroll
        for (int j = 0; j < 2; ++j)
#pragma unroll
            for (int kt = 0; kt < 4; ++kt)
#pragma unroll
                for (int r = 0; r < 4; ++r) s[j][kt][r] = exp2f(s[j][kt][r]);
        s16x8 pf[2][2];
#pragma unroll
        for (int j = 0; j < 2; ++j)
#pragma unroll
            for (int kc = 0; kc < 2; ++kc) {
                s16x8 tt;
#pragma unroll
                for (int r = 0; r < 4; ++r) { tt[r] = f2b(s[j][2 * kc][r]); tt[4 + r] = f2b(s[j][2 * kc + 1][r]); }
                pf[j][kc] = tt;
            }
#pragma unroll
        for (int dt = 0; dt < 5; ++dt) {
            int dim = dt * 16 + li;
#pragma unroll
            for (int kc = 0; kc < 2; ++kc) {
                int2 a0 = *(const int2*)&Vs[dim * 64 + (((8 * kc + g) ^ li) * 4)];
                int2 a1 = *(const int2*)&Vs[dim * 64 + (((8 * kc + 4 + g) ^ li) * 4)];
                union { s16x8 v; int i[4]; } vf;
                vf.i[0] = a0.x; vf.i[1] = a0.y; vf.i[2] = a1.x; vf.i[3] = a1.y;
                o[0][dt] = __builtin_amdgcn_mfma_f32_16x16x32_bf16(vf.v, pf[0][kc], o[0][dt], 0, 0, 0);
                o[1][dt] = __builtin_amdgcn_mfma_f32_16x16x32_bf16(vf.v, pf[1][kc], o[1][dt], 0, 0, 0);
            }
        }
    }
#pragma unroll
    for (int j = 0; j < 2; ++j) {
        int qcol = qc0 + j * 16 + li;
        size_t qbase = ((size_t)(bh * 2048 + qcol) * 4 + ks) * 64;
#pragma unroll
        for (int dt = 0; dt < 4; ++dt) {
            union { short s[4]; int2 v; } pk;
#pragma unroll
            for (int r = 0; r < 4; ++r) pk.s[r] = f2b(o[j][dt][r]);
            *(int2*)(po + qbase + dt * 16 + 4 * g) = pk.v;
        }
        if (g == 0) pl[(size_t)(bh * 2048 + qcol) * 4 + ks] = o[j][4][0];
    }
}

// ---------------- scatter: block-aggregated expert list build ----------------
__global__ __launch_bounds__(256)
void k_scatter(const int4* __restrict__ toke, const float4* __restrict__ tokw,
               float* __restrict__ ewt, int* __restrict__ ecnt, int* __restrict__ etok) {
    __shared__ int lcnt[16];
    __shared__ int lbase[16];
    int tid = threadIdx.x;
    int t = blockIdx.x * 256 + tid;
    if (tid < 16) lcnt[tid] = 0;
    __syncthreads();
    int4 e4 = toke[t];
    float4 w4 = tokw[t];
    int es[4] = { e4.x, e4.y, e4.z, e4.w };
    float wv[4] = { w4.x, w4.y, w4.z, w4.w };
    int ls[4];
#pragma unroll
    for (int kk = 0; kk < 4; ++kk) ls[kk] = atomicAdd(&lcnt[es[kk]], 1);
    __syncthreads();
    if (tid < 16) lbase[tid] = atomicAdd(&ecnt[tid], lcnt[tid]);
    __syncthreads();
#pragma unroll
    for (int kk = 0; kk < 4; ++kk) {
        int slot = lbase[es[kk]] + ls[kk];
        etok[es[kk] * 4096 + slot] = t * 4 + kk;
        ewt[es[kk] * 4096 + slot] = wv[kk];
    }
}

// ---------------- MoE stage 1 (MFMA, 8 waves, inline tile-scan): eact = silu(x@wg)*(x@wu) --------
__global__ __launch_bounds__(512)
void k_moe1m(const short* __restrict__ X, const short* __restrict__ WGt, const short* __restrict__ WUt,
             const int* __restrict__ ecnt, const int* __restrict__ etok, short* __restrict__ eact) {
    __shared__ int ecs[16];
    __shared__ __align__(16) short As[128 * 64];
    __shared__ __align__(16) short Bg[64 * 64];
    __shared__ __align__(16) short Bu[64 * 64];
    __shared__ int toks[128];
    int tid = threadIdx.x;
    if (tid < 16) ecs[tid] = ecnt[tid];
    __syncthreads();
    int bid = blockIdx.x, e = 0;
    for (; e < 16; ++e) { int n = (ecs[e] + 127) >> 7; if (bid < n) break; bid -= n; }
    if (e >= 16) return;
    int base = bid << 7;
    int rows = min(128, ecs[e] - base);
    int n0 = blockIdx.y * 64;
    if (tid < 128) toks[tid] = (tid < rows) ? etok[e * 4096 + base + tid] : -1;
    __syncthreads();
    int w = tid >> 6, l = tid & 63, g = l >> 4, li = l & 15;
    int wm = w >> 1, wn = w & 1;
    const short* wgp = WGt + (size_t)e * 256 * 512;
    const short* wup = WUt + (size_t)e * 256 * 512;
    f32x4 ag[2][2] = {}, au[2][2] = {};
    for (int k0 = 0; k0 < 512; k0 += 64) {
        __syncthreads();
#pragma unroll
        for (int p = 0; p < 2; ++p) {
            int flat = p * 512 + tid;
            int row = flat >> 3, ch = flat & 7;
            int tk = toks[row];
            int4 v = {0, 0, 0, 0};
            if (tk >= 0) v = *(const int4*)(X + (size_t)(tk >> 2) * 512 + k0 + 8 * ch);
            *(int4*)&As[row * 64 + ((ch ^ (row & 7)) * 8)] = v;
        }
        {
            int n = tid >> 3, ch = tid & 7;
            *(int4*)&Bg[n * 64 + ((ch ^ (n & 7)) * 8)] = *(const int4*)(wgp + (size_t)(n0 + n) * 512 + k0 + 8 * ch);
            *(int4*)&Bu[n * 64 + ((ch ^ (n & 7)) * 8)] = *(const int4*)(wup + (size_t)(n0 + n) * 512 + k0 + 8 * ch);
        }
        __syncthreads();
#pragma unroll
        for (int kc = 0; kc < 2; ++kc) {
            s16x8 af[2], bg[2], bu[2];
#pragma unroll
            for (int mt = 0; mt < 2; ++mt) {
                int row = wm * 32 + mt * 16 + li;
                af[mt] = *(const s16x8*)&As[row * 64 + (((4 * kc + g) ^ (li & 7)) * 8)];
            }
#pragma unroll
            for (int nt = 0; nt < 2; ++nt) {
                int n = wn * 32 + nt * 16 + li;
                bg[nt] = *(const s16x8*)&Bg[n * 64 + (((4 * kc + g) ^ (li & 7)) * 8)];
                bu[nt] = *(const s16x8*)&Bu[n * 64 + (((4 * kc + g) ^ (li & 7)) * 8)];
            }
#pragma unroll
            for (int mt = 0; mt < 2; ++mt)
#pragma unroll
                for (int nt = 0; nt < 2; ++nt) {
                    ag[mt][nt] = __builtin_amdgcn_mfma_f32_16x16x32_bf16(af[mt], bg[nt], ag[mt][nt], 0, 0, 0);
                    au[mt][nt] = __builtin_amdgcn_mfma_f32_16x16x32_bf16(af[mt], bu[nt], au[mt][nt], 0, 0, 0);
                }
        }
    }
#pragma unroll
    for (int mt = 0; mt < 2; ++mt)
#pragma unroll
        for (int nt = 0; nt < 2; ++nt)
#pragma unroll
            for (int r = 0; r < 4; ++r) {
                int local = wm * 32 + mt * 16 + 4 * g + r;
                if (local < rows) {
                    int entry = toks[local];
                    int gn = n0 + wn * 32 + nt * 16 + li;
                    float gv = ag[mt][nt][r], uv = au[mt][nt][r];
                    eact[(size_t)entry * 256 + gn] = f2b(gv / (1.f + __expf(-gv)) * uv);
                }
            }
}

// ---------------- MoE stage 2 (MFMA, 8 waves, inline tile-scan): out += w * (eact @ wd) ----------
__global__ __launch_bounds__(512)
void k_moe2m(const short* __restrict__ EA, const short* __restrict__ WDt,
             const int* __restrict__ ecnt, const int* __restrict__ etok,
             const float* __restrict__ ewt, float* __restrict__ oacc) {
    __shared__ int ecs[16];
    __shared__ __align__(16) short As[128 * 64];
    __shared__ __align__(16) short Bs[64 * 64];
    __shared__ int toks[128];
    __shared__ float wts[128];
    int tid = threadIdx.x;
    if (tid < 16) ecs[tid] = ecnt[tid];
    __syncthreads();
    int bid = blockIdx.x, e = 0;
    for (; e < 16; ++e) { int n = (ecs[e] + 127) >> 7; if (bid < n) break; bid -= n; }
    if (e >= 16) return;
    int base = bid << 7;
    int rows = min(128, ecs[e] - base);
    int n0 = blockIdx.y * 64;
    if (tid < 128) {
        toks[tid] = (tid < rows) ? etok[e * 4096 + base + tid] : -1;
        wts[tid]  = (tid < rows) ? ewt[e * 4096 + base + tid] : 0.f;
    }
    __syncthreads();
    int w = tid >> 6, l = tid & 63, g = l >> 4, li = l & 15;
    int wm = w >> 1, wn = w & 1;
    const short* wdp = WDt + (size_t)e * 512 * 256;
    f32x4 acc[2][2] = {};
    for (int k0 = 0; k0 < 256; k0 += 64) {
        __syncthreads();
#pragma unroll
        for (int p = 0; p < 2; ++p) {
            int flat = p * 512 + tid;
            int row = flat >> 3, ch = flat & 7;
            int tk = toks[row];
            int4 v = {0, 0, 0, 0};
            if (tk >= 0) v = *(const int4*)(EA + (size_t)tk * 256 + k0 + 8 * ch);
            *(int4*)&As[row * 64 + ((ch ^ (row & 7)) * 8)] = v;
        }
        {
            int n = tid >> 3, ch = tid & 7;
            *(int4*)&Bs[n * 64 + ((ch ^ (n & 7)) * 8)] = *(const int4*)(wdp + (size_t)(n0 + n) * 256 + k0 + 8 * ch);
        }
        __syncthreads();
#pragma unroll
        for (int kc = 0; kc < 2; ++kc) {
            s16x8 af[2], bf[2];
#pragma unroll
            for (int mt = 0; mt < 2; ++mt) {
                int row = wm * 32 + mt * 16 + li;
                af[mt] = *(const s16x8*)&As[row * 64 + (((4 * kc + g) ^ (li & 7)) * 8)];
            }
#pragma unroll
            for (int nt = 0; nt < 2; ++nt) {
                int n = wn * 32 + nt * 16 + li;
                bf[nt] = *(const s16x8*)&Bs[n * 64 + (((4 * kc + g) ^ (li & 7)) * 8)];
            }
#pragma unroll
            for (int mt = 0; mt < 2; ++mt)
#pragma unroll
                for (int nt = 0; nt < 2; ++nt)
                    acc[mt][nt] = __builtin_amdgcn_mfma_f32_16x16x32_bf16(af[mt], bf[nt], acc[mt][nt], 0, 0, 0);
        }
    }
#pragma unroll
    for (int mt = 0; mt < 2; ++mt)
#pragma unroll
        for (int nt = 0; nt < 2; ++nt)
#pragma unroll
            for (int r = 0; r < 4; ++r) {
                int local = wm * 32 + mt * 16 + 4 * g + r;
                if (local < rows) {
                    int tok = toks[local] >> 2;
                    int gn = n0 + wn * 32 + nt * 16 + li;
                    atomicAdd(&oacc[(size_t)tok * 512 + gn], acc[mt][nt][r] * wts[local]);
                }
            }
}

// ---------------- host launcher ----------------
extern "C" void kernel_launch(void* const* d_in, const int* in_sizes, int n_in,
                              void* d_out, int out_size, void* d_ws, size_t ws_size,
                              hipStream_t stream) {
    const float* hs       = (const float*)d_in[0];
    const float* w_innorm = (const float*)d_in[1];
    const float* w_dq     = (const float*)d_in[2];
    const float* w_qnorm  = (const float*)d_in[3];
    const float* w_uq     = (const float*)d_in[4];
    const float* w_dkv    = (const float*)d_in[5];
    const float* w_kvnorm = (const float*)d_in[6];
    const float* w_ukv    = (const float*)d_in[7];
    const float* w_o      = (const float*)d_in[8];
    const float* w_post   = (const float*)d_in[9];
    const float* w_gate   = (const float*)d_in[10];
    const float* sh_wg    = (const float*)d_in[11];
    const float* sh_wu    = (const float*)d_in[12];
    const float* sh_wd    = (const float*)d_in[13];
    const float* r_wg     = (const float*)d_in[14];
    const float* r_wu     = (const float*)d_in[15];
    const float* r_wd     = (const float*)d_in[16];

    float* ws   = (float*)d_ws;
    float* cqkv = ws + OFF_CQKV;
    short* qcrb = (short*)(ws + OFF_QCR);
    short* kvbb = (short*)(ws + OFF_KVB);
    float* r2   = ws + OFF_R2;
    short* po   = (short*)(ws + OFF_PO);
    float* pl   = ws + OFF_PL;
    int4*  toke = (int4*)(ws + OFF_TOKE);
    float4* tokw = (float4*)(ws + OFF_TOKW);
    float* ewt  = ws + OFF_EWT;
    int*   ecnt = (int*)(ws + OFF_ECNT);
    int*   etok = (int*)(ws + OFF_ETOK);
    short* xnb   = (short*)(ws + OFF_XNB);
    short* cqnb  = (short*)(ws + OFF_CQNB);
    short* ckvnb = (short*)(ws + OFF_CKVNB);
    short* qb    = (short*)(ws + OFF_QB);
    short* kb    = (short*)(ws + OFF_KB);
    short* vbt   = (short*)(ws + OFF_VBT);
    short* xn2b  = (short*)(ws + OFF_XN2B);
    short* gact  = (short*)(ws + OFF_GACT);
    short* eact  = (short*)(ws + OFF_EACT);
    short* wqkvT = (short*)(ws + OFF_WQKVT);
    short* wuqT  = (short*)(ws + OFF_WUQT);
    short* wukvT = (short*)(ws + OFF_WUKVT);
    short* woT   = (short*)(ws + OFF_WOT);
    short* shwgT = (short*)(ws + OFF_SHWGT);
    short* shwuT = (short*)(ws + OFF_SHWUT);
    short* shwdT = (short*)(ws + OFF_SHWDT);
    short* rwgT  = (short*)(ws + OFF_RWGT);
    short* rwuT  = (short*)(ws + OFF_RWUT);
    short* rwdT  = (short*)(ws + OFF_RWDT);

    float* outF = (float*)d_out;

    // 0. fused weight convert+transpose (bf16 [N][K])
    CvtTab tab;
    const float* srcs[11] = { w_dq, w_dkv, w_uq, w_ukv, w_o, sh_wg, sh_wu, sh_wd, r_wg, r_wu, r_wd };
    short* dsts[11] = { wqkvT, wqkvT + (size_t)256 * 512, wuqT, wukvT, woT, shwgT, shwuT, shwdT, rwgT, rwuT, rwdT };
    int Ks_[11] = { 512, 512, 256, 128, 512, 512, 512, 256, 512, 512, 256 };
    int Ns_[11] = { 256, 160, 768, 1024, 512, 256, 256, 512, 256, 256, 512 };
    int Es_[11] = { 1, 1, 1, 1, 1, 1, 1, 1, 16, 16, 16 };
    int cum = 0;
    for (int i = 0; i < 11; ++i) {
        tab.src[i] = srcs[i]; tab.dst[i] = dsts[i];
        tab.K[i] = Ks_[i]; tab.N[i] = Ns_[i];
        cum += Es_[i] * (Ks_[i] >> 5) * (Ns_[i] >> 5);
        tab.end[i] = cum;
    }
    k_cvt_all<<<cum, 256, 0, stream>>>(tab);

    // 1. input RMSNorm -> bf16 (also zeroes ecnt)
    k_rms<<<Tt, 256, 0, stream>>>(hs, 512, w_innorm, xnb, 512, 512, ecnt);
    // 2. fused down-projection (dq|dkv), N=416, f32 out
    k_mgemm<0><<<dim3(7, 64), 512, 0, stream>>>(xnb, wqkvT, (void*)cqkv, nullptr, 416, 512);
    // 3. fused latent norms -> bf16
    k_rms2<<<2 * Tt, 256, 0, stream>>>(cqkv, w_qnorm, cqnb, w_kvnorm, ckvnb);
    // 4. up-projections -> bf16 directly
    k_mgemm<2><<<dim3(12, 64), 512, 0, stream>>>(cqnb, wuqT, (void*)qcrb, nullptr, 768, 256);
    k_mgemm<2><<<dim3(16, 64), 512, 0, stream>>>(ckvnb, wukvT, (void*)kvbb, nullptr, 1024, 128);
    // 5. fused q/k/v build (RoPE, Q pre-scaled incl log2e; bf16 inputs)
    k_build_qkv<<<(2 * 16 * 2048 * 96 + 16 * 64 * 2048) / 256, 256, 0, stream>>>(qcrb, kvbb, cqkv, qb, kb, vbt);
    // 6. K-split(4) MFMA flash attention (32 q/wave, MFMA denominator)
    k_attn<<<1024, 256, 0, stream>>>(qb, kb, vbt, po, pl);
    // 7. wo projection fused with partial combine + residual
    k_wo_gemm<<<dim3(8, 64), 512, 0, stream>>>(po, pl, woT, r2, hs);
    // 8. fused post-norm + router
    k_rms_router<<<Tt, 256, 0, stream>>>(r2, w_post, w_gate, xn2b, toke, tokw);
    // 9. shared expert then down-proj + residual into d_out
    k_shexp<<<dim3(64, 4), 512, 0, stream>>>(xn2b, shwgT, shwuT, gact);
    k_mgemm<1><<<dim3(8, 64), 512, 0, stream>>>(gact, shwdT, (void*)outF, r2, 512, 256);
    // 10. scatter + MoE (inline tile-scan)
    k_scatter<<<16, 256, 0, stream>>>(toke, tokw, ewt, ecnt, etok);
    k_moe1m<<<dim3(144, 4), 512, 0, stream>>>(xn2b, rwgT, rwuT, ecnt, etok, eact);
    k_moe2m<<<dim3(144, 8), 512, 0, stream>>>(eact, rwdT, ecnt, etok, ewt, outF);
}

// Round 19
// 217.994 us; speedup vs baseline: 1.1094x; 1.0442x over previous
//
#include <hip/hip_runtime.h>
#include <hip/hip_bf16.h>
#include <math.h>

typedef float f32x4 __attribute__((ext_vector_type(4)));
typedef short s16x8 __attribute__((ext_vector_type(8)));

// ---------------- problem constants ----------------
constexpr int Tt = 4096;
constexpr int NEn = 16;
constexpr float EPSf = 1.1920929e-07f;

__device__ __forceinline__ short f2b(float f) {
    union { __hip_bfloat16 h; short s; } u;
    u.h = __float2bfloat16(f);
    return u.s;
}
__device__ __forceinline__ float b2f(short s) {
    union { float f; unsigned u; } v;
    v.u = ((unsigned)(unsigned short)s) << 16;
    return v.f;
}

// ---------------- workspace layout (float elements, 16-float aligned) ----------------
constexpr size_t alg(size_t x) { return (x + 15) & ~(size_t)15; }
// f32 buffers (region [0, OFF_R2) is reused for attention partials after build)
constexpr size_t OFF_CQKV = 0;                                   // T*416 f32 (cq 0..255 | ckv 256..415)
constexpr size_t OFF_QCR  = alg(OFF_CQKV + (size_t)Tt * 416);    // T*768 bf16 (rope sections only)
constexpr size_t OFF_KVB  = alg(OFF_QCR  + (size_t)Tt * 768);    // (unused now; kept for layout stability)
constexpr size_t OFF_R2   = alg(OFF_KVB  + (size_t)Tt * 1024);   // T*512 f32
constexpr size_t OFF_TOKE = alg(OFF_R2   + (size_t)Tt * 512);    // T*4 ints
constexpr size_t OFF_TOKW = alg(OFF_TOKE + (size_t)Tt * 4);      // T*4 f32
constexpr size_t OFF_EWT  = alg(OFF_TOKW + (size_t)Tt * 4);      // 16*4096 f32
constexpr size_t OFF_ECNT = alg(OFF_EWT  + (size_t)NEn * Tt);    // ints
constexpr size_t OFF_ETOK = alg(OFF_ECNT + 64);                  // 16*4096 ints
// attention partials ALIAS dead CQKV/QCR/KVB region (dead after k_build_rope):
constexpr size_t OFF_PO   = 0;                                   // bf16 16*2048*4*64 = 4,194,304 float-slots
constexpr size_t OFF_PL   = (size_t)16 * 2048 * 4 * 64 / 2;      // f32 131,072
// bf16 buffers (element counts halved into float units)
constexpr size_t OFF_XNB   = alg(OFF_ETOK + (size_t)NEn * Tt);       // T*512 bf16
constexpr size_t OFF_CQNB  = alg(OFF_XNB   + (size_t)Tt * 512 / 2);  // T*256 bf16
constexpr size_t OFF_CKVNB = alg(OFF_CQNB  + (size_t)Tt * 256 / 2);  // T*128 bf16
constexpr size_t OFF_QB    = alg(OFF_CKVNB + (size_t)Tt * 128 / 2);  // 16*2048*96 bf16
constexpr size_t OFF_KB    = alg(OFF_QB    + (size_t)16 * 2048 * 96 / 2);
constexpr size_t OFF_VBT   = alg(OFF_KB    + (size_t)16 * 2048 * 96 / 2); // 16*64*2048 bf16
constexpr size_t OFF_XN2B  = alg(OFF_VBT   + (size_t)16 * 64 * 2048 / 2);
constexpr size_t OFF_GACT  = alg(OFF_XN2B  + (size_t)Tt * 512 / 2);  // T*256 bf16
constexpr size_t OFF_EACT  = alg(OFF_GACT  + (size_t)Tt * 256 / 2);  // 16384*256 bf16
// transposed bf16 weights [N][K]
constexpr size_t OFF_WQKVT = alg(OFF_EACT  + (size_t)16384 * 256 / 2); // 416*512
constexpr size_t OFF_WUQT  = alg(OFF_WQKVT + (size_t)416 * 512 / 2);
constexpr size_t OFF_WUKVT = alg(OFF_WUQT  + (size_t)768 * 256 / 2);
constexpr size_t OFF_WOT   = alg(OFF_WUKVT + (size_t)1024 * 128 / 2);
constexpr size_t OFF_SHWGT = alg(OFF_WOT   + (size_t)512 * 512 / 2);
constexpr size_t OFF_SHWUT = alg(OFF_SHWGT + (size_t)256 * 512 / 2);
constexpr size_t OFF_SHWDT = alg(OFF_SHWUT + (size_t)256 * 512 / 2);
constexpr size_t OFF_RWGT  = alg(OFF_SHWDT + (size_t)512 * 256 / 2);
constexpr size_t OFF_RWUT  = alg(OFF_RWGT  + (size_t)16 * 256 * 512 / 2);
constexpr size_t OFF_RWDT  = alg(OFF_RWUT  + (size_t)16 * 256 * 512 / 2);

// ---------------- fused convert + transpose (all weights, one launch) ----------------
struct CvtTab {
    const float* src[11];
    short* dst[11];
    int K[11], N[11], end[11];
};
__global__ __launch_bounds__(256)
void k_cvt_all(CvtTab tab) {
    __shared__ float t[32][33];
    int bid = blockIdx.x;
    int i = 0;
    while (bid >= tab.end[i]) ++i;
    int tloc = bid - (i ? tab.end[i - 1] : 0);
    int K = tab.K[i], N = tab.N[i];
    int ntiles = N >> 5, perE = ntiles * (K >> 5);
    int e = tloc / perE, rem = tloc - e * perE;
    int k0 = (rem / ntiles) << 5, n0 = (rem % ntiles) << 5;
    size_t eo = (size_t)e * K * N;
    const float* src = tab.src[i];
    short* dst = tab.dst[i];
    int c = threadIdx.x & 31, r = threadIdx.x >> 5;
#pragma unroll
    for (int q = 0; q < 4; ++q)
        t[r + 8 * q][c] = src[eo + (size_t)(k0 + r + 8 * q) * N + n0 + c];
    __syncthreads();
#pragma unroll
    for (int q = 0; q < 4; ++q)
        dst[eo + (size_t)(n0 + r + 8 * q) * K + k0 + c] = f2b(t[c][r + 8 * q]);
}

// ---------------- RMSNorm f32 in -> bf16 out (also zeroes ecnt for later scatter) ---------------
__global__ void k_rms(const float* __restrict__ in, int inStride, const float* __restrict__ w,
                      short* __restrict__ outB, int outStride, int D, int* __restrict__ ecnt) {
    int row = blockIdx.x, tid = threadIdx.x;
    if (row == 0 && tid < 16) ecnt[tid] = 0;
    __shared__ float xs[512];
    __shared__ float red[256];
    const float* ip = in + (size_t)row * inStride;
    float ss = 0.f;
    for (int i = tid; i < D; i += 256) { float v = ip[i]; xs[i] = v; ss += v * v; }
    red[tid] = ss; __syncthreads();
    for (int s = 128; s > 0; s >>= 1) { if (tid < s) red[tid] += red[tid + s]; __syncthreads(); }
    float sc = rsqrtf(red[0] / (float)D + EPSf);
    for (int i = tid; i < D; i += 256) outB[(size_t)row * outStride + i] = f2b(xs[i] * sc * w[i]);
}

// ---------------- fused latent RMSNorm pair over cqkv[4096][416] ----------------
__global__ void k_rms2(const float* __restrict__ cqkv, const float* __restrict__ wq, short* __restrict__ cqnb,
                       const float* __restrict__ wkv, short* __restrict__ ckvnb) {
    int row = blockIdx.x, tid = threadIdx.x;
    __shared__ float xs[256];
    __shared__ float red[256];
    const float* ip; const float* w; short* ob; int D, outStride, r;
    if (row < Tt) { r = row;      ip = cqkv + (size_t)r * 416;       w = wq;  ob = cqnb;  D = 256; outStride = 256; }
    else          { r = row - Tt; ip = cqkv + (size_t)r * 416 + 256; w = wkv; ob = ckvnb; D = 128; outStride = 128; }
    float ss = 0.f;
    for (int i = tid; i < D; i += 256) { float v = ip[i]; xs[i] = v; ss += v * v; }
    red[tid] = ss; __syncthreads();
    for (int s = 128; s > 0; s >>= 1) { if (tid < s) red[tid] += red[tid + s]; __syncthreads(); }
    float sc = rsqrtf(red[0] / (float)D + EPSf);
    for (int i = tid; i < D; i += 256) ob[(size_t)r * outStride + i] = f2b(xs[i] * sc * w[i]);
}

// ---------------- fused post-RMSNorm + router ----------------
__global__ __launch_bounds__(256)
void k_rms_router(const float* __restrict__ r2, const float* __restrict__ wpost,
                  const float* __restrict__ wg,
                  short* __restrict__ xn2b, int4* __restrict__ toke, float4* __restrict__ tokw) {
    int t = blockIdx.x, tid = threadIdx.x;
    __shared__ float xs[512];
    __shared__ float red[256];
    __shared__ float part[16][17];
    __shared__ float sc[16];
    const float* ip = r2 + (size_t)t * 512;
    float ss = 0.f;
    for (int i = tid; i < 512; i += 256) { float v = ip[i]; xs[i] = v; ss += v * v; }
    red[tid] = ss; __syncthreads();
    for (int s = 128; s > 0; s >>= 1) { if (tid < s) red[tid] += red[tid + s]; __syncthreads(); }
    float scale = rsqrtf(red[0] / 512.f + EPSf);
    for (int i = tid; i < 512; i += 256) {
        float v = xs[i] * scale * wpost[i];
        xs[i] = v;
        xn2b[(size_t)t * 512 + i] = f2b(v);
    }
    __syncthreads();
    {
        int e = tid & 15, ch = tid >> 4;
        const float* wp = wg + (size_t)ch * 32 * 16 + e;
        float s = 0.f;
#pragma unroll 8
        for (int k = 0; k < 32; ++k) s = fmaf(xs[ch * 32 + k], wp[(size_t)k * 16], s);
        part[ch][e] = s;
    }
    __syncthreads();
    if (tid < 16) {
        float s = 0.f;
#pragma unroll
        for (int c = 0; c < 16; ++c) s += part[c][tid];
        sc[tid] = 1.f / (1.f + expf(-s));
    }
    __syncthreads();
    if (tid < 64) {
        int lane = tid, e = lane & 15;
        float scv = sc[e];
        unsigned sel = 0;
        float tw[4]; int ti[4];
#pragma unroll
        for (int kk = 0; kk < 4; ++kk) {
            float cand = ((sel >> e) & 1u) ? -1e30f : scv;
            float mx = cand;
            mx = fmaxf(mx, __shfl_xor(mx, 1));
            mx = fmaxf(mx, __shfl_xor(mx, 2));
            mx = fmaxf(mx, __shfl_xor(mx, 4));
            mx = fmaxf(mx, __shfl_xor(mx, 8));
            unsigned long long msk = __ballot(cand == mx);
            int bi = (__ffsll(msk) - 1) & 15;
            tw[kk] = mx; ti[kk] = bi;
            sel |= 1u << bi;
        }
        if (lane == 0) {
            float inv = 1.f / (tw[0] + tw[1] + tw[2] + tw[3]);
            toke[t] = make_int4(ti[0], ti[1], ti[2], ti[3]);
            tokw[t] = make_float4(tw[0] * inv, tw[1] * inv, tw[2] * inv, tw[3] * inv);
        }
    }
}

// ---------------- MFMA GEMM (64x64 tile, 8 waves) ----------------
// EPI 0 = f32 out, 1 = f32+residual, 2 = bf16 out,
// EPI 3 = ukv scatter: gn=h*128+dd; dd<64 -> kb (aux), dd>=64 -> vbt transposed (aux2)
// EPI 4 = uq scatter:  gn=h*96+dd;  dd<64 -> qb*scale (aux), dd>=64 -> qcrb (Cv)
template <int EPI>
__global__ __launch_bounds__(512)
void k_mgemm(const short* __restrict__ A, const short* __restrict__ BT,
             void* __restrict__ Cv, const float* __restrict__ add, int N, int K,
             short* __restrict__ aux, short* __restrict__ aux2) {
    __shared__ __align__(16) short As[64 * 64];
    __shared__ __align__(16) short Bs[64 * 64];
    int tid = threadIdx.x;
    int w = tid >> 6, l = tid & 63, g = l >> 4, li = l & 15;
    int wm = w >> 1, wn = w & 1;
    int m0 = blockIdx.y * 64, n0 = blockIdx.x * 64;
    f32x4 acc[2] = {};
    for (int k0 = 0; k0 < K; k0 += 64) {
        __syncthreads();
        {
            int row = tid >> 3, ch = tid & 7;
            *(int4*)&As[row * 64 + ((ch ^ (row & 7)) * 8)] =
                *(const int4*)(A + (size_t)(m0 + row) * K + k0 + 8 * ch);
            int4 v = {0, 0, 0, 0};
            if (n0 + row < N) v = *(const int4*)(BT + (size_t)(n0 + row) * K + k0 + 8 * ch);
            *(int4*)&Bs[row * 64 + ((ch ^ (row & 7)) * 8)] = v;
        }
        __syncthreads();
#pragma unroll
        for (int kc = 0; kc < 2; ++kc) {
            int row = wm * 16 + li;
            s16x8 af = *(const s16x8*)&As[row * 64 + (((4 * kc + g) ^ (li & 7)) * 8)];
#pragma unroll
            for (int nt = 0; nt < 2; ++nt) {
                int n = wn * 32 + nt * 16 + li;
                s16x8 bf = *(const s16x8*)&Bs[n * 64 + (((4 * kc + g) ^ (li & 7)) * 8)];
                acc[nt] = __builtin_amdgcn_mfma_f32_16x16x32_bf16(af, bf, acc[nt], 0, 0, 0);
            }
        }
    }
#pragma unroll
    for (int nt = 0; nt < 2; ++nt)
#pragma unroll
        for (int r = 0; r < 4; ++r) {
            int gm = m0 + wm * 16 + 4 * g + r;
            int gn = n0 + wn * 32 + nt * 16 + li;
            if (gn < N) {
                float v = acc[nt][r];
                if (EPI == 1) {
                    ((float*)Cv)[(size_t)gm * N + gn] = v + add[(size_t)gm * N + gn];
                } else if (EPI == 2) {
                    ((short*)Cv)[(size_t)gm * N + gn] = f2b(v);
                } else if (EPI == 3) {
                    int h = gn >> 7, dd = gn & 127;
                    int b = gm >> 11, srow = gm & 2047;
                    int bh = b * 8 + h;
                    if (dd < 64)
                        aux[((size_t)(bh * 2048 + srow)) * 96 + dd] = f2b(v);
                    else
                        aux2[(size_t)bh * 64 * 2048 + (size_t)(dd - 64) * 2048 + srow] = f2b(v);
                } else if (EPI == 4) {
                    int h = gn / 96, dd = gn - h * 96;
                    int b = gm >> 11, srow = gm & 2047;
                    int bh = b * 8 + h;
                    if (dd < 64)
                        aux[((size_t)(bh * 2048 + srow)) * 96 + dd] = f2b(v * 0.14724389f);
                    else
                        ((short*)Cv)[(size_t)gm * N + gn] = f2b(v);
                } else {
                    ((float*)Cv)[(size_t)gm * N + gn] = v;
                }
            }
        }
}

// ---------------- wo projection fused with attention partial combine ----------------
__global__ __launch_bounds__(512)
void k_wo_gemm(const short* __restrict__ po, const float* __restrict__ pl,
               const short* __restrict__ BT, float* __restrict__ C,
               const float* __restrict__ add) {
    constexpr int N = 512, K = 512;
    __shared__ __align__(16) short As[64 * 64];
    __shared__ __align__(16) short Bs[64 * 64];
    int tid = threadIdx.x;
    int w = tid >> 6, l = tid & 63, g = l >> 4, li = l & 15;
    int wm = w >> 1, wn = w & 1;
    int m0 = blockIdx.y * 64, n0 = blockIdx.x * 64;
    int row = tid >> 3, ch = tid & 7;
    int t = m0 + row;
    int b = t >> 11, q = t & 2047;
    f32x4 acc[2] = {};
    for (int k0 = 0; k0 < K; k0 += 64) {
        int h = k0 >> 6;
        int bhq = (b * 8 + h) * 2048 + q;
        size_t pb = (size_t)bhq * 256 + 8 * ch;
        float4 l4 = *(const float4*)(pl + (size_t)bhq * 4);
        float inv = 1.f / (l4.x + l4.y + l4.z + l4.w);
        union { int4 v; short s[8]; } p0, p1, p2, p3, ov;
        p0.v = *(const int4*)(po + pb);
        p1.v = *(const int4*)(po + pb + 64);
        p2.v = *(const int4*)(po + pb + 128);
        p3.v = *(const int4*)(po + pb + 192);
#pragma unroll
        for (int i = 0; i < 8; ++i) {
            float os = b2f(p0.s[i]) + b2f(p1.s[i]) + b2f(p2.s[i]) + b2f(p3.s[i]);
            ov.s[i] = f2b(os * inv);
        }
        int4 bv = *(const int4*)(BT + (size_t)(n0 + row) * K + k0 + 8 * ch);
        __syncthreads();
        *(int4*)&As[row * 64 + ((ch ^ (row & 7)) * 8)] = ov.v;
        *(int4*)&Bs[row * 64 + ((ch ^ (row & 7)) * 8)] = bv;
        __syncthreads();
#pragma unroll
        for (int kc = 0; kc < 2; ++kc) {
            int rr = wm * 16 + li;
            s16x8 af = *(const s16x8*)&As[rr * 64 + (((4 * kc + g) ^ (li & 7)) * 8)];
#pragma unroll
            for (int nt = 0; nt < 2; ++nt) {
                int n = wn * 32 + nt * 16 + li;
                s16x8 bf = *(const s16x8*)&Bs[n * 64 + (((4 * kc + g) ^ (li & 7)) * 8)];
                acc[nt] = __builtin_amdgcn_mfma_f32_16x16x32_bf16(af, bf, acc[nt], 0, 0, 0);
            }
        }
    }
#pragma unroll
    for (int nt = 0; nt < 2; ++nt)
#pragma unroll
        for (int r = 0; r < 4; ++r) {
            int gm = m0 + wm * 16 + 4 * g + r;
            int gn = n0 + wn * 32 + nt * 16 + li;
            C[(size_t)gm * N + gn] = acc[nt][r] + add[(size_t)gm * N + gn];
        }
}

// ---------------- shared expert (64x64 tile, 8 waves): gact = silu(x@wg)*(x@wu) ----------------
__global__ __launch_bounds__(512)
void k_shexp(const short* __restrict__ X, const short* __restrict__ WGt, const short* __restrict__ WUt,
             short* __restrict__ gact) {
    __shared__ __align__(16) short As[64 * 64];
    __shared__ __align__(16) short Bg[64 * 64];
    __shared__ __align__(16) short Bu[64 * 64];
    int tid = threadIdx.x;
    int w = tid >> 6, l = tid & 63, g = l >> 4, li = l & 15;
    int wm = w >> 1, wn = w & 1;
    int m0 = blockIdx.x * 64, n0 = blockIdx.y * 64;
    f32x4 ag[2] = {}, au[2] = {};
    for (int k0 = 0; k0 < 512; k0 += 64) {
        __syncthreads();
        {
            int row = tid >> 3, ch = tid & 7;
            *(int4*)&As[row * 64 + ((ch ^ (row & 7)) * 8)] =
                *(const int4*)(X + (size_t)(m0 + row) * 512 + k0 + 8 * ch);
            *(int4*)&Bg[row * 64 + ((ch ^ (row & 7)) * 8)] =
                *(const int4*)(WGt + (size_t)(n0 + row) * 512 + k0 + 8 * ch);
            *(int4*)&Bu[row * 64 + ((ch ^ (row & 7)) * 8)] =
                *(const int4*)(WUt + (size_t)(n0 + row) * 512 + k0 + 8 * ch);
        }
        __syncthreads();
#pragma unroll
        for (int kc = 0; kc < 2; ++kc) {
            int row = wm * 16 + li;
            s16x8 af = *(const s16x8*)&As[row * 64 + (((4 * kc + g) ^ (li & 7)) * 8)];
#pragma unroll
            for (int nt = 0; nt < 2; ++nt) {
                int n = wn * 32 + nt * 16 + li;
                s16x8 bg = *(const s16x8*)&Bg[n * 64 + (((4 * kc + g) ^ (li & 7)) * 8)];
                s16x8 bu = *(const s16x8*)&Bu[n * 64 + (((4 * kc + g) ^ (li & 7)) * 8)];
                ag[nt] = __builtin_amdgcn_mfma_f32_16x16x32_bf16(af, bg, ag[nt], 0, 0, 0);
                au[nt] = __builtin_amdgcn_mfma_f32_16x16x32_bf16(af, bu, au[nt], 0, 0, 0);
            }
        }
    }
#pragma unroll
    for (int nt = 0; nt < 2; ++nt)
#pragma unroll
        for (int r = 0; r < 4; ++r) {
            int gm = m0 + wm * 16 + 4 * g + r;
            int gn = n0 + wn * 32 + nt * 16 + li;
            float gv = ag[nt][r], uv = au[nt][r];
            gact[(size_t)gm * 256 + gn] = f2b(gv / (1.f + __expf(-gv)) * uv);
        }
}

// ---------------- rope-only build: q-rope from qcrb, k-rope from cqkv ----------------
__global__ void k_build_rope(const short* __restrict__ qcrb, const float* __restrict__ cqkv,
                             short* __restrict__ qb, short* __restrict__ kb) {
    const float scale = 0.14724389f;  // log2(e)/sqrt(96)
    int gid = blockIdx.x * 256 + threadIdx.x;
    const int NR = 16 * 2048 * 32;    // 1,048,576 rope elements each for q and k
    if (gid < NR) {
        int d2 = gid & 31;
        int rs = gid >> 5;
        int srow = rs & 2047;
        int bh = rs >> 11;
        int b = bh >> 3, h = bh & 7;
        int t = b * 2048 + srow;
        const short* src = qcrb + (size_t)t * 768 + h * 96;
        int fi = d2 & 15;
        float ang = (float)srow * __expf(-((float)(2 * fi) / 32.f) * 9.210340371976184f);
        float s, c; __sincosf(ang, &s, &c);
        float x = b2f(src[64 + d2]);
        float r = (d2 < 16) ? -b2f(src[64 + d2 + 16]) : b2f(src[64 + d2 - 16]);
        qb[((size_t)(bh * 2048 + srow)) * 96 + 64 + d2] = f2b((x * c + r * s) * scale);
    } else {
        int g2 = gid - NR;
        int d2 = g2 & 31;
        int rs = g2 >> 5;
        int srow = rs & 2047;
        int bh = rs >> 11;
        int b = bh >> 3;
        int t = b * 2048 + srow;
        int fi = d2 & 15;
        float ang = (float)srow * __expf(-((float)(2 * fi) / 32.f) * 9.210340371976184f);
        float s, c; __sincosf(ang, &s, &c);
        float x = cqkv[(size_t)t * 416 + 384 + d2];
        float r = (d2 < 16) ? -cqkv[(size_t)t * 416 + 384 + d2 + 16]
                            :  cqkv[(size_t)t * 416 + 384 + d2 - 16];
        kb[((size_t)(bh * 2048 + srow)) * 96 + 64 + d2] = f2b(x * c + r * s);
    }
}

// ---------------- K-split(4) MFMA flash attention, 32 q/wave, MFMA denominator ----------------
__global__ __launch_bounds__(256)
void k_attn(const short* __restrict__ qb, const short* __restrict__ kb,
            const short* __restrict__ vbt, short* __restrict__ po, float* __restrict__ pl) {
    __shared__ __align__(16) short Ks[64 * 100];
    __shared__ __align__(16) short Vs[80 * 64];
    int tid = threadIdx.x;
    int w = tid >> 6, l = tid & 63, g = l >> 4, li = l & 15;
    int blk = blockIdx.x;
    int bh = blk >> 6, rem = blk & 63;
    int qt = rem >> 2, ks = rem & 3;
    int qc0 = qt * 128 + w * 32;

    {
        const short one = 0x3F80;  // bf16 1.0
        for (int i = tid; i < 16 * 64; i += 256)
            Vs[64 * 64 + i] = (i < 64) ? one : (short)0;
    }

    s16x8 qf[2][3];
#pragma unroll
    for (int j = 0; j < 2; ++j) {
        const short* qp = qb + (size_t)(bh * 2048 + qc0 + j * 16 + li) * 96;
#pragma unroll
        for (int c = 0; c < 3; ++c) qf[j][c] = *(const s16x8*)(qp + 32 * c + 8 * g);
    }

    f32x4 o[2][5] = {};
    const short* kbase = kb + (size_t)bh * 2048 * 96;
    const short* vbase = vbt + (size_t)bh * 64 * 2048;

    for (int t = 0; t < 8; ++t) {
        int koff = ks * 512 + t * 64;
        __syncthreads();
#pragma unroll
        for (int p = 0; p < 3; ++p) {
            int flat = p * 256 + tid;
            int key = flat / 12, u = flat % 12;
            *(int4*)&Ks[key * 100 + 8 * u] = *(const int4*)(kbase + (size_t)(koff + key) * 96 + 8 * u);
        }
#pragma unroll
        for (int p = 0; p < 2; ++p) {
            int flat = p * 256 + tid;
            int dim = flat >> 3, kc8 = flat & 7;
            int4 v = *(const int4*)(vbase + (size_t)dim * 2048 + koff + 8 * kc8);
            int sw = dim & 15;
            *(int2*)&Vs[dim * 64 + (((2 * kc8) ^ sw) * 4)]     = make_int2(v.x, v.y);
            *(int2*)&Vs[dim * 64 + (((2 * kc8 + 1) ^ sw) * 4)] = make_int2(v.z, v.w);
        }
        __syncthreads();

        f32x4 s[2][4];
#pragma unroll
        for (int kt = 0; kt < 4; ++kt) {
            f32x4 a0 = {}, a1 = {};
#pragma unroll
            for (int c = 0; c < 3; ++c) {
                s16x8 kf = *(const s16x8*)&Ks[(kt * 16 + li) * 100 + 32 * c + 8 * g];
                a0 = __builtin_amdgcn_mfma_f32_16x16x32_bf16(kf, qf[0][c], a0, 0, 0, 0);
                a1 = __builtin_amdgcn_mfma_f32_16x16x32_bf16(kf, qf[1][c], a1, 0, 0, 0);
            }
            s[0][kt] = a0; s[1][kt] = a1;
        }
#pragma unroll
        for (int j = 0; j < 2; ++j)
#pragma unroll
            for (int kt = 0; kt < 4; ++kt)
#pragma unroll
                for (int r = 0; r < 4; ++r) s[j][kt][r] = exp2f(s[j][kt][r]);
        s16x8 pf[2][2];
#pragma unroll
        for (int j = 0; j < 2; ++j)
#pragma unroll
            for (int kc = 0; kc < 2; ++kc) {
                s16x8 tt;
#pragma unroll
                for (int r = 0; r < 4; ++r) { tt[r] = f2b(s[j][2 * kc][r]); tt[4 + r] = f2b(s[j][2 * kc + 1][r]); }
                pf[j][kc] = tt;
            }
#pragma unroll
        for (int dt = 0; dt < 5; ++dt) {
            int dim = dt * 16 + li;
#pragma unroll
            for (int kc = 0; kc < 2; ++kc) {
                int2 a0 = *(const int2*)&Vs[dim * 64 + (((8 * kc + g) ^ li) * 4)];
                int2 a1 = *(const int2*)&Vs[dim * 64 + (((8 * kc + 4 + g) ^ li) * 4)];
                union { s16x8 v; int i[4]; } vf;
                vf.i[0] = a0.x; vf.i[1] = a0.y; vf.i[2] = a1.x; vf.i[3] = a1.y;
                o[0][dt] = __builtin_amdgcn_mfma_f32_16x16x32_bf16(vf.v, pf[0][kc], o[0][dt], 0, 0, 0);
                o[1][dt] = __builtin_amdgcn_mfma_f32_16x16x32_bf16(vf.v, pf[1][kc], o[1][dt], 0, 0, 0);
            }
        }
    }
#pragma unroll
    for (int j = 0; j < 2; ++j) {
        int qcol = qc0 + j * 16 + li;
        size_t qbase = ((size_t)(bh * 2048 + qcol) * 4 + ks) * 64;
#pragma unroll
        for (int dt = 0; dt < 4; ++dt) {
            union { short s[4]; int2 v; } pk;
#pragma unroll
            for (int r = 0; r < 4; ++r) pk.s[r] = f2b(o[j][dt][r]);
            *(int2*)(po + qbase + dt * 16 + 4 * g) = pk.v;
        }
        if (g == 0) pl[(size_t)(bh * 2048 + qcol) * 4 + ks] = o[j][4][0];
    }
}

// ---------------- scatter: block-aggregated expert list build ----------------
__global__ __launch_bounds__(256)
void k_scatter(const int4* __restrict__ toke, const float4* __restrict__ tokw,
               float* __restrict__ ewt, int* __restrict__ ecnt, int* __restrict__ etok) {
    __shared__ int lcnt[16];
    __shared__ int lbase[16];
    int tid = threadIdx.x;
    int t = blockIdx.x * 256 + tid;
    if (tid < 16) lcnt[tid] = 0;
    __syncthreads();
    int4 e4 = toke[t];
    float4 w4 = tokw[t];
    int es[4] = { e4.x, e4.y, e4.z, e4.w };
    float wv[4] = { w4.x, w4.y, w4.z, w4.w };
    int ls[4];
#pragma unroll
    for (int kk = 0; kk < 4; ++kk) ls[kk] = atomicAdd(&lcnt[es[kk]], 1);
    __syncthreads();
    if (tid < 16) lbase[tid] = atomicAdd(&ecnt[tid], lcnt[tid]);
    __syncthreads();
#pragma unroll
    for (int kk = 0; kk < 4; ++kk) {
        int slot = lbase[es[kk]] + ls[kk];
        etok[es[kk] * 4096 + slot] = t * 4 + kk;
        ewt[es[kk] * 4096 + slot] = wv[kk];
    }
}

// ---------------- MoE stage 1 (MFMA, 8 waves, inline tile-scan): eact = silu(x@wg)*(x@wu) --------
__global__ __launch_bounds__(512)
void k_moe1m(const short* __restrict__ X, const short* __restrict__ WGt, const short* __restrict__ WUt,
             const int* __restrict__ ecnt, const int* __restrict__ etok, short* __restrict__ eact) {
    __shared__ int ecs[16];
    __shared__ __align__(16) short As[128 * 64];
    __shared__ __align__(16) short Bg[64 * 64];
    __shared__ __align__(16) short Bu[64 * 64];
    __shared__ int toks[128];
    int tid = threadIdx.x;
    if (tid < 16) ecs[tid] = ecnt[tid];
    __syncthreads();
    int bid = blockIdx.x, e = 0;
    for (; e < 16; ++e) { int n = (ecs[e] + 127) >> 7; if (bid < n) break; bid -= n; }
    if (e >= 16) return;
    int base = bid << 7;
    int rows = min(128, ecs[e] - base);
    int n0 = blockIdx.y * 64;
    if (tid < 128) toks[tid] = (tid < rows) ? etok[e * 4096 + base + tid] : -1;
    __syncthreads();
    int w = tid >> 6, l = tid & 63, g = l >> 4, li = l & 15;
    int wm = w >> 1, wn = w & 1;
    const short* wgp = WGt + (size_t)e * 256 * 512;
    const short* wup = WUt + (size_t)e * 256 * 512;
    f32x4 ag[2][2] = {}, au[2][2] = {};
    for (int k0 = 0; k0 < 512; k0 += 64) {
        __syncthreads();
#pragma unroll
        for (int p = 0; p < 2; ++p) {
            int flat = p * 512 + tid;
            int row = flat >> 3, ch = flat & 7;
            int tk = toks[row];
            int4 v = {0, 0, 0, 0};
            if (tk >= 0) v = *(const int4*)(X + (size_t)(tk >> 2) * 512 + k0 + 8 * ch);
            *(int4*)&As[row * 64 + ((ch ^ (row & 7)) * 8)] = v;
        }
        {
            int n = tid >> 3, ch = tid & 7;
            *(int4*)&Bg[n * 64 + ((ch ^ (n & 7)) * 8)] = *(const int4*)(wgp + (size_t)(n0 + n) * 512 + k0 + 8 * ch);
            *(int4*)&Bu[n * 64 + ((ch ^ (n & 7)) * 8)] = *(const int4*)(wup + (size_t)(n0 + n) * 512 + k0 + 8 * ch);
        }
        __syncthreads();
#pragma unroll
        for (int kc = 0; kc < 2; ++kc) {
            s16x8 af[2], bg[2], bu[2];
#pragma unroll
            for (int mt = 0; mt < 2; ++mt) {
                int row = wm * 32 + mt * 16 + li;
                af[mt] = *(const s16x8*)&As[row * 64 + (((4 * kc + g) ^ (li & 7)) * 8)];
            }
#pragma unroll
            for (int nt = 0; nt < 2; ++nt) {
                int n = wn * 32 + nt * 16 + li;
                bg[nt] = *(const s16x8*)&Bg[n * 64 + (((4 * kc + g) ^ (li & 7)) * 8)];
                bu[nt] = *(const s16x8*)&Bu[n * 64 + (((4 * kc + g) ^ (li & 7)) * 8)];
            }
#pragma unroll
            for (int mt = 0; mt < 2; ++mt)
#pragma unroll
                for (int nt = 0; nt < 2; ++nt) {
                    ag[mt][nt] = __builtin_amdgcn_mfma_f32_16x16x32_bf16(af[mt], bg[nt], ag[mt][nt], 0, 0, 0);
                    au[mt][nt] = __builtin_amdgcn_mfma_f32_16x16x32_bf16(af[mt], bu[nt], au[mt][nt], 0, 0, 0);
                }
        }
    }
#pragma unroll
    for (int mt = 0; mt < 2; ++mt)
#pragma unroll
        for (int nt = 0; nt < 2; ++nt)
#pragma unroll
            for (int r = 0; r < 4; ++r) {
                int local = wm * 32 + mt * 16 + 4 * g + r;
                if (local < rows) {
                    int entry = toks[local];
                    int gn = n0 + wn * 32 + nt * 16 + li;
                    float gv = ag[mt][nt][r], uv = au[mt][nt][r];
                    eact[(size_t)entry * 256 + gn] = f2b(gv / (1.f + __expf(-gv)) * uv);
                }
            }
}

// ---------------- MoE stage 2 (MFMA, 8 waves, inline tile-scan): out += w * (eact @ wd) ----------
__global__ __launch_bounds__(512)
void k_moe2m(const short* __restrict__ EA, const short* __restrict__ WDt,
             const int* __restrict__ ecnt, const int* __restrict__ etok,
             const float* __restrict__ ewt, float* __restrict__ oacc) {
    __shared__ int ecs[16];
    __shared__ __align__(16) short As[128 * 64];
    __shared__ __align__(16) short Bs[64 * 64];
    __shared__ int toks[128];
    __shared__ float wts[128];
    int tid = threadIdx.x;
    if (tid < 16) ecs[tid] = ecnt[tid];
    __syncthreads();
    int bid = blockIdx.x, e = 0;
    for (; e < 16; ++e) { int n = (ecs[e] + 127) >> 7; if (bid < n) break; bid -= n; }
    if (e >= 16) return;
    int base = bid << 7;
    int rows = min(128, ecs[e] - base);
    int n0 = blockIdx.y * 64;
    if (tid < 128) {
        toks[tid] = (tid < rows) ? etok[e * 4096 + base + tid] : -1;
        wts[tid]  = (tid < rows) ? ewt[e * 4096 + base + tid] : 0.f;
    }
    __syncthreads();
    int w = tid >> 6, l = tid & 63, g = l >> 4, li = l & 15;
    int wm = w >> 1, wn = w & 1;
    const short* wdp = WDt + (size_t)e * 512 * 256;
    f32x4 acc[2][2] = {};
    for (int k0 = 0; k0 < 256; k0 += 64) {
        __syncthreads();
#pragma unroll
        for (int p = 0; p < 2; ++p) {
            int flat = p * 512 + tid;
            int row = flat >> 3, ch = flat & 7;
            int tk = toks[row];
            int4 v = {0, 0, 0, 0};
            if (tk >= 0) v = *(const int4*)(EA + (size_t)tk * 256 + k0 + 8 * ch);
            *(int4*)&As[row * 64 + ((ch ^ (row & 7)) * 8)] = v;
        }
        {
            int n = tid >> 3, ch = tid & 7;
            *(int4*)&Bs[n * 64 + ((ch ^ (n & 7)) * 8)] = *(const int4*)(wdp + (size_t)(n0 + n) * 256 + k0 + 8 * ch);
        }
        __syncthreads();
#pragma unroll
        for (int kc = 0; kc < 2; ++kc) {
            s16x8 af[2], bf[2];
#pragma unroll
            for (int mt = 0; mt < 2; ++mt) {
                int row = wm * 32 + mt * 16 + li;
                af[mt] = *(const s16x8*)&As[row * 64 + (((4 * kc + g) ^ (li & 7)) * 8)];
            }
#pragma unroll
            for (int nt = 0; nt < 2; ++nt) {
                int n = wn * 32 + nt * 16 + li;
                bf[nt] = *(const s16x8*)&Bs[n * 64 + (((4 * kc + g) ^ (li & 7)) * 8)];
            }
#pragma unroll
            for (int mt = 0; mt < 2; ++mt)
#pragma unroll
                for (int nt = 0; nt < 2; ++nt)
                    acc[mt][nt] = __builtin_amdgcn_mfma_f32_16x16x32_bf16(af[mt], bf[nt], acc[mt][nt], 0, 0, 0);
        }
    }
#pragma unroll
    for (int mt = 0; mt < 2; ++mt)
#pragma unroll
        for (int nt = 0; nt < 2; ++nt)
#pragma unroll
            for (int r = 0; r < 4; ++r) {
                int local = wm * 32 + mt * 16 + 4 * g + r;
                if (local < rows) {
                    int tok = toks[local] >> 2;
                    int gn = n0 + wn * 32 + nt * 16 + li;
                    atomicAdd(&oacc[(size_t)tok * 512 + gn], acc[mt][nt][r] * wts[local]);
                }
            }
}

// ---------------- host launcher ----------------
extern "C" void kernel_launch(void* const* d_in, const int* in_sizes, int n_in,
                              void* d_out, int out_size, void* d_ws, size_t ws_size,
                              hipStream_t stream) {
    const float* hs       = (const float*)d_in[0];
    const float* w_innorm = (const float*)d_in[1];
    const float* w_dq     = (const float*)d_in[2];
    const float* w_qnorm  = (const float*)d_in[3];
    const float* w_uq     = (const float*)d_in[4];
    const float* w_dkv    = (const float*)d_in[5];
    const float* w_kvnorm = (const float*)d_in[6];
    const float* w_ukv    = (const float*)d_in[7];
    const float* w_o      = (const float*)d_in[8];
    const float* w_post   = (const float*)d_in[9];
    const float* w_gate   = (const float*)d_in[10];
    const float* sh_wg    = (const float*)d_in[11];
    const float* sh_wu    = (const float*)d_in[12];
    const float* sh_wd    = (const float*)d_in[13];
    const float* r_wg     = (const float*)d_in[14];
    const float* r_wu     = (const float*)d_in[15];
    const float* r_wd     = (const float*)d_in[16];

    float* ws   = (float*)d_ws;
    float* cqkv = ws + OFF_CQKV;
    short* qcrb = (short*)(ws + OFF_QCR);
    float* r2   = ws + OFF_R2;
    short* po   = (short*)(ws + OFF_PO);
    float* pl   = ws + OFF_PL;
    int4*  toke = (int4*)(ws + OFF_TOKE);
    float4* tokw = (float4*)(ws + OFF_TOKW);
    float* ewt  = ws + OFF_EWT;
    int*   ecnt = (int*)(ws + OFF_ECNT);
    int*   etok = (int*)(ws + OFF_ETOK);
    short* xnb   = (short*)(ws + OFF_XNB);
    short* cqnb  = (short*)(ws + OFF_CQNB);
    short* ckvnb = (short*)(ws + OFF_CKVNB);
    short* qb    = (short*)(ws + OFF_QB);
    short* kb    = (short*)(ws + OFF_KB);
    short* vbt   = (short*)(ws + OFF_VBT);
    short* xn2b  = (short*)(ws + OFF_XN2B);
    short* gact  = (short*)(ws + OFF_GACT);
    short* eact  = (short*)(ws + OFF_EACT);
    short* wqkvT = (short*)(ws + OFF_WQKVT);
    short* wuqT  = (short*)(ws + OFF_WUQT);
    short* wukvT = (short*)(ws + OFF_WUKVT);
    short* woT   = (short*)(ws + OFF_WOT);
    short* shwgT = (short*)(ws + OFF_SHWGT);
    short* shwuT = (short*)(ws + OFF_SHWUT);
    short* shwdT = (short*)(ws + OFF_SHWDT);
    short* rwgT  = (short*)(ws + OFF_RWGT);
    short* rwuT  = (short*)(ws + OFF_RWUT);
    short* rwdT  = (short*)(ws + OFF_RWDT);

    float* outF = (float*)d_out;

    // 0. fused weight convert+transpose (bf16 [N][K])
    CvtTab tab;
    const float* srcs[11] = { w_dq, w_dkv, w_uq, w_ukv, w_o, sh_wg, sh_wu, sh_wd, r_wg, r_wu, r_wd };
    short* dsts[11] = { wqkvT, wqkvT + (size_t)256 * 512, wuqT, wukvT, woT, shwgT, shwuT, shwdT, rwgT, rwuT, rwdT };
    int Ks_[11] = { 512, 512, 256, 128, 512, 512, 512, 256, 512, 512, 256 };
    int Ns_[11] = { 256, 160, 768, 1024, 512, 256, 256, 512, 256, 256, 512 };
    int Es_[11] = { 1, 1, 1, 1, 1, 1, 1, 1, 16, 16, 16 };
    int cum = 0;
    for (int i = 0; i < 11; ++i) {
        tab.src[i] = srcs[i]; tab.dst[i] = dsts[i];
        tab.K[i] = Ks_[i]; tab.N[i] = Ns_[i];
        cum += Es_[i] * (Ks_[i] >> 5) * (Ns_[i] >> 5);
        tab.end[i] = cum;
    }
    k_cvt_all<<<cum, 256, 0, stream>>>(tab);

    // 1. input RMSNorm -> bf16 (also zeroes ecnt)
    k_rms<<<Tt, 256, 0, stream>>>(hs, 512, w_innorm, xnb, 512, 512, ecnt);
    // 2. fused down-projection (dq|dkv), N=416, f32 out
    k_mgemm<0><<<dim3(7, 64), 512, 0, stream>>>(xnb, wqkvT, (void*)cqkv, nullptr, 416, 512, nullptr, nullptr);
    // 3. fused latent norms -> bf16
    k_rms2<<<2 * Tt, 256, 0, stream>>>(cqkv, w_qnorm, cqnb, w_kvnorm, ckvnb);
    // 4. up-projections: uq scatters q-copy (scaled) to qb + rope part to qcrb;
    //    ukv scatters K-copy to kb and V (transposed) to vbt
    k_mgemm<4><<<dim3(12, 64), 512, 0, stream>>>(cqnb, wuqT, (void*)qcrb, nullptr, 768, 256, qb, nullptr);
    k_mgemm<3><<<dim3(16, 64), 512, 0, stream>>>(ckvnb, wukvT, nullptr, nullptr, 1024, 128, kb, vbt);
    // 5. rope-only build (q-rope from qcrb, k-rope from cqkv)
    k_build_rope<<<(2 * 16 * 2048 * 32) / 256, 256, 0, stream>>>(qcrb, cqkv, qb, kb);
    // 6. K-split(4) MFMA flash attention (32 q/wave, MFMA denominator)
    k_attn<<<1024, 256, 0, stream>>>(qb, kb, vbt, po, pl);
    // 7. wo projection fused with partial combine + residual
    k_wo_gemm<<<dim3(8, 64), 512, 0, stream>>>(po, pl, woT, r2, hs);
    // 8. fused post-norm + router
    k_rms_router<<<Tt, 256, 0, stream>>>(r2, w_post, w_gate, xn2b, toke, tokw);
    // 9. shared expert then down-proj + residual into d_out
    k_shexp<<<dim3(64, 4), 512, 0, stream>>>(xn2b, shwgT, shwuT, gact);
    k_mgemm<1><<<dim3(8, 64), 512, 0, stream>>>(gact, shwdT, (void*)outF, r2, 512, 256, nullptr, nullptr);
    // 10. scatter + MoE (inline tile-scan)
    k_scatter<<<16, 256, 0, stream>>>(toke, tokw, ewt, ecnt, etok);
    k_moe1m<<<dim3(144, 4), 512, 0, stream>>>(xn2b, rwgT, rwuT, ecnt, etok, eact);
    k_moe2m<<<dim3(144, 8), 512, 0, stream>>>(eact, rwdT, ecnt, etok, ewt, outF);
}

// Round 20
// 215.975 us; speedup vs baseline: 1.1197x; 1.0093x over previous
//
#include <hip/hip_runtime.h>
#include <hip/hip_bf16.h>
#include <math.h>

typedef float f32x4 __attribute__((ext_vector_type(4)));
typedef short s16x8 __attribute__((ext_vector_type(8)));

// ---------------- problem constants ----------------
constexpr int Tt = 4096;
constexpr int NEn = 16;
constexpr float EPSf = 1.1920929e-07f;

__device__ __forceinline__ short f2b(float f) {
    union { __hip_bfloat16 h; short s; } u;
    u.h = __float2bfloat16(f);
    return u.s;
}
__device__ __forceinline__ float b2f(short s) {
    union { float f; unsigned u; } v;
    v.u = ((unsigned)(unsigned short)s) << 16;
    return v.f;
}

// ---------------- workspace layout (float elements, 16-float aligned) ----------------
constexpr size_t alg(size_t x) { return (x + 15) & ~(size_t)15; }
// f32 buffers (region [0, OFF_R2) is reused for attention partials after build)
constexpr size_t OFF_CQKV = 0;                                   // T*416 f32 (cq 0..255 | ckv 256..415)
constexpr size_t OFF_QCR  = alg(OFF_CQKV + (size_t)Tt * 416);    // T*768 bf16 (rope sections only)
constexpr size_t OFF_KVB  = alg(OFF_QCR  + (size_t)Tt * 768);    // (unused; kept for layout stability)
constexpr size_t OFF_R2   = alg(OFF_KVB  + (size_t)Tt * 1024);   // T*512 f32
constexpr size_t OFF_TOKE = alg(OFF_R2   + (size_t)Tt * 512);    // T*4 ints
constexpr size_t OFF_TOKW = alg(OFF_TOKE + (size_t)Tt * 4);      // T*4 f32
constexpr size_t OFF_EWT  = alg(OFF_TOKW + (size_t)Tt * 4);      // 16*4096 f32
constexpr size_t OFF_ECNT = alg(OFF_EWT  + (size_t)NEn * Tt);    // ints
constexpr size_t OFF_ETOK = alg(OFF_ECNT + 64);                  // 16*4096 ints
// attention partials ALIAS dead CQKV/QCR/KVB region (dead after k_build_rope):
constexpr size_t OFF_PO   = 0;                                   // bf16 16*2048*4*64 = 4,194,304 float-slots
constexpr size_t OFF_PL   = (size_t)16 * 2048 * 4 * 64 / 2;      // f32 131,072
// bf16 buffers (element counts halved into float units)
constexpr size_t OFF_XNB   = alg(OFF_ETOK + (size_t)NEn * Tt);       // T*512 bf16
constexpr size_t OFF_CQNB  = alg(OFF_XNB   + (size_t)Tt * 512 / 2);  // T*256 bf16
constexpr size_t OFF_CKVNB = alg(OFF_CQNB  + (size_t)Tt * 256 / 2);  // T*128 bf16
constexpr size_t OFF_QB    = alg(OFF_CKVNB + (size_t)Tt * 128 / 2);  // 16*2048*96 bf16
constexpr size_t OFF_KB    = alg(OFF_QB    + (size_t)16 * 2048 * 96 / 2);
constexpr size_t OFF_VBT   = alg(OFF_KB    + (size_t)16 * 2048 * 96 / 2); // 16*64*2048 bf16
constexpr size_t OFF_XN2B  = alg(OFF_VBT   + (size_t)16 * 64 * 2048 / 2);
constexpr size_t OFF_GACT  = alg(OFF_XN2B  + (size_t)Tt * 512 / 2);  // T*256 bf16
constexpr size_t OFF_EACT  = alg(OFF_GACT  + (size_t)Tt * 256 / 2);  // 16384*256 bf16
// transposed bf16 weights [N][K]
constexpr size_t OFF_WQKVT = alg(OFF_EACT  + (size_t)16384 * 256 / 2); // 416*512
constexpr size_t OFF_WUQT  = alg(OFF_WQKVT + (size_t)416 * 512 / 2);
constexpr size_t OFF_WUKVT = alg(OFF_WUQT  + (size_t)768 * 256 / 2);
constexpr size_t OFF_WOT   = alg(OFF_WUKVT + (size_t)1024 * 128 / 2);
constexpr size_t OFF_SHWGT = alg(OFF_WOT   + (size_t)512 * 512 / 2);
constexpr size_t OFF_SHWUT = alg(OFF_SHWGT + (size_t)256 * 512 / 2);
constexpr size_t OFF_SHWDT = alg(OFF_SHWUT + (size_t)256 * 512 / 2);
constexpr size_t OFF_RWGT  = alg(OFF_SHWDT + (size_t)512 * 256 / 2);
constexpr size_t OFF_RWUT  = alg(OFF_RWGT  + (size_t)16 * 256 * 512 / 2);
constexpr size_t OFF_RWDT  = alg(OFF_RWUT  + (size_t)16 * 256 * 512 / 2);

// ---------------- fused convert + transpose (all weights, one launch) ----------------
struct CvtTab {
    const float* src[11];
    short* dst[11];
    int K[11], N[11], end[11];
};
__global__ __launch_bounds__(256)
void k_cvt_all(CvtTab tab) {
    __shared__ float t[32][33];
    int bid = blockIdx.x;
    int i = 0;
    while (bid >= tab.end[i]) ++i;
    int tloc = bid - (i ? tab.end[i - 1] : 0);
    int K = tab.K[i], N = tab.N[i];
    int ntiles = N >> 5, perE = ntiles * (K >> 5);
    int e = tloc / perE, rem = tloc - e * perE;
    int k0 = (rem / ntiles) << 5, n0 = (rem % ntiles) << 5;
    size_t eo = (size_t)e * K * N;
    const float* src = tab.src[i];
    short* dst = tab.dst[i];
    int c = threadIdx.x & 31, r = threadIdx.x >> 5;
#pragma unroll
    for (int q = 0; q < 4; ++q)
        t[r + 8 * q][c] = src[eo + (size_t)(k0 + r + 8 * q) * N + n0 + c];
    __syncthreads();
#pragma unroll
    for (int q = 0; q < 4; ++q)
        dst[eo + (size_t)(n0 + r + 8 * q) * K + k0 + c] = f2b(t[c][r + 8 * q]);
}

// ---------------- RMSNorm f32 in -> bf16 out (also zeroes ecnt for later scatter) ---------------
__global__ void k_rms(const float* __restrict__ in, int inStride, const float* __restrict__ w,
                      short* __restrict__ outB, int outStride, int D, int* __restrict__ ecnt) {
    int row = blockIdx.x, tid = threadIdx.x;
    if (row == 0 && tid < 16) ecnt[tid] = 0;
    __shared__ float xs[512];
    __shared__ float red[256];
    const float* ip = in + (size_t)row * inStride;
    float ss = 0.f;
    for (int i = tid; i < D; i += 256) { float v = ip[i]; xs[i] = v; ss += v * v; }
    red[tid] = ss; __syncthreads();
    for (int s = 128; s > 0; s >>= 1) { if (tid < s) red[tid] += red[tid + s]; __syncthreads(); }
    float sc = rsqrtf(red[0] / (float)D + EPSf);
    for (int i = tid; i < D; i += 256) outB[(size_t)row * outStride + i] = f2b(xs[i] * sc * w[i]);
}

// ---------------- fused latent RMSNorm pair over cqkv[4096][416] ----------------
__global__ void k_rms2(const float* __restrict__ cqkv, const float* __restrict__ wq, short* __restrict__ cqnb,
                       const float* __restrict__ wkv, short* __restrict__ ckvnb) {
    int row = blockIdx.x, tid = threadIdx.x;
    __shared__ float xs[256];
    __shared__ float red[256];
    const float* ip; const float* w; short* ob; int D, outStride, r;
    if (row < Tt) { r = row;      ip = cqkv + (size_t)r * 416;       w = wq;  ob = cqnb;  D = 256; outStride = 256; }
    else          { r = row - Tt; ip = cqkv + (size_t)r * 416 + 256; w = wkv; ob = ckvnb; D = 128; outStride = 128; }
    float ss = 0.f;
    for (int i = tid; i < D; i += 256) { float v = ip[i]; xs[i] = v; ss += v * v; }
    red[tid] = ss; __syncthreads();
    for (int s = 128; s > 0; s >>= 1) { if (tid < s) red[tid] += red[tid + s]; __syncthreads(); }
    float sc = rsqrtf(red[0] / (float)D + EPSf);
    for (int i = tid; i < D; i += 256) ob[(size_t)r * outStride + i] = f2b(xs[i] * sc * w[i]);
}

// ---------------- fused post-RMSNorm + router ----------------
__global__ __launch_bounds__(256)
void k_rms_router(const float* __restrict__ r2, const float* __restrict__ wpost,
                  const float* __restrict__ wg,
                  short* __restrict__ xn2b, int4* __restrict__ toke, float4* __restrict__ tokw) {
    int t = blockIdx.x, tid = threadIdx.x;
    __shared__ float xs[512];
    __shared__ float red[256];
    __shared__ float part[16][17];
    __shared__ float sc[16];
    const float* ip = r2 + (size_t)t * 512;
    float ss = 0.f;
    for (int i = tid; i < 512; i += 256) { float v = ip[i]; xs[i] = v; ss += v * v; }
    red[tid] = ss; __syncthreads();
    for (int s = 128; s > 0; s >>= 1) { if (tid < s) red[tid] += red[tid + s]; __syncthreads(); }
    float scale = rsqrtf(red[0] / 512.f + EPSf);
    for (int i = tid; i < 512; i += 256) {
        float v = xs[i] * scale * wpost[i];
        xs[i] = v;
        xn2b[(size_t)t * 512 + i] = f2b(v);
    }
    __syncthreads();
    {
        int e = tid & 15, ch = tid >> 4;
        const float* wp = wg + (size_t)ch * 32 * 16 + e;
        float s = 0.f;
#pragma unroll 8
        for (int k = 0; k < 32; ++k) s = fmaf(xs[ch * 32 + k], wp[(size_t)k * 16], s);
        part[ch][e] = s;
    }
    __syncthreads();
    if (tid < 16) {
        float s = 0.f;
#pragma unroll
        for (int c = 0; c < 16; ++c) s += part[c][tid];
        sc[tid] = 1.f / (1.f + expf(-s));
    }
    __syncthreads();
    if (tid < 64) {
        int lane = tid, e = lane & 15;
        float scv = sc[e];
        unsigned sel = 0;
        float tw[4]; int ti[4];
#pragma unroll
        for (int kk = 0; kk < 4; ++kk) {
            float cand = ((sel >> e) & 1u) ? -1e30f : scv;
            float mx = cand;
            mx = fmaxf(mx, __shfl_xor(mx, 1));
            mx = fmaxf(mx, __shfl_xor(mx, 2));
            mx = fmaxf(mx, __shfl_xor(mx, 4));
            mx = fmaxf(mx, __shfl_xor(mx, 8));
            unsigned long long msk = __ballot(cand == mx);
            int bi = (__ffsll(msk) - 1) & 15;
            tw[kk] = mx; ti[kk] = bi;
            sel |= 1u << bi;
        }
        if (lane == 0) {
            float inv = 1.f / (tw[0] + tw[1] + tw[2] + tw[3]);
            toke[t] = make_int4(ti[0], ti[1], ti[2], ti[3]);
            tokw[t] = make_float4(tw[0] * inv, tw[1] * inv, tw[2] * inv, tw[3] * inv);
        }
    }
}

// ---------------- MFMA GEMM (64x64 tile, 8 waves) ----------------
// EPI 0 = f32 out, 1 = f32+residual, 2 = bf16 out,
// EPI 3 = ukv scatter: gn=h*128+dd; dd<64 -> kb (aux), dd>=64 -> vbt transposed (aux2)
// EPI 4 = uq scatter:  gn=h*96+dd;  dd<64 -> qb*scale (aux), dd>=64 -> qcrb (Cv)
template <int EPI>
__global__ __launch_bounds__(512)
void k_mgemm(const short* __restrict__ A, const short* __restrict__ BT,
             void* __restrict__ Cv, const float* __restrict__ add, int N, int K,
             short* __restrict__ aux, short* __restrict__ aux2) {
    __shared__ __align__(16) short As[64 * 64];
    __shared__ __align__(16) short Bs[64 * 64];
    int tid = threadIdx.x;
    int w = tid >> 6, l = tid & 63, g = l >> 4, li = l & 15;
    int wm = w >> 1, wn = w & 1;
    int m0 = blockIdx.y * 64, n0 = blockIdx.x * 64;
    f32x4 acc[2] = {};
    for (int k0 = 0; k0 < K; k0 += 64) {
        __syncthreads();
        {
            int row = tid >> 3, ch = tid & 7;
            *(int4*)&As[row * 64 + ((ch ^ (row & 7)) * 8)] =
                *(const int4*)(A + (size_t)(m0 + row) * K + k0 + 8 * ch);
            int4 v = {0, 0, 0, 0};
            if (n0 + row < N) v = *(const int4*)(BT + (size_t)(n0 + row) * K + k0 + 8 * ch);
            *(int4*)&Bs[row * 64 + ((ch ^ (row & 7)) * 8)] = v;
        }
        __syncthreads();
#pragma unroll
        for (int kc = 0; kc < 2; ++kc) {
            int row = wm * 16 + li;
            s16x8 af = *(const s16x8*)&As[row * 64 + (((4 * kc + g) ^ (li & 7)) * 8)];
#pragma unroll
            for (int nt = 0; nt < 2; ++nt) {
                int n = wn * 32 + nt * 16 + li;
                s16x8 bf = *(const s16x8*)&Bs[n * 64 + (((4 * kc + g) ^ (li & 7)) * 8)];
                acc[nt] = __builtin_amdgcn_mfma_f32_16x16x32_bf16(af, bf, acc[nt], 0, 0, 0);
            }
        }
    }
#pragma unroll
    for (int nt = 0; nt < 2; ++nt)
#pragma unroll
        for (int r = 0; r < 4; ++r) {
            int gm = m0 + wm * 16 + 4 * g + r;
            int gn = n0 + wn * 32 + nt * 16 + li;
            if (gn < N) {
                float v = acc[nt][r];
                if (EPI == 1) {
                    ((float*)Cv)[(size_t)gm * N + gn] = v + add[(size_t)gm * N + gn];
                } else if (EPI == 2) {
                    ((short*)Cv)[(size_t)gm * N + gn] = f2b(v);
                } else if (EPI == 3) {
                    int h = gn >> 7, dd = gn & 127;
                    int b = gm >> 11, srow = gm & 2047;
                    int bh = b * 8 + h;
                    if (dd < 64)
                        aux[((size_t)(bh * 2048 + srow)) * 96 + dd] = f2b(v);
                    else
                        aux2[(size_t)bh * 64 * 2048 + (size_t)(dd - 64) * 2048 + srow] = f2b(v);
                } else if (EPI == 4) {
                    int h = gn / 96, dd = gn - h * 96;
                    int b = gm >> 11, srow = gm & 2047;
                    int bh = b * 8 + h;
                    if (dd < 64)
                        aux[((size_t)(bh * 2048 + srow)) * 96 + dd] = f2b(v * 0.14724389f);
                    else
                        ((short*)Cv)[(size_t)gm * N + gn] = f2b(v);
                } else {
                    ((float*)Cv)[(size_t)gm * N + gn] = v;
                }
            }
        }
}

// ---------------- wo projection fused with attention partial combine ----------------
__global__ __launch_bounds__(512)
void k_wo_gemm(const short* __restrict__ po, const float* __restrict__ pl,
               const short* __restrict__ BT, float* __restrict__ C,
               const float* __restrict__ add) {
    constexpr int N = 512, K = 512;
    __shared__ __align__(16) short As[64 * 64];
    __shared__ __align__(16) short Bs[64 * 64];
    int tid = threadIdx.x;
    int w = tid >> 6, l = tid & 63, g = l >> 4, li = l & 15;
    int wm = w >> 1, wn = w & 1;
    int m0 = blockIdx.y * 64, n0 = blockIdx.x * 64;
    int row = tid >> 3, ch = tid & 7;
    int t = m0 + row;
    int b = t >> 11, q = t & 2047;
    f32x4 acc[2] = {};
    for (int k0 = 0; k0 < K; k0 += 64) {
        int h = k0 >> 6;
        int bhq = (b * 8 + h) * 2048 + q;
        size_t pb = (size_t)bhq * 256 + 8 * ch;
        float4 l4 = *(const float4*)(pl + (size_t)bhq * 4);
        float inv = 1.f / (l4.x + l4.y + l4.z + l4.w);
        union { int4 v; short s[8]; } p0, p1, p2, p3, ov;
        p0.v = *(const int4*)(po + pb);
        p1.v = *(const int4*)(po + pb + 64);
        p2.v = *(const int4*)(po + pb + 128);
        p3.v = *(const int4*)(po + pb + 192);
#pragma unroll
        for (int i = 0; i < 8; ++i) {
            float os = b2f(p0.s[i]) + b2f(p1.s[i]) + b2f(p2.s[i]) + b2f(p3.s[i]);
            ov.s[i] = f2b(os * inv);
        }
        int4 bv = *(const int4*)(BT + (size_t)(n0 + row) * K + k0 + 8 * ch);
        __syncthreads();
        *(int4*)&As[row * 64 + ((ch ^ (row & 7)) * 8)] = ov.v;
        *(int4*)&Bs[row * 64 + ((ch ^ (row & 7)) * 8)] = bv;
        __syncthreads();
#pragma unroll
        for (int kc = 0; kc < 2; ++kc) {
            int rr = wm * 16 + li;
            s16x8 af = *(const s16x8*)&As[rr * 64 + (((4 * kc + g) ^ (li & 7)) * 8)];
#pragma unroll
            for (int nt = 0; nt < 2; ++nt) {
                int n = wn * 32 + nt * 16 + li;
                s16x8 bf = *(const s16x8*)&Bs[n * 64 + (((4 * kc + g) ^ (li & 7)) * 8)];
                acc[nt] = __builtin_amdgcn_mfma_f32_16x16x32_bf16(af, bf, acc[nt], 0, 0, 0);
            }
        }
    }
#pragma unroll
    for (int nt = 0; nt < 2; ++nt)
#pragma unroll
        for (int r = 0; r < 4; ++r) {
            int gm = m0 + wm * 16 + 4 * g + r;
            int gn = n0 + wn * 32 + nt * 16 + li;
            C[(size_t)gm * N + gn] = acc[nt][r] + add[(size_t)gm * N + gn];
        }
}

// ---------------- shared expert (64x64 tile, 8 waves): gact = silu(x@wg)*(x@wu) ----------------
__global__ __launch_bounds__(512)
void k_shexp(const short* __restrict__ X, const short* __restrict__ WGt, const short* __restrict__ WUt,
             short* __restrict__ gact) {
    __shared__ __align__(16) short As[64 * 64];
    __shared__ __align__(16) short Bg[64 * 64];
    __shared__ __align__(16) short Bu[64 * 64];
    int tid = threadIdx.x;
    int w = tid >> 6, l = tid & 63, g = l >> 4, li = l & 15;
    int wm = w >> 1, wn = w & 1;
    int m0 = blockIdx.x * 64, n0 = blockIdx.y * 64;
    f32x4 ag[2] = {}, au[2] = {};
    for (int k0 = 0; k0 < 512; k0 += 64) {
        __syncthreads();
        {
            int row = tid >> 3, ch = tid & 7;
            *(int4*)&As[row * 64 + ((ch ^ (row & 7)) * 8)] =
                *(const int4*)(X + (size_t)(m0 + row) * 512 + k0 + 8 * ch);
            *(int4*)&Bg[row * 64 + ((ch ^ (row & 7)) * 8)] =
                *(const int4*)(WGt + (size_t)(n0 + row) * 512 + k0 + 8 * ch);
            *(int4*)&Bu[row * 64 + ((ch ^ (row & 7)) * 8)] =
                *(const int4*)(WUt + (size_t)(n0 + row) * 512 + k0 + 8 * ch);
        }
        __syncthreads();
#pragma unroll
        for (int kc = 0; kc < 2; ++kc) {
            int row = wm * 16 + li;
            s16x8 af = *(const s16x8*)&As[row * 64 + (((4 * kc + g) ^ (li & 7)) * 8)];
#pragma unroll
            for (int nt = 0; nt < 2; ++nt) {
                int n = wn * 32 + nt * 16 + li;
                s16x8 bg = *(const s16x8*)&Bg[n * 64 + (((4 * kc + g) ^ (li & 7)) * 8)];
                s16x8 bu = *(const s16x8*)&Bu[n * 64 + (((4 * kc + g) ^ (li & 7)) * 8)];
                ag[nt] = __builtin_amdgcn_mfma_f32_16x16x32_bf16(af, bg, ag[nt], 0, 0, 0);
                au[nt] = __builtin_amdgcn_mfma_f32_16x16x32_bf16(af, bu, au[nt], 0, 0, 0);
            }
        }
    }
#pragma unroll
    for (int nt = 0; nt < 2; ++nt)
#pragma unroll
        for (int r = 0; r < 4; ++r) {
            int gm = m0 + wm * 16 + 4 * g + r;
            int gn = n0 + wn * 32 + nt * 16 + li;
            float gv = ag[nt][r], uv = au[nt][r];
            gact[(size_t)gm * 256 + gn] = f2b(gv / (1.f + __expf(-gv)) * uv);
        }
}

// ---------------- rope-only build: q-rope from qcrb, k-rope from cqkv ----------------
__global__ void k_build_rope(const short* __restrict__ qcrb, const float* __restrict__ cqkv,
                             short* __restrict__ qb, short* __restrict__ kb) {
    const float scale = 0.14724389f;  // log2(e)/sqrt(96)
    int gid = blockIdx.x * 256 + threadIdx.x;
    const int NR = 16 * 2048 * 32;
    if (gid < NR) {
        int d2 = gid & 31;
        int rs = gid >> 5;
        int srow = rs & 2047;
        int bh = rs >> 11;
        int b = bh >> 3, h = bh & 7;
        int t = b * 2048 + srow;
        const short* src = qcrb + (size_t)t * 768 + h * 96;
        int fi = d2 & 15;
        float ang = (float)srow * __expf(-((float)(2 * fi) / 32.f) * 9.210340371976184f);
        float s, c; __sincosf(ang, &s, &c);
        float x = b2f(src[64 + d2]);
        float r = (d2 < 16) ? -b2f(src[64 + d2 + 16]) : b2f(src[64 + d2 - 16]);
        qb[((size_t)(bh * 2048 + srow)) * 96 + 64 + d2] = f2b((x * c + r * s) * scale);
    } else {
        int g2 = gid - NR;
        int d2 = g2 & 31;
        int rs = g2 >> 5;
        int srow = rs & 2047;
        int bh = rs >> 11;
        int b = bh >> 3;
        int t = b * 2048 + srow;
        int fi = d2 & 15;
        float ang = (float)srow * __expf(-((float)(2 * fi) / 32.f) * 9.210340371976184f);
        float s, c; __sincosf(ang, &s, &c);
        float x = cqkv[(size_t)t * 416 + 384 + d2];
        float r = (d2 < 16) ? -cqkv[(size_t)t * 416 + 384 + d2 + 16]
                            :  cqkv[(size_t)t * 416 + 384 + d2 - 16];
        kb[((size_t)(bh * 2048 + srow)) * 96 + 64 + d2] = f2b(x * c + r * s);
    }
}

// ---------------- K-split(4) MFMA flash attention, 32 q/wave, MFMA denominator ----------------
__global__ __launch_bounds__(256)
void k_attn(const short* __restrict__ qb, const short* __restrict__ kb,
            const short* __restrict__ vbt, short* __restrict__ po, float* __restrict__ pl) {
    __shared__ __align__(16) short Ks[64 * 100];
    __shared__ __align__(16) short Vs[80 * 64];
    int tid = threadIdx.x;
    int w = tid >> 6, l = tid & 63, g = l >> 4, li = l & 15;
    int blk = blockIdx.x;
    int bh = blk >> 6, rem = blk & 63;
    int qt = rem >> 2, ks = rem & 3;
    int qc0 = qt * 128 + w * 32;

    {
        const short one = 0x3F80;  // bf16 1.0
        for (int i = tid; i < 16 * 64; i += 256)
            Vs[64 * 64 + i] = (i < 64) ? one : (short)0;
    }

    s16x8 qf[2][3];
#pragma unroll
    for (int j = 0; j < 2; ++j) {
        const short* qp = qb + (size_t)(bh * 2048 + qc0 + j * 16 + li) * 96;
#pragma unroll
        for (int c = 0; c < 3; ++c) qf[j][c] = *(const s16x8*)(qp + 32 * c + 8 * g);
    }

    f32x4 o[2][5] = {};
    const short* kbase = kb + (size_t)bh * 2048 * 96;
    const short* vbase = vbt + (size_t)bh * 64 * 2048;

    for (int t = 0; t < 8; ++t) {
        int koff = ks * 512 + t * 64;
        __syncthreads();
#pragma unroll
        for (int p = 0; p < 3; ++p) {
            int flat = p * 256 + tid;
            int key = flat / 12, u = flat % 12;
            *(int4*)&Ks[key * 100 + 8 * u] = *(const int4*)(kbase + (size_t)(koff + key) * 96 + 8 * u);
        }
#pragma unroll
        for (int p = 0; p < 2; ++p) {
            int flat = p * 256 + tid;
            int dim = flat >> 3, kc8 = flat & 7;
            int4 v = *(const int4*)(vbase + (size_t)dim * 2048 + koff + 8 * kc8);
            int sw = dim & 15;
            *(int2*)&Vs[dim * 64 + (((2 * kc8) ^ sw) * 4)]     = make_int2(v.x, v.y);
            *(int2*)&Vs[dim * 64 + (((2 * kc8 + 1) ^ sw) * 4)] = make_int2(v.z, v.w);
        }
        __syncthreads();

        f32x4 s[2][4];
#pragma unroll
        for (int kt = 0; kt < 4; ++kt) {
            f32x4 a0 = {}, a1 = {};
#pragma unroll
            for (int c = 0; c < 3; ++c) {
                s16x8 kf = *(const s16x8*)&Ks[(kt * 16 + li) * 100 + 32 * c + 8 * g];
                a0 = __builtin_amdgcn_mfma_f32_16x16x32_bf16(kf, qf[0][c], a0, 0, 0, 0);
                a1 = __builtin_amdgcn_mfma_f32_16x16x32_bf16(kf, qf[1][c], a1, 0, 0, 0);
            }
            s[0][kt] = a0; s[1][kt] = a1;
        }
#pragma unroll
        for (int j = 0; j < 2; ++j)
#pragma unroll
            for (int kt = 0; kt < 4; ++kt)
#pragma unroll
                for (int r = 0; r < 4; ++r) s[j][kt][r] = exp2f(s[j][kt][r]);
        s16x8 pf[2][2];
#pragma unroll
        for (int j = 0; j < 2; ++j)
#pragma unroll
            for (int kc = 0; kc < 2; ++kc) {
                s16x8 tt;
#pragma unroll
                for (int r = 0; r < 4; ++r) { tt[r] = f2b(s[j][2 * kc][r]); tt[4 + r] = f2b(s[j][2 * kc + 1][r]); }
                pf[j][kc] = tt;
            }
#pragma unroll
        for (int dt = 0; dt < 5; ++dt) {
            int dim = dt * 16 + li;
#pragma unroll
            for (int kc = 0; kc < 2; ++kc) {
                int2 a0 = *(const int2*)&Vs[dim * 64 + (((8 * kc + g) ^ li) * 4)];
                int2 a1 = *(const int2*)&Vs[dim * 64 + (((8 * kc + 4 + g) ^ li) * 4)];
                union { s16x8 v; int i[4]; } vf;
                vf.i[0] = a0.x; vf.i[1] = a0.y; vf.i[2] = a1.x; vf.i[3] = a1.y;
                o[0][dt] = __builtin_amdgcn_mfma_f32_16x16x32_bf16(vf.v, pf[0][kc], o[0][dt], 0, 0, 0);
                o[1][dt] = __builtin_amdgcn_mfma_f32_16x16x32_bf16(vf.v, pf[1][kc], o[1][dt], 0, 0, 0);
            }
        }
    }
#pragma unroll
    for (int j = 0; j < 2; ++j) {
        int qcol = qc0 + j * 16 + li;
        size_t qbase = ((size_t)(bh * 2048 + qcol) * 4 + ks) * 64;
#pragma unroll
        for (int dt = 0; dt < 4; ++dt) {
            union { short s[4]; int2 v; } pk;
#pragma unroll
            for (int r = 0; r < 4; ++r) pk.s[r] = f2b(o[j][dt][r]);
            *(int2*)(po + qbase + dt * 16 + 4 * g) = pk.v;
        }
        if (g == 0) pl[(size_t)(bh * 2048 + qcol) * 4 + ks] = o[j][4][0];
    }
}

// ---------------- scatter: block-aggregated expert list build ----------------
__global__ __launch_bounds__(256)
void k_scatter(const int4* __restrict__ toke, const float4* __restrict__ tokw,
               float* __restrict__ ewt, int* __restrict__ ecnt, int* __restrict__ etok) {
    __shared__ int lcnt[16];
    __shared__ int lbase[16];
    int tid = threadIdx.x;
    int t = blockIdx.x * 256 + tid;
    if (tid < 16) lcnt[tid] = 0;
    __syncthreads();
    int4 e4 = toke[t];
    float4 w4 = tokw[t];
    int es[4] = { e4.x, e4.y, e4.z, e4.w };
    float wv[4] = { w4.x, w4.y, w4.z, w4.w };
    int ls[4];
#pragma unroll
    for (int kk = 0; kk < 4; ++kk) ls[kk] = atomicAdd(&lcnt[es[kk]], 1);
    __syncthreads();
    if (tid < 16) lbase[tid] = atomicAdd(&ecnt[tid], lcnt[tid]);
    __syncthreads();
#pragma unroll
    for (int kk = 0; kk < 4; ++kk) {
        int slot = lbase[es[kk]] + ls[kk];
        etok[es[kk] * 4096 + slot] = t * 4 + kk;
        ewt[es[kk] * 4096 + slot] = wv[kk];
    }
}

// ---------------- MoE stage 1 (MFMA, 8 waves, inline tile-scan, XCD swizzle) --------------------
// grid (144,4)=576 blocks. Linear wg id lin = bx + 144*by; XCD = lin%8 (round-robin assumption).
// virt = (lin%8)*72 + lin/8 groups contiguous virt per XCD; decode virt -> (tile = virt/4, y = virt%4)
// so each XCD covers ~2 experts' full work -> expert weights L2-resident. Bijective (576 = 8*72).
__global__ __launch_bounds__(512)
void k_moe1m(const short* __restrict__ X, const short* __restrict__ WGt, const short* __restrict__ WUt,
             const int* __restrict__ ecnt, const int* __restrict__ etok, short* __restrict__ eact) {
    __shared__ int ecs[16];
    __shared__ __align__(16) short As[128 * 64];
    __shared__ __align__(16) short Bg[64 * 64];
    __shared__ __align__(16) short Bu[64 * 64];
    __shared__ int toks[128];
    int tid = threadIdx.x;
    if (tid < 16) ecs[tid] = ecnt[tid];
    __syncthreads();
    int lin = blockIdx.x + 144 * blockIdx.y;          // 0..575
    int virt = (lin & 7) * 72 + (lin >> 3);           // bijective chunked swizzle
    int bid = virt >> 2;                              // tile-scan index 0..143
    int n0 = (virt & 3) * 64;
    int e = 0;
    for (; e < 16; ++e) { int n = (ecs[e] + 127) >> 7; if (bid < n) break; bid -= n; }
    if (e >= 16) return;
    int base = bid << 7;
    int rows = min(128, ecs[e] - base);
    if (tid < 128) toks[tid] = (tid < rows) ? etok[e * 4096 + base + tid] : -1;
    __syncthreads();
    int w = tid >> 6, l = tid & 63, g = l >> 4, li = l & 15;
    int wm = w >> 1, wn = w & 1;
    const short* wgp = WGt + (size_t)e * 256 * 512;
    const short* wup = WUt + (size_t)e * 256 * 512;
    f32x4 ag[2][2] = {}, au[2][2] = {};
    for (int k0 = 0; k0 < 512; k0 += 64) {
        __syncthreads();
#pragma unroll
        for (int p = 0; p < 2; ++p) {
            int flat = p * 512 + tid;
            int row = flat >> 3, ch = flat & 7;
            int tk = toks[row];
            int4 v = {0, 0, 0, 0};
            if (tk >= 0) v = *(const int4*)(X + (size_t)(tk >> 2) * 512 + k0 + 8 * ch);
            *(int4*)&As[row * 64 + ((ch ^ (row & 7)) * 8)] = v;
        }
        {
            int n = tid >> 3, ch = tid & 7;
            *(int4*)&Bg[n * 64 + ((ch ^ (n & 7)) * 8)] = *(const int4*)(wgp + (size_t)(n0 + n) * 512 + k0 + 8 * ch);
            *(int4*)&Bu[n * 64 + ((ch ^ (n & 7)) * 8)] = *(const int4*)(wup + (size_t)(n0 + n) * 512 + k0 + 8 * ch);
        }
        __syncthreads();
#pragma unroll
        for (int kc = 0; kc < 2; ++kc) {
            s16x8 af[2], bg[2], bu[2];
#pragma unroll
            for (int mt = 0; mt < 2; ++mt) {
                int row = wm * 32 + mt * 16 + li;
                af[mt] = *(const s16x8*)&As[row * 64 + (((4 * kc + g) ^ (li & 7)) * 8)];
            }
#pragma unroll
            for (int nt = 0; nt < 2; ++nt) {
                int n = wn * 32 + nt * 16 + li;
                bg[nt] = *(const s16x8*)&Bg[n * 64 + (((4 * kc + g) ^ (li & 7)) * 8)];
                bu[nt] = *(const s16x8*)&Bu[n * 64 + (((4 * kc + g) ^ (li & 7)) * 8)];
            }
#pragma unroll
            for (int mt = 0; mt < 2; ++mt)
#pragma unroll
                for (int nt = 0; nt < 2; ++nt) {
                    ag[mt][nt] = __builtin_amdgcn_mfma_f32_16x16x32_bf16(af[mt], bg[nt], ag[mt][nt], 0, 0, 0);
                    au[mt][nt] = __builtin_amdgcn_mfma_f32_16x16x32_bf16(af[mt], bu[nt], au[mt][nt], 0, 0, 0);
                }
        }
    }
#pragma unroll
    for (int mt = 0; mt < 2; ++mt)
#pragma unroll
        for (int nt = 0; nt < 2; ++nt)
#pragma unroll
            for (int r = 0; r < 4; ++r) {
                int local = wm * 32 + mt * 16 + 4 * g + r;
                if (local < rows) {
                    int entry = toks[local];
                    int gn = n0 + wn * 32 + nt * 16 + li;
                    float gv = ag[mt][nt][r], uv = au[mt][nt][r];
                    eact[(size_t)entry * 256 + gn] = f2b(gv / (1.f + __expf(-gv)) * uv);
                }
            }
}

// ---------------- MoE stage 2 (MFMA, 8 waves, inline tile-scan, XCD swizzle) --------------------
// grid (144,8)=1152 blocks; virt = (lin%8)*144 + lin/8; tile = virt/8, y = virt%8.
__global__ __launch_bounds__(512)
void k_moe2m(const short* __restrict__ EA, const short* __restrict__ WDt,
             const int* __restrict__ ecnt, const int* __restrict__ etok,
             const float* __restrict__ ewt, float* __restrict__ oacc) {
    __shared__ int ecs[16];
    __shared__ __align__(16) short As[128 * 64];
    __shared__ __align__(16) short Bs[64 * 64];
    __shared__ int toks[128];
    __shared__ float wts[128];
    int tid = threadIdx.x;
    if (tid < 16) ecs[tid] = ecnt[tid];
    __syncthreads();
    int lin = blockIdx.x + 144 * blockIdx.y;          // 0..1151
    int virt = (lin & 7) * 144 + (lin >> 3);          // bijective (1152 = 8*144)
    int bid = virt >> 3;                              // tile-scan index 0..143
    int n0 = (virt & 7) * 64;
    int e = 0;
    for (; e < 16; ++e) { int n = (ecs[e] + 127) >> 7; if (bid < n) break; bid -= n; }
    if (e >= 16) return;
    int base = bid << 7;
    int rows = min(128, ecs[e] - base);
    if (tid < 128) {
        toks[tid] = (tid < rows) ? etok[e * 4096 + base + tid] : -1;
        wts[tid]  = (tid < rows) ? ewt[e * 4096 + base + tid] : 0.f;
    }
    __syncthreads();
    int w = tid >> 6, l = tid & 63, g = l >> 4, li = l & 15;
    int wm = w >> 1, wn = w & 1;
    const short* wdp = WDt + (size_t)e * 512 * 256;
    f32x4 acc[2][2] = {};
    for (int k0 = 0; k0 < 256; k0 += 64) {
        __syncthreads();
#pragma unroll
        for (int p = 0; p < 2; ++p) {
            int flat = p * 512 + tid;
            int row = flat >> 3, ch = flat & 7;
            int tk = toks[row];
            int4 v = {0, 0, 0, 0};
            if (tk >= 0) v = *(const int4*)(EA + (size_t)tk * 256 + k0 + 8 * ch);
            *(int4*)&As[row * 64 + ((ch ^ (row & 7)) * 8)] = v;
        }
        {
            int n = tid >> 3, ch = tid & 7;
            *(int4*)&Bs[n * 64 + ((ch ^ (n & 7)) * 8)] = *(const int4*)(wdp + (size_t)(n0 + n) * 256 + k0 + 8 * ch);
        }
        __syncthreads();
#pragma unroll
        for (int kc = 0; kc < 2; ++kc) {
            s16x8 af[2], bf[2];
#pragma unroll
            for (int mt = 0; mt < 2; ++mt) {
                int row = wm * 32 + mt * 16 + li;
                af[mt] = *(const s16x8*)&As[row * 64 + (((4 * kc + g) ^ (li & 7)) * 8)];
            }
#pragma unroll
            for (int nt = 0; nt < 2; ++nt) {
                int n = wn * 32 + nt * 16 + li;
                bf[nt] = *(const s16x8*)&Bs[n * 64 + (((4 * kc + g) ^ (li & 7)) * 8)];
            }
#pragma unroll
            for (int mt = 0; mt < 2; ++mt)
#pragma unroll
                for (int nt = 0; nt < 2; ++nt)
                    acc[mt][nt] = __builtin_amdgcn_mfma_f32_16x16x32_bf16(af[mt], bf[nt], acc[mt][nt], 0, 0, 0);
        }
    }
#pragma unroll
    for (int mt = 0; mt < 2; ++mt)
#pragma unroll
        for (int nt = 0; nt < 2; ++nt)
#pragma unroll
            for (int r = 0; r < 4; ++r) {
                int local = wm * 32 + mt * 16 + 4 * g + r;
                if (local < rows) {
                    int tok = toks[local] >> 2;
                    int gn = n0 + wn * 32 + nt * 16 + li;
                    atomicAdd(&oacc[(size_t)tok * 512 + gn], acc[mt][nt][r] * wts[local]);
                }
            }
}

// ---------------- host launcher ----------------
extern "C" void kernel_launch(void* const* d_in, const int* in_sizes, int n_in,
                              void* d_out, int out_size, void* d_ws, size_t ws_size,
                              hipStream_t stream) {
    const float* hs       = (const float*)d_in[0];
    const float* w_innorm = (const float*)d_in[1];
    const float* w_dq     = (const float*)d_in[2];
    const float* w_qnorm  = (const float*)d_in[3];
    const float* w_uq     = (const float*)d_in[4];
    const float* w_dkv    = (const float*)d_in[5];
    const float* w_kvnorm = (const float*)d_in[6];
    const float* w_ukv    = (const float*)d_in[7];
    const float* w_o      = (const float*)d_in[8];
    const float* w_post   = (const float*)d_in[9];
    const float* w_gate   = (const float*)d_in[10];
    const float* sh_wg    = (const float*)d_in[11];
    const float* sh_wu    = (const float*)d_in[12];
    const float* sh_wd    = (const float*)d_in[13];
    const float* r_wg     = (const float*)d_in[14];
    const float* r_wu     = (const float*)d_in[15];
    const float* r_wd     = (const float*)d_in[16];

    float* ws   = (float*)d_ws;
    float* cqkv = ws + OFF_CQKV;
    short* qcrb = (short*)(ws + OFF_QCR);
    float* r2   = ws + OFF_R2;
    short* po   = (short*)(ws + OFF_PO);
    float* pl   = ws + OFF_PL;
    int4*  toke = (int4*)(ws + OFF_TOKE);
    float4* tokw = (float4*)(ws + OFF_TOKW);
    float* ewt  = ws + OFF_EWT;
    int*   ecnt = (int*)(ws + OFF_ECNT);
    int*   etok = (int*)(ws + OFF_ETOK);
    short* xnb   = (short*)(ws + OFF_XNB);
    short* cqnb  = (short*)(ws + OFF_CQNB);
    short* ckvnb = (short*)(ws + OFF_CKVNB);
    short* qb    = (short*)(ws + OFF_QB);
    short* kb    = (short*)(ws + OFF_KB);
    short* vbt   = (short*)(ws + OFF_VBT);
    short* xn2b  = (short*)(ws + OFF_XN2B);
    short* gact  = (short*)(ws + OFF_GACT);
    short* eact  = (short*)(ws + OFF_EACT);
    short* wqkvT = (short*)(ws + OFF_WQKVT);
    short* wuqT  = (short*)(ws + OFF_WUQT);
    short* wukvT = (short*)(ws + OFF_WUKVT);
    short* woT   = (short*)(ws + OFF_WOT);
    short* shwgT = (short*)(ws + OFF_SHWGT);
    short* shwuT = (short*)(ws + OFF_SHWUT);
    short* shwdT = (short*)(ws + OFF_SHWDT);
    short* rwgT  = (short*)(ws + OFF_RWGT);
    short* rwuT  = (short*)(ws + OFF_RWUT);
    short* rwdT  = (short*)(ws + OFF_RWDT);

    float* outF = (float*)d_out;

    // 0. fused weight convert+transpose (bf16 [N][K])
    CvtTab tab;
    const float* srcs[11] = { w_dq, w_dkv, w_uq, w_ukv, w_o, sh_wg, sh_wu, sh_wd, r_wg, r_wu, r_wd };
    short* dsts[11] = { wqkvT, wqkvT + (size_t)256 * 512, wuqT, wukvT, woT, shwgT, shwuT, shwdT, rwgT, rwuT, rwdT };
    int Ks_[11] = { 512, 512, 256, 128, 512, 512, 512, 256, 512, 512, 256 };
    int Ns_[11] = { 256, 160, 768, 1024, 512, 256, 256, 512, 256, 256, 512 };
    int Es_[11] = { 1, 1, 1, 1, 1, 1, 1, 1, 16, 16, 16 };
    int cum = 0;
    for (int i = 0; i < 11; ++i) {
        tab.src[i] = srcs[i]; tab.dst[i] = dsts[i];
        tab.K[i] = Ks_[i]; tab.N[i] = Ns_[i];
        cum += Es_[i] * (Ks_[i] >> 5) * (Ns_[i] >> 5);
        tab.end[i] = cum;
    }
    k_cvt_all<<<cum, 256, 0, stream>>>(tab);

    // 1. input RMSNorm -> bf16 (also zeroes ecnt)
    k_rms<<<Tt, 256, 0, stream>>>(hs, 512, w_innorm, xnb, 512, 512, ecnt);
    // 2. fused down-projection (dq|dkv), N=416, f32 out
    k_mgemm<0><<<dim3(7, 64), 512, 0, stream>>>(xnb, wqkvT, (void*)cqkv, nullptr, 416, 512, nullptr, nullptr);
    // 3. fused latent norms -> bf16
    k_rms2<<<2 * Tt, 256, 0, stream>>>(cqkv, w_qnorm, cqnb, w_kvnorm, ckvnb);
    // 4. up-projections: uq scatters q-copy (scaled) to qb + rope part to qcrb;
    //    ukv scatters K-copy to kb and V (transposed) to vbt
    k_mgemm<4><<<dim3(12, 64), 512, 0, stream>>>(cqnb, wuqT, (void*)qcrb, nullptr, 768, 256, qb, nullptr);
    k_mgemm<3><<<dim3(16, 64), 512, 0, stream>>>(ckvnb, wukvT, nullptr, nullptr, 1024, 128, kb, vbt);
    // 5. rope-only build (q-rope from qcrb, k-rope from cqkv)
    k_build_rope<<<(2 * 16 * 2048 * 32) / 256, 256, 0, stream>>>(qcrb, cqkv, qb, kb);
    // 6. K-split(4) MFMA flash attention (32 q/wave, MFMA denominator)
    k_attn<<<1024, 256, 0, stream>>>(qb, kb, vbt, po, pl);
    // 7. wo projection fused with partial combine + residual
    k_wo_gemm<<<dim3(8, 64), 512, 0, stream>>>(po, pl, woT, r2, hs);
    // 8. fused post-norm + router
    k_rms_router<<<Tt, 256, 0, stream>>>(r2, w_post, w_gate, xn2b, toke, tokw);
    // 9. shared expert then down-proj + residual into d_out
    k_shexp<<<dim3(64, 4), 512, 0, stream>>>(xn2b, shwgT, shwuT, gact);
    k_mgemm<1><<<dim3(8, 64), 512, 0, stream>>>(gact, shwdT, (void*)outF, r2, 512, 256, nullptr, nullptr);
    // 10. scatter + MoE (inline tile-scan, XCD-swizzled)
    k_scatter<<<16, 256, 0, stream>>>(toke, tokw, ewt, ecnt, etok);
    k_moe1m<<<dim3(144, 4), 512, 0, stream>>>(xn2b, rwgT, rwuT, ecnt, etok, eact);
    k_moe2m<<<dim3(144, 8), 512, 0, stream>>>(eact, rwdT, ecnt, etok, ewt, outF);
}

// Round 21
// 206.248 us; speedup vs baseline: 1.1725x; 1.0472x over previous
//
#include <hip/hip_runtime.h>
#include <hip/hip_bf16.h>
#include <math.h>

typedef float f32x4 __attribute__((ext_vector_type(4)));
typedef short s16x8 __attribute__((ext_vector_type(8)));

// ---------------- problem constants ----------------
constexpr int Tt = 4096;
constexpr int NEn = 16;
constexpr float EPSf = 1.1920929e-07f;
constexpr int CVT_BLOCKS = 7312;   // total 32x32 tiles across all 11 weight tensors

__device__ __forceinline__ short f2b(float f) {
    union { __hip_bfloat16 h; short s; } u;
    u.h = __float2bfloat16(f);
    return u.s;
}
__device__ __forceinline__ float b2f(short s) {
    union { float f; unsigned u; } v;
    v.u = ((unsigned)(unsigned short)s) << 16;
    return v.f;
}

// ---------------- workspace layout (float elements, 16-float aligned) ----------------
constexpr size_t alg(size_t x) { return (x + 15) & ~(size_t)15; }
constexpr size_t OFF_CQKV = 0;                                   // T*416 f32
constexpr size_t OFF_QCR  = alg(OFF_CQKV + (size_t)Tt * 416);    // T*768 bf16 (rope sections only)
constexpr size_t OFF_KVB  = alg(OFF_QCR  + (size_t)Tt * 768);    // (unused; layout stability)
constexpr size_t OFF_R2   = alg(OFF_KVB  + (size_t)Tt * 1024);   // T*512 f32
constexpr size_t OFF_TOKE = alg(OFF_R2   + (size_t)Tt * 512);    // T*4 ints
constexpr size_t OFF_TOKW = alg(OFF_TOKE + (size_t)Tt * 4);      // T*4 f32
constexpr size_t OFF_EWT  = alg(OFF_TOKW + (size_t)Tt * 4);      // 16*4096 f32
constexpr size_t OFF_ECNT = alg(OFF_EWT  + (size_t)NEn * Tt);    // ints
constexpr size_t OFF_ETOK = alg(OFF_ECNT + 64);                  // 16*4096 ints
constexpr size_t OFF_PO   = 0;                                   // bf16 partials alias dead region
constexpr size_t OFF_PL   = (size_t)16 * 2048 * 4 * 64 / 2;      // f32
constexpr size_t OFF_XNB   = alg(OFF_ETOK + (size_t)NEn * Tt);
constexpr size_t OFF_CQNB  = alg(OFF_XNB   + (size_t)Tt * 512 / 2);
constexpr size_t OFF_CKVNB = alg(OFF_CQNB  + (size_t)Tt * 256 / 2);
constexpr size_t OFF_QB    = alg(OFF_CKVNB + (size_t)Tt * 128 / 2);
constexpr size_t OFF_KB    = alg(OFF_QB    + (size_t)16 * 2048 * 96 / 2);
constexpr size_t OFF_VBT   = alg(OFF_KB    + (size_t)16 * 2048 * 96 / 2);
constexpr size_t OFF_XN2B  = alg(OFF_VBT   + (size_t)16 * 64 * 2048 / 2);
constexpr size_t OFF_GACT  = alg(OFF_XN2B  + (size_t)Tt * 512 / 2);
constexpr size_t OFF_EACT  = alg(OFF_GACT  + (size_t)Tt * 256 / 2);
constexpr size_t OFF_WQKVT = alg(OFF_EACT  + (size_t)16384 * 256 / 2);
constexpr size_t OFF_WUQT  = alg(OFF_WQKVT + (size_t)416 * 512 / 2);
constexpr size_t OFF_WUKVT = alg(OFF_WUQT  + (size_t)768 * 256 / 2);
constexpr size_t OFF_WOT   = alg(OFF_WUKVT + (size_t)1024 * 128 / 2);
constexpr size_t OFF_SHWGT = alg(OFF_WOT   + (size_t)512 * 512 / 2);
constexpr size_t OFF_SHWUT = alg(OFF_SHWGT + (size_t)256 * 512 / 2);
constexpr size_t OFF_SHWDT = alg(OFF_SHWUT + (size_t)256 * 512 / 2);
constexpr size_t OFF_RWGT  = alg(OFF_SHWDT + (size_t)512 * 256 / 2);
constexpr size_t OFF_RWUT  = alg(OFF_RWGT  + (size_t)16 * 256 * 512 / 2);
constexpr size_t OFF_RWDT  = alg(OFF_RWUT  + (size_t)16 * 256 * 512 / 2);

struct CvtTab {
    const float* src[11];
    short* dst[11];
    int K[11], N[11], end[11];
};

// ---------------- merged: weight convert+transpose  ||  input RMSNorm ----------------
__global__ __launch_bounds__(256)
void k_cvt_rms(CvtTab tab, const float* __restrict__ in, const float* __restrict__ w,
               short* __restrict__ outB, int* __restrict__ ecnt) {
    __shared__ float t[32][33];
    __shared__ float xs[512];
    __shared__ float red[256];
    int bid = blockIdx.x, tid = threadIdx.x;
    if (bid < CVT_BLOCKS) {
        int i = 0;
        while (bid >= tab.end[i]) ++i;
        int tloc = bid - (i ? tab.end[i - 1] : 0);
        int K = tab.K[i], N = tab.N[i];
        int ntiles = N >> 5, perE = ntiles * (K >> 5);
        int e = tloc / perE, rem = tloc - e * perE;
        int k0 = (rem / ntiles) << 5, n0 = (rem % ntiles) << 5;
        size_t eo = (size_t)e * K * N;
        const float* src = tab.src[i];
        short* dst = tab.dst[i];
        int c = tid & 31, r = tid >> 5;
#pragma unroll
        for (int q = 0; q < 4; ++q)
            t[r + 8 * q][c] = src[eo + (size_t)(k0 + r + 8 * q) * N + n0 + c];
        __syncthreads();
#pragma unroll
        for (int q = 0; q < 4; ++q)
            dst[eo + (size_t)(n0 + r + 8 * q) * K + k0 + c] = f2b(t[c][r + 8 * q]);
    } else {
        int row = bid - CVT_BLOCKS;
        if (row == 0 && tid < 16) ecnt[tid] = 0;
        const float* ip = in + (size_t)row * 512;
        float ss = 0.f;
        for (int i = tid; i < 512; i += 256) { float v = ip[i]; xs[i] = v; ss += v * v; }
        red[tid] = ss; __syncthreads();
        for (int s = 128; s > 0; s >>= 1) { if (tid < s) red[tid] += red[tid + s]; __syncthreads(); }
        float sc = rsqrtf(red[0] / 512.f + EPSf);
        for (int i = tid; i < 512; i += 256) outB[(size_t)row * 512 + i] = f2b(xs[i] * sc * w[i]);
    }
}

// ---------------- fused latent RMSNorm pair over cqkv[4096][416] ----------------
__global__ void k_rms2(const float* __restrict__ cqkv, const float* __restrict__ wq, short* __restrict__ cqnb,
                       const float* __restrict__ wkv, short* __restrict__ ckvnb) {
    int row = blockIdx.x, tid = threadIdx.x;
    __shared__ float xs[256];
    __shared__ float red[256];
    const float* ip; const float* w; short* ob; int D, outStride, r;
    if (row < Tt) { r = row;      ip = cqkv + (size_t)r * 416;       w = wq;  ob = cqnb;  D = 256; outStride = 256; }
    else          { r = row - Tt; ip = cqkv + (size_t)r * 416 + 256; w = wkv; ob = ckvnb; D = 128; outStride = 128; }
    float ss = 0.f;
    for (int i = tid; i < D; i += 256) { float v = ip[i]; xs[i] = v; ss += v * v; }
    red[tid] = ss; __syncthreads();
    for (int s = 128; s > 0; s >>= 1) { if (tid < s) red[tid] += red[tid + s]; __syncthreads(); }
    float sc = rsqrtf(red[0] / (float)D + EPSf);
    for (int i = tid; i < D; i += 256) ob[(size_t)r * outStride + i] = f2b(xs[i] * sc * w[i]);
}

// ---------------- fused post-RMSNorm + router ----------------
__global__ __launch_bounds__(256)
void k_rms_router(const float* __restrict__ r2, const float* __restrict__ wpost,
                  const float* __restrict__ wg,
                  short* __restrict__ xn2b, int4* __restrict__ toke, float4* __restrict__ tokw) {
    int t = blockIdx.x, tid = threadIdx.x;
    __shared__ float xs[512];
    __shared__ float red[256];
    __shared__ float part[16][17];
    __shared__ float sc[16];
    const float* ip = r2 + (size_t)t * 512;
    float ss = 0.f;
    for (int i = tid; i < 512; i += 256) { float v = ip[i]; xs[i] = v; ss += v * v; }
    red[tid] = ss; __syncthreads();
    for (int s = 128; s > 0; s >>= 1) { if (tid < s) red[tid] += red[tid + s]; __syncthreads(); }
    float scale = rsqrtf(red[0] / 512.f + EPSf);
    for (int i = tid; i < 512; i += 256) {
        float v = xs[i] * scale * wpost[i];
        xs[i] = v;
        xn2b[(size_t)t * 512 + i] = f2b(v);
    }
    __syncthreads();
    {
        int e = tid & 15, ch = tid >> 4;
        const float* wp = wg + (size_t)ch * 32 * 16 + e;
        float s = 0.f;
#pragma unroll 8
        for (int k = 0; k < 32; ++k) s = fmaf(xs[ch * 32 + k], wp[(size_t)k * 16], s);
        part[ch][e] = s;
    }
    __syncthreads();
    if (tid < 16) {
        float s = 0.f;
#pragma unroll
        for (int c = 0; c < 16; ++c) s += part[c][tid];
        sc[tid] = 1.f / (1.f + expf(-s));
    }
    __syncthreads();
    if (tid < 64) {
        int lane = tid, e = lane & 15;
        float scv = sc[e];
        unsigned sel = 0;
        float tw[4]; int ti[4];
#pragma unroll
        for (int kk = 0; kk < 4; ++kk) {
            float cand = ((sel >> e) & 1u) ? -1e30f : scv;
            float mx = cand;
            mx = fmaxf(mx, __shfl_xor(mx, 1));
            mx = fmaxf(mx, __shfl_xor(mx, 2));
            mx = fmaxf(mx, __shfl_xor(mx, 4));
            mx = fmaxf(mx, __shfl_xor(mx, 8));
            unsigned long long msk = __ballot(cand == mx);
            int bi = (__ffsll(msk) - 1) & 15;
            tw[kk] = mx; ti[kk] = bi;
            sel |= 1u << bi;
        }
        if (lane == 0) {
            float inv = 1.f / (tw[0] + tw[1] + tw[2] + tw[3]);
            toke[t] = make_int4(ti[0], ti[1], ti[2], ti[3]);
            tokw[t] = make_float4(tw[0] * inv, tw[1] * inv, tw[2] * inv, tw[3] * inv);
        }
    }
}

// ---------------- standalone MFMA GEMM (EPI 0 = f32 out): used for dq ----------------
__global__ __launch_bounds__(512)
void k_mgemm0(const short* __restrict__ A, const short* __restrict__ BT,
              float* __restrict__ C, int N, int K) {
    __shared__ __align__(16) short As[64 * 64];
    __shared__ __align__(16) short Bs[64 * 64];
    int tid = threadIdx.x;
    int w = tid >> 6, l = tid & 63, g = l >> 4, li = l & 15;
    int wm = w >> 1, wn = w & 1;
    int m0 = blockIdx.y * 64, n0 = blockIdx.x * 64;
    f32x4 acc[2] = {};
    for (int k0 = 0; k0 < K; k0 += 64) {
        __syncthreads();
        {
            int row = tid >> 3, ch = tid & 7;
            *(int4*)&As[row * 64 + ((ch ^ (row & 7)) * 8)] =
                *(const int4*)(A + (size_t)(m0 + row) * K + k0 + 8 * ch);
            int4 v = {0, 0, 0, 0};
            if (n0 + row < N) v = *(const int4*)(BT + (size_t)(n0 + row) * K + k0 + 8 * ch);
            *(int4*)&Bs[row * 64 + ((ch ^ (row & 7)) * 8)] = v;
        }
        __syncthreads();
#pragma unroll
        for (int kc = 0; kc < 2; ++kc) {
            int row = wm * 16 + li;
            s16x8 af = *(const s16x8*)&As[row * 64 + (((4 * kc + g) ^ (li & 7)) * 8)];
#pragma unroll
            for (int nt = 0; nt < 2; ++nt) {
                int n = wn * 32 + nt * 16 + li;
                s16x8 bf = *(const s16x8*)&Bs[n * 64 + (((4 * kc + g) ^ (li & 7)) * 8)];
                acc[nt] = __builtin_amdgcn_mfma_f32_16x16x32_bf16(af, bf, acc[nt], 0, 0, 0);
            }
        }
    }
#pragma unroll
    for (int nt = 0; nt < 2; ++nt)
#pragma unroll
        for (int r = 0; r < 4; ++r) {
            int gm = m0 + wm * 16 + 4 * g + r;
            int gn = n0 + wn * 32 + nt * 16 + li;
            if (gn < N) C[(size_t)gm * N + gn] = acc[nt][r];
        }
}

// ---------------- merged up-projections: uq (bx<12) || ukv (bx>=12) ----------------
__global__ __launch_bounds__(512)
void k_upproj(const short* __restrict__ cqnb, const short* __restrict__ wuqT,
              short* __restrict__ qcrb, short* __restrict__ qb,
              const short* __restrict__ ckvnb, const short* __restrict__ wukvT,
              short* __restrict__ kb, short* __restrict__ vbt) {
    __shared__ __align__(16) short As[64 * 64];
    __shared__ __align__(16) short Bs[64 * 64];
    int tid = threadIdx.x;
    int w = tid >> 6, l = tid & 63, g = l >> 4, li = l & 15;
    int wm = w >> 1, wn = w & 1;
    bool isQ = blockIdx.x < 12;
    const short* A  = isQ ? cqnb : ckvnb;
    const short* BT = isQ ? wuqT : wukvT;
    int N = isQ ? 768 : 1024;
    int K = isQ ? 256 : 128;
    int n0 = (isQ ? blockIdx.x : blockIdx.x - 12) * 64;
    int m0 = blockIdx.y * 64;
    f32x4 acc[2] = {};
    for (int k0 = 0; k0 < K; k0 += 64) {
        __syncthreads();
        {
            int row = tid >> 3, ch = tid & 7;
            *(int4*)&As[row * 64 + ((ch ^ (row & 7)) * 8)] =
                *(const int4*)(A + (size_t)(m0 + row) * K + k0 + 8 * ch);
            int4 v = {0, 0, 0, 0};
            if (n0 + row < N) v = *(const int4*)(BT + (size_t)(n0 + row) * K + k0 + 8 * ch);
            *(int4*)&Bs[row * 64 + ((ch ^ (row & 7)) * 8)] = v;
        }
        __syncthreads();
#pragma unroll
        for (int kc = 0; kc < 2; ++kc) {
            int row = wm * 16 + li;
            s16x8 af = *(const s16x8*)&As[row * 64 + (((4 * kc + g) ^ (li & 7)) * 8)];
#pragma unroll
            for (int nt = 0; nt < 2; ++nt) {
                int n = wn * 32 + nt * 16 + li;
                s16x8 bf = *(const s16x8*)&Bs[n * 64 + (((4 * kc + g) ^ (li & 7)) * 8)];
                acc[nt] = __builtin_amdgcn_mfma_f32_16x16x32_bf16(af, bf, acc[nt], 0, 0, 0);
            }
        }
    }
#pragma unroll
    for (int nt = 0; nt < 2; ++nt)
#pragma unroll
        for (int r = 0; r < 4; ++r) {
            int gm = m0 + wm * 16 + 4 * g + r;
            int gn = n0 + wn * 32 + nt * 16 + li;
            if (gn >= N) continue;
            float v = acc[nt][r];
            int b = gm >> 11, srow = gm & 2047;
            if (isQ) {
                int h = gn / 96, dd = gn - h * 96;
                int bh = b * 8 + h;
                if (dd < 64)
                    qb[((size_t)(bh * 2048 + srow)) * 96 + dd] = f2b(v * 0.14724389f);
                else
                    qcrb[(size_t)gm * 768 + gn] = f2b(v);
            } else {
                int h = gn >> 7, dd = gn & 127;
                int bh = b * 8 + h;
                if (dd < 64)
                    kb[((size_t)(bh * 2048 + srow)) * 96 + dd] = f2b(v);
                else
                    vbt[(size_t)bh * 64 * 2048 + (size_t)(dd - 64) * 2048 + srow] = f2b(v);
            }
        }
}

// ---------------- wo projection fused with attention partial combine ----------------
__global__ __launch_bounds__(512)
void k_wo_gemm(const short* __restrict__ po, const float* __restrict__ pl,
               const short* __restrict__ BT, float* __restrict__ C,
               const float* __restrict__ add) {
    constexpr int N = 512, K = 512;
    __shared__ __align__(16) short As[64 * 64];
    __shared__ __align__(16) short Bs[64 * 64];
    int tid = threadIdx.x;
    int w = tid >> 6, l = tid & 63, g = l >> 4, li = l & 15;
    int wm = w >> 1, wn = w & 1;
    int m0 = blockIdx.y * 64, n0 = blockIdx.x * 64;
    int row = tid >> 3, ch = tid & 7;
    int t = m0 + row;
    int b = t >> 11, q = t & 2047;
    f32x4 acc[2] = {};
    for (int k0 = 0; k0 < K; k0 += 64) {
        int h = k0 >> 6;
        int bhq = (b * 8 + h) * 2048 + q;
        size_t pb = (size_t)bhq * 256 + 8 * ch;
        float4 l4 = *(const float4*)(pl + (size_t)bhq * 4);
        float inv = 1.f / (l4.x + l4.y + l4.z + l4.w);
        union { int4 v; short s[8]; } p0, p1, p2, p3, ov;
        p0.v = *(const int4*)(po + pb);
        p1.v = *(const int4*)(po + pb + 64);
        p2.v = *(const int4*)(po + pb + 128);
        p3.v = *(const int4*)(po + pb + 192);
#pragma unroll
        for (int i = 0; i < 8; ++i) {
            float os = b2f(p0.s[i]) + b2f(p1.s[i]) + b2f(p2.s[i]) + b2f(p3.s[i]);
            ov.s[i] = f2b(os * inv);
        }
        int4 bv = *(const int4*)(BT + (size_t)(n0 + row) * K + k0 + 8 * ch);
        __syncthreads();
        *(int4*)&As[row * 64 + ((ch ^ (row & 7)) * 8)] = ov.v;
        *(int4*)&Bs[row * 64 + ((ch ^ (row & 7)) * 8)] = bv;
        __syncthreads();
#pragma unroll
        for (int kc = 0; kc < 2; ++kc) {
            int rr = wm * 16 + li;
            s16x8 af = *(const s16x8*)&As[rr * 64 + (((4 * kc + g) ^ (li & 7)) * 8)];
#pragma unroll
            for (int nt = 0; nt < 2; ++nt) {
                int n = wn * 32 + nt * 16 + li;
                s16x8 bf = *(const s16x8*)&Bs[n * 64 + (((4 * kc + g) ^ (li & 7)) * 8)];
                acc[nt] = __builtin_amdgcn_mfma_f32_16x16x32_bf16(af, bf, acc[nt], 0, 0, 0);
            }
        }
    }
#pragma unroll
    for (int nt = 0; nt < 2; ++nt)
#pragma unroll
        for (int r = 0; r < 4; ++r) {
            int gm = m0 + wm * 16 + 4 * g + r;
            int gn = n0 + wn * 32 + nt * 16 + li;
            C[(size_t)gm * N + gn] = acc[nt][r] + add[(size_t)gm * N + gn];
        }
}

// ---------------- rope-only build: q-rope from qcrb, k-rope from cqkv ----------------
__global__ void k_build_rope(const short* __restrict__ qcrb, const float* __restrict__ cqkv,
                             short* __restrict__ qb, short* __restrict__ kb) {
    const float scale = 0.14724389f;  // log2(e)/sqrt(96)
    int gid = blockIdx.x * 256 + threadIdx.x;
    const int NR = 16 * 2048 * 32;
    if (gid < NR) {
        int d2 = gid & 31;
        int rs = gid >> 5;
        int srow = rs & 2047;
        int bh = rs >> 11;
        int b = bh >> 3, h = bh & 7;
        int t = b * 2048 + srow;
        const short* src = qcrb + (size_t)t * 768 + h * 96;
        int fi = d2 & 15;
        float ang = (float)srow * __expf(-((float)(2 * fi) / 32.f) * 9.210340371976184f);
        float s, c; __sincosf(ang, &s, &c);
        float x = b2f(src[64 + d2]);
        float r = (d2 < 16) ? -b2f(src[64 + d2 + 16]) : b2f(src[64 + d2 - 16]);
        qb[((size_t)(bh * 2048 + srow)) * 96 + 64 + d2] = f2b((x * c + r * s) * scale);
    } else {
        int g2 = gid - NR;
        int d2 = g2 & 31;
        int rs = g2 >> 5;
        int srow = rs & 2047;
        int bh = rs >> 11;
        int b = bh >> 3;
        int t = b * 2048 + srow;
        int fi = d2 & 15;
        float ang = (float)srow * __expf(-((float)(2 * fi) / 32.f) * 9.210340371976184f);
        float s, c; __sincosf(ang, &s, &c);
        float x = cqkv[(size_t)t * 416 + 384 + d2];
        float r = (d2 < 16) ? -cqkv[(size_t)t * 416 + 384 + d2 + 16]
                            :  cqkv[(size_t)t * 416 + 384 + d2 - 16];
        kb[((size_t)(bh * 2048 + srow)) * 96 + 64 + d2] = f2b(x * c + r * s);
    }
}

// ---------------- K-split(4) MFMA flash attention, 32 q/wave, MFMA denominator ----------------
__global__ __launch_bounds__(256)
void k_attn(const short* __restrict__ qb, const short* __restrict__ kb,
            const short* __restrict__ vbt, short* __restrict__ po, float* __restrict__ pl) {
    __shared__ __align__(16) short Ks[64 * 100];
    __shared__ __align__(16) short Vs[80 * 64];
    int tid = threadIdx.x;
    int w = tid >> 6, l = tid & 63, g = l >> 4, li = l & 15;
    int blk = blockIdx.x;
    int bh = blk >> 6, rem = blk & 63;
    int qt = rem >> 2, ks = rem & 3;
    int qc0 = qt * 128 + w * 32;

    {
        const short one = 0x3F80;  // bf16 1.0
        for (int i = tid; i < 16 * 64; i += 256)
            Vs[64 * 64 + i] = (i < 64) ? one : (short)0;
    }

    s16x8 qf[2][3];
#pragma unroll
    for (int j = 0; j < 2; ++j) {
        const short* qp = qb + (size_t)(bh * 2048 + qc0 + j * 16 + li) * 96;
#pragma unroll
        for (int c = 0; c < 3; ++c) qf[j][c] = *(const s16x8*)(qp + 32 * c + 8 * g);
    }

    f32x4 o[2][5] = {};
    const short* kbase = kb + (size_t)bh * 2048 * 96;
    const short* vbase = vbt + (size_t)bh * 64 * 2048;

    for (int t = 0; t < 8; ++t) {
        int koff = ks * 512 + t * 64;
        __syncthreads();
#pragma unroll
        for (int p = 0; p < 3; ++p) {
            int flat = p * 256 + tid;
            int key = flat / 12, u = flat % 12;
            *(int4*)&Ks[key * 100 + 8 * u] = *(const int4*)(kbase + (size_t)(koff + key) * 96 + 8 * u);
        }
#pragma unroll
        for (int p = 0; p < 2; ++p) {
            int flat = p * 256 + tid;
            int dim = flat >> 3, kc8 = flat & 7;
            int4 v = *(const int4*)(vbase + (size_t)dim * 2048 + koff + 8 * kc8);
            int sw = dim & 15;
            *(int2*)&Vs[dim * 64 + (((2 * kc8) ^ sw) * 4)]     = make_int2(v.x, v.y);
            *(int2*)&Vs[dim * 64 + (((2 * kc8 + 1) ^ sw) * 4)] = make_int2(v.z, v.w);
        }
        __syncthreads();

        f32x4 s[2][4];
#pragma unroll
        for (int kt = 0; kt < 4; ++kt) {
            f32x4 a0 = {}, a1 = {};
#pragma unroll
            for (int c = 0; c < 3; ++c) {
                s16x8 kf = *(const s16x8*)&Ks[(kt * 16 + li) * 100 + 32 * c + 8 * g];
                a0 = __builtin_amdgcn_mfma_f32_16x16x32_bf16(kf, qf[0][c], a0, 0, 0, 0);
                a1 = __builtin_amdgcn_mfma_f32_16x16x32_bf16(kf, qf[1][c], a1, 0, 0, 0);
            }
            s[0][kt] = a0; s[1][kt] = a1;
        }
#pragma unroll
        for (int j = 0; j < 2; ++j)
#pragma unroll
            for (int kt = 0; kt < 4; ++kt)
#pragma unroll
                for (int r = 0; r < 4; ++r) s[j][kt][r] = exp2f(s[j][kt][r]);
        s16x8 pf[2][2];
#pragma unroll
        for (int j = 0; j < 2; ++j)
#pragma unroll
            for (int kc = 0; kc < 2; ++kc) {
                s16x8 tt;
#pragma unroll
                for (int r = 0; r < 4; ++r) { tt[r] = f2b(s[j][2 * kc][r]); tt[4 + r] = f2b(s[j][2 * kc + 1][r]); }
                pf[j][kc] = tt;
            }
#pragma unroll
        for (int dt = 0; dt < 5; ++dt) {
            int dim = dt * 16 + li;
#pragma unroll
            for (int kc = 0; kc < 2; ++kc) {
                int2 a0 = *(const int2*)&Vs[dim * 64 + (((8 * kc + g) ^ li) * 4)];
                int2 a1 = *(const int2*)&Vs[dim * 64 + (((8 * kc + 4 + g) ^ li) * 4)];
                union { s16x8 v; int i[4]; } vf;
                vf.i[0] = a0.x; vf.i[1] = a0.y; vf.i[2] = a1.x; vf.i[3] = a1.y;
                o[0][dt] = __builtin_amdgcn_mfma_f32_16x16x32_bf16(vf.v, pf[0][kc], o[0][dt], 0, 0, 0);
                o[1][dt] = __builtin_amdgcn_mfma_f32_16x16x32_bf16(vf.v, pf[1][kc], o[1][dt], 0, 0, 0);
            }
        }
    }
#pragma unroll
    for (int j = 0; j < 2; ++j) {
        int qcol = qc0 + j * 16 + li;
        size_t qbase = ((size_t)(bh * 2048 + qcol) * 4 + ks) * 64;
#pragma unroll
        for (int dt = 0; dt < 4; ++dt) {
            union { short s[4]; int2 v; } pk;
#pragma unroll
            for (int r = 0; r < 4; ++r) pk.s[r] = f2b(o[j][dt][r]);
            *(int2*)(po + qbase + dt * 16 + 4 * g) = pk.v;
        }
        if (g == 0) pl[(size_t)(bh * 2048 + qcol) * 4 + ks] = o[j][4][0];
    }
}

// ---------------- merged: shared expert (blocks 0..255) || scatter (blocks 256..271) ------------
__global__ __launch_bounds__(512)
void k_shexp_scatter(const short* __restrict__ X, const short* __restrict__ WGt,
                     const short* __restrict__ WUt, short* __restrict__ gact,
                     const int4* __restrict__ toke, const float4* __restrict__ tokw,
                     float* __restrict__ ewt, int* __restrict__ ecnt, int* __restrict__ etok) {
    __shared__ __align__(16) short As[64 * 64];
    __shared__ __align__(16) short Bg[64 * 64];
    __shared__ __align__(16) short Bu[64 * 64];
    __shared__ int lcnt[16];
    __shared__ int lbase[16];
    int bid = blockIdx.x, tid = threadIdx.x;
    if (bid < 256) {
        int w = tid >> 6, l = tid & 63, g = l >> 4, li = l & 15;
        int wm = w >> 1, wn = w & 1;
        int m0 = (bid & 63) * 64, n0 = (bid >> 6) * 64;
        f32x4 ag[2] = {}, au[2] = {};
        for (int k0 = 0; k0 < 512; k0 += 64) {
            __syncthreads();
            {
                int row = tid >> 3, ch = tid & 7;
                *(int4*)&As[row * 64 + ((ch ^ (row & 7)) * 8)] =
                    *(const int4*)(X + (size_t)(m0 + row) * 512 + k0 + 8 * ch);
                *(int4*)&Bg[row * 64 + ((ch ^ (row & 7)) * 8)] =
                    *(const int4*)(WGt + (size_t)(n0 + row) * 512 + k0 + 8 * ch);
                *(int4*)&Bu[row * 64 + ((ch ^ (row & 7)) * 8)] =
                    *(const int4*)(WUt + (size_t)(n0 + row) * 512 + k0 + 8 * ch);
            }
            __syncthreads();
#pragma unroll
            for (int kc = 0; kc < 2; ++kc) {
                int row = wm * 16 + li;
                s16x8 af = *(const s16x8*)&As[row * 64 + (((4 * kc + g) ^ (li & 7)) * 8)];
#pragma unroll
                for (int nt = 0; nt < 2; ++nt) {
                    int n = wn * 32 + nt * 16 + li;
                    s16x8 bg = *(const s16x8*)&Bg[n * 64 + (((4 * kc + g) ^ (li & 7)) * 8)];
                    s16x8 bu = *(const s16x8*)&Bu[n * 64 + (((4 * kc + g) ^ (li & 7)) * 8)];
                    ag[nt] = __builtin_amdgcn_mfma_f32_16x16x32_bf16(af, bg, ag[nt], 0, 0, 0);
                    au[nt] = __builtin_amdgcn_mfma_f32_16x16x32_bf16(af, bu, au[nt], 0, 0, 0);
                }
            }
        }
#pragma unroll
        for (int nt = 0; nt < 2; ++nt)
#pragma unroll
            for (int r = 0; r < 4; ++r) {
                int gm = m0 + (tid >> 6 >> 1) * 16 + 4 * ((tid & 63) >> 4) + r;
                int gn = n0 + ((tid >> 6) & 1) * 32 + nt * 16 + (tid & 15);
                float gv = ag[nt][r], uv = au[nt][r];
                gact[(size_t)gm * 256 + gn] = f2b(gv / (1.f + __expf(-gv)) * uv);
            }
    } else {
        int sb = bid - 256;
        bool act = tid < 256;
        int t = sb * 256 + (tid & 255);
        if (tid < 16) lcnt[tid] = 0;
        __syncthreads();
        int es[4]; float wv[4]; int ls[4] = {0, 0, 0, 0};
        if (act) {
            int4 e4 = toke[t];
            float4 w4 = tokw[t];
            es[0] = e4.x; es[1] = e4.y; es[2] = e4.z; es[3] = e4.w;
            wv[0] = w4.x; wv[1] = w4.y; wv[2] = w4.z; wv[3] = w4.w;
#pragma unroll
            for (int kk = 0; kk < 4; ++kk) ls[kk] = atomicAdd(&lcnt[es[kk]], 1);
        }
        __syncthreads();
        if (tid < 16) lbase[tid] = atomicAdd(&ecnt[tid], lcnt[tid]);
        __syncthreads();
        if (act) {
#pragma unroll
            for (int kk = 0; kk < 4; ++kk) {
                int slot = lbase[es[kk]] + ls[kk];
                etok[es[kk] * 4096 + slot] = t * 4 + kk;
                ewt[es[kk] * 4096 + slot] = wv[kk];
            }
        }
    }
}

// ---------------- merged: shared-down GEMM (blocks 0..511) || MoE1 (blocks 512..1087) -----------
__global__ __launch_bounds__(512)
void k_shd_moe1(const short* __restrict__ gact, const short* __restrict__ shwdT,
                float* __restrict__ outF, const float* __restrict__ r2,
                const short* __restrict__ X, const short* __restrict__ WGt,
                const short* __restrict__ WUt,
                const int* __restrict__ ecnt, const int* __restrict__ etok,
                short* __restrict__ eact) {
    __shared__ __align__(16) short smem[16384];   // 32 KB carve
    __shared__ int toks[128];
    __shared__ int ecs[16];
    int bid = blockIdx.x, tid = threadIdx.x;
    int w = tid >> 6, l = tid & 63, g = l >> 4, li = l & 15;
    int wm = w >> 1, wn = w & 1;
    if (bid < 512) {
        // ---- shared-expert down projection: C[4096][512] = gact @ shwdT^T + r2 ----
        short* As = smem;              // 64*64
        short* Bs = smem + 4096;       // 64*64
        constexpr int N = 512, K = 256;
        int n0 = (bid & 7) * 64, m0 = (bid >> 3) * 64;
        f32x4 acc[2] = {};
        for (int k0 = 0; k0 < K; k0 += 64) {
            __syncthreads();
            {
                int row = tid >> 3, ch = tid & 7;
                *(int4*)&As[row * 64 + ((ch ^ (row & 7)) * 8)] =
                    *(const int4*)(gact + (size_t)(m0 + row) * K + k0 + 8 * ch);
                *(int4*)&Bs[row * 64 + ((ch ^ (row & 7)) * 8)] =
                    *(const int4*)(shwdT + (size_t)(n0 + row) * K + k0 + 8 * ch);
            }
            __syncthreads();
#pragma unroll
            for (int kc = 0; kc < 2; ++kc) {
                int row = wm * 16 + li;
                s16x8 af = *(const s16x8*)&As[row * 64 + (((4 * kc + g) ^ (li & 7)) * 8)];
#pragma unroll
                for (int nt = 0; nt < 2; ++nt) {
                    int n = wn * 32 + nt * 16 + li;
                    s16x8 bf = *(const s16x8*)&Bs[n * 64 + (((4 * kc + g) ^ (li & 7)) * 8)];
                    acc[nt] = __builtin_amdgcn_mfma_f32_16x16x32_bf16(af, bf, acc[nt], 0, 0, 0);
                }
            }
        }
#pragma unroll
        for (int nt = 0; nt < 2; ++nt)
#pragma unroll
            for (int r = 0; r < 4; ++r) {
                int gm = m0 + wm * 16 + 4 * g + r;
                int gn = n0 + wn * 32 + nt * 16 + li;
                outF[(size_t)gm * N + gn] = acc[nt][r] + r2[(size_t)gm * N + gn];
            }
    } else {
        // ---- MoE stage 1 with inline tile-scan + XCD swizzle ----
        short* As = smem;              // 128*64
        short* Bg = smem + 8192;       // 64*64
        short* Bu = smem + 12288;      // 64*64
        if (tid < 16) ecs[tid] = ecnt[tid];
        __syncthreads();
        int lin = bid - 512;                           // 0..575, (bid%8 == lin%8 since 512%8==0)
        int virt = (lin & 7) * 72 + (lin >> 3);        // bijective chunked swizzle
        int tb = virt >> 2;
        int n0 = (virt & 3) * 64;
        int e = 0;
        for (; e < 16; ++e) { int n = (ecs[e] + 127) >> 7; if (tb < n) break; tb -= n; }
        if (e >= 16) return;
        int base = tb << 7;
        int rows = min(128, ecs[e] - base);
        if (tid < 128) toks[tid] = (tid < rows) ? etok[e * 4096 + base + tid] : -1;
        __syncthreads();
        const short* wgp = WGt + (size_t)e * 256 * 512;
        const short* wup = WUt + (size_t)e * 256 * 512;
        f32x4 ag[2][2] = {}, au[2][2] = {};
        for (int k0 = 0; k0 < 512; k0 += 64) {
            __syncthreads();
#pragma unroll
            for (int p = 0; p < 2; ++p) {
                int flat = p * 512 + tid;
                int row = flat >> 3, ch = flat & 7;
                int tk = toks[row];
                int4 v = {0, 0, 0, 0};
                if (tk >= 0) v = *(const int4*)(X + (size_t)(tk >> 2) * 512 + k0 + 8 * ch);
                *(int4*)&As[row * 64 + ((ch ^ (row & 7)) * 8)] = v;
            }
            {
                int n = tid >> 3, ch = tid & 7;
                *(int4*)&Bg[n * 64 + ((ch ^ (n & 7)) * 8)] = *(const int4*)(wgp + (size_t)(n0 + n) * 512 + k0 + 8 * ch);
                *(int4*)&Bu[n * 64 + ((ch ^ (n & 7)) * 8)] = *(const int4*)(wup + (size_t)(n0 + n) * 512 + k0 + 8 * ch);
            }
            __syncthreads();
#pragma unroll
            for (int kc = 0; kc < 2; ++kc) {
                s16x8 af[2], bg[2], bu[2];
#pragma unroll
                for (int mt = 0; mt < 2; ++mt) {
                    int row = wm * 32 + mt * 16 + li;
                    af[mt] = *(const s16x8*)&As[row * 64 + (((4 * kc + g) ^ (li & 7)) * 8)];
                }
#pragma unroll
                for (int nt = 0; nt < 2; ++nt) {
                    int n = wn * 32 + nt * 16 + li;
                    bg[nt] = *(const s16x8*)&Bg[n * 64 + (((4 * kc + g) ^ (li & 7)) * 8)];
                    bu[nt] = *(const s16x8*)&Bu[n * 64 + (((4 * kc + g) ^ (li & 7)) * 8)];
                }
#pragma unroll
                for (int mt = 0; mt < 2; ++mt)
#pragma unroll
                    for (int nt = 0; nt < 2; ++nt) {
                        ag[mt][nt] = __builtin_amdgcn_mfma_f32_16x16x32_bf16(af[mt], bg[nt], ag[mt][nt], 0, 0, 0);
                        au[mt][nt] = __builtin_amdgcn_mfma_f32_16x16x32_bf16(af[mt], bu[nt], au[mt][nt], 0, 0, 0);
                    }
            }
        }
#pragma unroll
        for (int mt = 0; mt < 2; ++mt)
#pragma unroll
            for (int nt = 0; nt < 2; ++nt)
#pragma unroll
                for (int r = 0; r < 4; ++r) {
                    int local = wm * 32 + mt * 16 + 4 * g + r;
                    if (local < rows) {
                        int entry = toks[local];
                        int gn = n0 + wn * 32 + nt * 16 + li;
                        float gv = ag[mt][nt][r], uv = au[mt][nt][r];
                        eact[(size_t)entry * 256 + gn] = f2b(gv / (1.f + __expf(-gv)) * uv);
                    }
                }
    }
}

// ---------------- MoE stage 2 (MFMA, 8 waves, inline tile-scan, XCD swizzle) --------------------
__global__ __launch_bounds__(512)
void k_moe2m(const short* __restrict__ EA, const short* __restrict__ WDt,
             const int* __restrict__ ecnt, const int* __restrict__ etok,
             const float* __restrict__ ewt, float* __restrict__ oacc) {
    __shared__ int ecs[16];
    __shared__ __align__(16) short As[128 * 64];
    __shared__ __align__(16) short Bs[64 * 64];
    __shared__ int toks[128];
    __shared__ float wts[128];
    int tid = threadIdx.x;
    if (tid < 16) ecs[tid] = ecnt[tid];
    __syncthreads();
    int lin = blockIdx.x + 144 * blockIdx.y;
    int virt = (lin & 7) * 144 + (lin >> 3);
    int bid = virt >> 3;
    int n0 = (virt & 7) * 64;
    int e = 0;
    for (; e < 16; ++e) { int n = (ecs[e] + 127) >> 7; if (bid < n) break; bid -= n; }
    if (e >= 16) return;
    int base = bid << 7;
    int rows = min(128, ecs[e] - base);
    if (tid < 128) {
        toks[tid] = (tid < rows) ? etok[e * 4096 + base + tid] : -1;
        wts[tid]  = (tid < rows) ? ewt[e * 4096 + base + tid] : 0.f;
    }
    __syncthreads();
    int w = tid >> 6, l = tid & 63, g = l >> 4, li = l & 15;
    int wm = w >> 1, wn = w & 1;
    const short* wdp = WDt + (size_t)e * 512 * 256;
    f32x4 acc[2][2] = {};
    for (int k0 = 0; k0 < 256; k0 += 64) {
        __syncthreads();
#pragma unroll
        for (int p = 0; p < 2; ++p) {
            int flat = p * 512 + tid;
            int row = flat >> 3, ch = flat & 7;
            int tk = toks[row];
            int4 v = {0, 0, 0, 0};
            if (tk >= 0) v = *(const int4*)(EA + (size_t)tk * 256 + k0 + 8 * ch);
            *(int4*)&As[row * 64 + ((ch ^ (row & 7)) * 8)] = v;
        }
        {
            int n = tid >> 3, ch = tid & 7;
            *(int4*)&Bs[n * 64 + ((ch ^ (n & 7)) * 8)] = *(const int4*)(wdp + (size_t)(n0 + n) * 256 + k0 + 8 * ch);
        }
        __syncthreads();
#pragma unroll
        for (int kc = 0; kc < 2; ++kc) {
            s16x8 af[2], bf[2];
#pragma unroll
            for (int mt = 0; mt < 2; ++mt) {
                int row = wm * 32 + mt * 16 + li;
                af[mt] = *(const s16x8*)&As[row * 64 + (((4 * kc + g) ^ (li & 7)) * 8)];
            }
#pragma unroll
            for (int nt = 0; nt < 2; ++nt) {
                int n = wn * 32 + nt * 16 + li;
                bf[nt] = *(const s16x8*)&Bs[n * 64 + (((4 * kc + g) ^ (li & 7)) * 8)];
            }
#pragma unroll
            for (int mt = 0; mt < 2; ++mt)
#pragma unroll
                for (int nt = 0; nt < 2; ++nt)
                    acc[mt][nt] = __builtin_amdgcn_mfma_f32_16x16x32_bf16(af[mt], bf[nt], acc[mt][nt], 0, 0, 0);
        }
    }
#pragma unroll
    for (int mt = 0; mt < 2; ++mt)
#pragma unroll
        for (int nt = 0; nt < 2; ++nt)
#pragma unroll
            for (int r = 0; r < 4; ++r) {
                int local = wm * 32 + mt * 16 + 4 * g + r;
                if (local < rows) {
                    int tok = toks[local] >> 2;
                    int gn = n0 + wn * 32 + nt * 16 + li;
                    atomicAdd(&oacc[(size_t)tok * 512 + gn], acc[mt][nt][r] * wts[local]);
                }
            }
}

// ---------------- host launcher ----------------
extern "C" void kernel_launch(void* const* d_in, const int* in_sizes, int n_in,
                              void* d_out, int out_size, void* d_ws, size_t ws_size,
                              hipStream_t stream) {
    const float* hs       = (const float*)d_in[0];
    const float* w_innorm = (const float*)d_in[1];
    const float* w_dq     = (const float*)d_in[2];
    const float* w_qnorm  = (const float*)d_in[3];
    const float* w_uq     = (const float*)d_in[4];
    const float* w_dkv    = (const float*)d_in[5];
    const float* w_kvnorm = (const float*)d_in[6];
    const float* w_ukv    = (const float*)d_in[7];
    const float* w_o      = (const float*)d_in[8];
    const float* w_post   = (const float*)d_in[9];
    const float* w_gate   = (const float*)d_in[10];
    const float* sh_wg    = (const float*)d_in[11];
    const float* sh_wu    = (const float*)d_in[12];
    const float* sh_wd    = (const float*)d_in[13];
    const float* r_wg     = (const float*)d_in[14];
    const float* r_wu     = (const float*)d_in[15];
    const float* r_wd     = (const float*)d_in[16];

    float* ws   = (float*)d_ws;
    float* cqkv = ws + OFF_CQKV;
    short* qcrb = (short*)(ws + OFF_QCR);
    float* r2   = ws + OFF_R2;
    short* po   = (short*)(ws + OFF_PO);
    float* pl   = ws + OFF_PL;
    int4*  toke = (int4*)(ws + OFF_TOKE);
    float4* tokw = (float4*)(ws + OFF_TOKW);
    float* ewt  = ws + OFF_EWT;
    int*   ecnt = (int*)(ws + OFF_ECNT);
    int*   etok = (int*)(ws + OFF_ETOK);
    short* xnb   = (short*)(ws + OFF_XNB);
    short* cqnb  = (short*)(ws + OFF_CQNB);
    short* ckvnb = (short*)(ws + OFF_CKVNB);
    short* qb    = (short*)(ws + OFF_QB);
    short* kb    = (short*)(ws + OFF_KB);
    short* vbt   = (short*)(ws + OFF_VBT);
    short* xn2b  = (short*)(ws + OFF_XN2B);
    short* gact  = (short*)(ws + OFF_GACT);
    short* eact  = (short*)(ws + OFF_EACT);
    short* wqkvT = (short*)(ws + OFF_WQKVT);
    short* wuqT  = (short*)(ws + OFF_WUQT);
    short* wukvT = (short*)(ws + OFF_WUKVT);
    short* woT   = (short*)(ws + OFF_WOT);
    short* shwgT = (short*)(ws + OFF_SHWGT);
    short* shwuT = (short*)(ws + OFF_SHWUT);
    short* shwdT = (short*)(ws + OFF_SHWDT);
    short* rwgT  = (short*)(ws + OFF_RWGT);
    short* rwuT  = (short*)(ws + OFF_RWUT);
    short* rwdT  = (short*)(ws + OFF_RWDT);

    float* outF = (float*)d_out;

    // 0+1. merged: weight convert+transpose || input RMSNorm (zeroes ecnt)
    CvtTab tab;
    const float* srcs[11] = { w_dq, w_dkv, w_uq, w_ukv, w_o, sh_wg, sh_wu, sh_wd, r_wg, r_wu, r_wd };
    short* dsts[11] = { wqkvT, wqkvT + (size_t)256 * 512, wuqT, wukvT, woT, shwgT, shwuT, shwdT, rwgT, rwuT, rwdT };
    int Ks_[11] = { 512, 512, 256, 128, 512, 512, 512, 256, 512, 512, 256 };
    int Ns_[11] = { 256, 160, 768, 1024, 512, 256, 256, 512, 256, 256, 512 };
    int Es_[11] = { 1, 1, 1, 1, 1, 1, 1, 1, 16, 16, 16 };
    int cum = 0;
    for (int i = 0; i < 11; ++i) {
        tab.src[i] = srcs[i]; tab.dst[i] = dsts[i];
        tab.K[i] = Ks_[i]; tab.N[i] = Ns_[i];
        cum += Es_[i] * (Ks_[i] >> 5) * (Ns_[i] >> 5);
        tab.end[i] = cum;
    }
    k_cvt_rms<<<CVT_BLOCKS + Tt, 256, 0, stream>>>(tab, hs, w_innorm, xnb, ecnt);

    // 2. fused down-projection (dq|dkv), N=416, f32 out
    k_mgemm0<<<dim3(7, 64), 512, 0, stream>>>(xnb, wqkvT, cqkv, 416, 512);
    // 3. fused latent norms -> bf16
    k_rms2<<<2 * Tt, 256, 0, stream>>>(cqkv, w_qnorm, cqnb, w_kvnorm, ckvnb);
    // 4. merged up-projections (uq scatter || ukv scatter)
    k_upproj<<<dim3(28, 64), 512, 0, stream>>>(cqnb, wuqT, qcrb, qb, ckvnb, wukvT, kb, vbt);
    // 5. rope-only build
    k_build_rope<<<(2 * 16 * 2048 * 32) / 256, 256, 0, stream>>>(qcrb, cqkv, qb, kb);
    // 6. K-split(4) MFMA flash attention
    k_attn<<<1024, 256, 0, stream>>>(qb, kb, vbt, po, pl);
    // 7. wo projection fused with partial combine + residual
    k_wo_gemm<<<dim3(8, 64), 512, 0, stream>>>(po, pl, woT, r2, hs);
    // 8. fused post-norm + router
    k_rms_router<<<Tt, 256, 0, stream>>>(r2, w_post, w_gate, xn2b, toke, tokw);
    // 9. merged: shared-expert up || scatter
    k_shexp_scatter<<<272, 512, 0, stream>>>(xn2b, shwgT, shwuT, gact, toke, tokw, ewt, ecnt, etok);
    // 10. merged: shared-expert down (into d_out) || MoE1
    k_shd_moe1<<<1088, 512, 0, stream>>>(gact, shwdT, outF, r2, xn2b, rwgT, rwuT, ecnt, etok, eact);
    // 11. MoE2 (atomic accumulate into d_out)
    k_moe2m<<<dim3(144, 8), 512, 0, stream>>>(eact, rwdT, ecnt, etok, ewt, outF);
}

// Round 22
// 200.868 us; speedup vs baseline: 1.2039x; 1.0268x over previous
//
#include <hip/hip_runtime.h>
#include <hip/hip_bf16.h>
#include <math.h>

typedef float f32x4 __attribute__((ext_vector_type(4)));
typedef short s16x8 __attribute__((ext_vector_type(8)));

// ---------------- problem constants ----------------
constexpr int Tt = 4096;
constexpr int NEn = 16;
constexpr float EPSf = 1.1920929e-07f;
constexpr int CVT_BLOCKS = 7312;   // total 32x32 tiles across all 11 weight tensors

__device__ __forceinline__ short f2b(float f) {
    union { __hip_bfloat16 h; short s; } u;
    u.h = __float2bfloat16(f);
    return u.s;
}
__device__ __forceinline__ float b2f(short s) {
    union { float f; unsigned u; } v;
    v.u = ((unsigned)(unsigned short)s) << 16;
    return v.f;
}

// ---------------- workspace layout (float elements, 16-float aligned) ----------------
constexpr size_t alg(size_t x) { return (x + 15) & ~(size_t)15; }
constexpr size_t OFF_CQKV = 0;                                   // T*416 f32
constexpr size_t OFF_QCR  = alg(OFF_CQKV + (size_t)Tt * 416);    // (free; layout stability)
constexpr size_t OFF_KVB  = alg(OFF_QCR  + (size_t)Tt * 768);    // (unused; layout stability)
constexpr size_t OFF_R2   = alg(OFF_KVB  + (size_t)Tt * 1024);   // T*512 f32
constexpr size_t OFF_TOKE = alg(OFF_R2   + (size_t)Tt * 512);    // T*4 ints
constexpr size_t OFF_TOKW = alg(OFF_TOKE + (size_t)Tt * 4);      // T*4 f32
constexpr size_t OFF_EWT  = alg(OFF_TOKW + (size_t)Tt * 4);      // 16*4096 f32
constexpr size_t OFF_ECNT = alg(OFF_EWT  + (size_t)NEn * Tt);    // ints
constexpr size_t OFF_ETOK = alg(OFF_ECNT + 64);                  // 16*4096 ints
constexpr size_t OFF_PO   = 0;                                   // bf16 partials alias dead region
constexpr size_t OFF_PL   = (size_t)16 * 2048 * 4 * 64 / 2;      // f32
constexpr size_t OFF_XNB   = alg(OFF_ETOK + (size_t)NEn * Tt);
constexpr size_t OFF_CQNB  = alg(OFF_XNB   + (size_t)Tt * 512 / 2);
constexpr size_t OFF_CKVNB = alg(OFF_CQNB  + (size_t)Tt * 256 / 2);
constexpr size_t OFF_QB    = alg(OFF_CKVNB + (size_t)Tt * 128 / 2);
constexpr size_t OFF_KB    = alg(OFF_QB    + (size_t)16 * 2048 * 96 / 2);
constexpr size_t OFF_VBT   = alg(OFF_KB    + (size_t)16 * 2048 * 96 / 2);
constexpr size_t OFF_XN2B  = alg(OFF_VBT   + (size_t)16 * 64 * 2048 / 2);
constexpr size_t OFF_GACT  = alg(OFF_XN2B  + (size_t)Tt * 512 / 2);
constexpr size_t OFF_EACT  = alg(OFF_GACT  + (size_t)Tt * 256 / 2);
constexpr size_t OFF_WQKVT = alg(OFF_EACT  + (size_t)16384 * 256 / 2);
constexpr size_t OFF_WUQT  = alg(OFF_WQKVT + (size_t)416 * 512 / 2);
constexpr size_t OFF_WUKVT = alg(OFF_WUQT  + (size_t)768 * 256 / 2);
constexpr size_t OFF_WOT   = alg(OFF_WUKVT + (size_t)1024 * 128 / 2);
constexpr size_t OFF_SHWGT = alg(OFF_WOT   + (size_t)512 * 512 / 2);
constexpr size_t OFF_SHWUT = alg(OFF_SHWGT + (size_t)256 * 512 / 2);
constexpr size_t OFF_SHWDT = alg(OFF_SHWUT + (size_t)256 * 512 / 2);
constexpr size_t OFF_RWGT  = alg(OFF_SHWDT + (size_t)512 * 256 / 2);
constexpr size_t OFF_RWUT  = alg(OFF_RWGT  + (size_t)16 * 256 * 512 / 2);
constexpr size_t OFF_RWDT  = alg(OFF_RWUT  + (size_t)16 * 256 * 512 / 2);

struct CvtTab {
    const float* src[11];
    short* dst[11];
    int K[11], N[11], end[11];
};

// ---------------- merged: weight convert+transpose  ||  input RMSNorm ----------------
__global__ __launch_bounds__(256)
void k_cvt_rms(CvtTab tab, const float* __restrict__ in, const float* __restrict__ w,
               short* __restrict__ outB, int* __restrict__ ecnt) {
    __shared__ float t[32][33];
    __shared__ float xs[512];
    __shared__ float red[256];
    int bid = blockIdx.x, tid = threadIdx.x;
    if (bid < CVT_BLOCKS) {
        int i = 0;
        while (bid >= tab.end[i]) ++i;
        int tloc = bid - (i ? tab.end[i - 1] : 0);
        int K = tab.K[i], N = tab.N[i];
        int ntiles = N >> 5, perE = ntiles * (K >> 5);
        int e = tloc / perE, rem = tloc - e * perE;
        int k0 = (rem / ntiles) << 5, n0 = (rem % ntiles) << 5;
        size_t eo = (size_t)e * K * N;
        const float* src = tab.src[i];
        short* dst = tab.dst[i];
        int c = tid & 31, r = tid >> 5;
#pragma unroll
        for (int q = 0; q < 4; ++q)
            t[r + 8 * q][c] = src[eo + (size_t)(k0 + r + 8 * q) * N + n0 + c];
        __syncthreads();
#pragma unroll
        for (int q = 0; q < 4; ++q)
            dst[eo + (size_t)(n0 + r + 8 * q) * K + k0 + c] = f2b(t[c][r + 8 * q]);
    } else {
        int row = bid - CVT_BLOCKS;
        if (row == 0 && tid < 16) ecnt[tid] = 0;
        const float* ip = in + (size_t)row * 512;
        float ss = 0.f;
        for (int i = tid; i < 512; i += 256) { float v = ip[i]; xs[i] = v; ss += v * v; }
        red[tid] = ss; __syncthreads();
        for (int s = 128; s > 0; s >>= 1) { if (tid < s) red[tid] += red[tid + s]; __syncthreads(); }
        float sc = rsqrtf(red[0] / 512.f + EPSf);
        for (int i = tid; i < 512; i += 256) outB[(size_t)row * 512 + i] = f2b(xs[i] * sc * w[i]);
    }
}

// ---------------- fused latent RMSNorm pair (blocks 0..8191) || k-rope build (blocks 8192..) ----
__global__ void k_rms2(const float* __restrict__ cqkv, const float* __restrict__ wq, short* __restrict__ cqnb,
                       const float* __restrict__ wkv, short* __restrict__ ckvnb, short* __restrict__ kb) {
    int row = blockIdx.x, tid = threadIdx.x;
    if (row >= 2 * Tt) {
        // k-rope: kb[bh][srow][64+d2] from cqkv[t][384+d2]
        int g2 = (row - 2 * Tt) * 256 + tid;   // 0 .. 16*2048*32-1
        int d2 = g2 & 31;
        int rs = g2 >> 5;
        int srow = rs & 2047;
        int bh = rs >> 11;
        int b = bh >> 3;
        int t = b * 2048 + srow;
        int fi = d2 & 15;
        float ang = (float)srow * __expf(-((float)(2 * fi) / 32.f) * 9.210340371976184f);
        float s, c; __sincosf(ang, &s, &c);
        float x = cqkv[(size_t)t * 416 + 384 + d2];
        float r = (d2 < 16) ? -cqkv[(size_t)t * 416 + 384 + d2 + 16]
                            :  cqkv[(size_t)t * 416 + 384 + d2 - 16];
        kb[((size_t)(bh * 2048 + srow)) * 96 + 64 + d2] = f2b(x * c + r * s);
        return;
    }
    __shared__ float xs[256];
    __shared__ float red[256];
    const float* ip; const float* w; short* ob; int D, outStride, r;
    if (row < Tt) { r = row;      ip = cqkv + (size_t)r * 416;       w = wq;  ob = cqnb;  D = 256; outStride = 256; }
    else          { r = row - Tt; ip = cqkv + (size_t)r * 416 + 256; w = wkv; ob = ckvnb; D = 128; outStride = 128; }
    float ss = 0.f;
    for (int i = tid; i < D; i += 256) { float v = ip[i]; xs[i] = v; ss += v * v; }
    red[tid] = ss; __syncthreads();
    for (int s = 128; s > 0; s >>= 1) { if (tid < s) red[tid] += red[tid + s]; __syncthreads(); }
    float sc = rsqrtf(red[0] / (float)D + EPSf);
    for (int i = tid; i < D; i += 256) ob[(size_t)r * outStride + i] = f2b(xs[i] * sc * w[i]);
}

// ---------------- fused post-RMSNorm + router ----------------
__global__ __launch_bounds__(256)
void k_rms_router(const float* __restrict__ r2, const float* __restrict__ wpost,
                  const float* __restrict__ wg,
                  short* __restrict__ xn2b, int4* __restrict__ toke, float4* __restrict__ tokw) {
    int t = blockIdx.x, tid = threadIdx.x;
    __shared__ float xs[512];
    __shared__ float red[256];
    __shared__ float part[16][17];
    __shared__ float sc[16];
    const float* ip = r2 + (size_t)t * 512;
    float ss = 0.f;
    for (int i = tid; i < 512; i += 256) { float v = ip[i]; xs[i] = v; ss += v * v; }
    red[tid] = ss; __syncthreads();
    for (int s = 128; s > 0; s >>= 1) { if (tid < s) red[tid] += red[tid + s]; __syncthreads(); }
    float scale = rsqrtf(red[0] / 512.f + EPSf);
    for (int i = tid; i < 512; i += 256) {
        float v = xs[i] * scale * wpost[i];
        xs[i] = v;
        xn2b[(size_t)t * 512 + i] = f2b(v);
    }
    __syncthreads();
    {
        int e = tid & 15, ch = tid >> 4;
        const float* wp = wg + (size_t)ch * 32 * 16 + e;
        float s = 0.f;
#pragma unroll 8
        for (int k = 0; k < 32; ++k) s = fmaf(xs[ch * 32 + k], wp[(size_t)k * 16], s);
        part[ch][e] = s;
    }
    __syncthreads();
    if (tid < 16) {
        float s = 0.f;
#pragma unroll
        for (int c = 0; c < 16; ++c) s += part[c][tid];
        sc[tid] = 1.f / (1.f + expf(-s));
    }
    __syncthreads();
    if (tid < 64) {
        int lane = tid, e = lane & 15;
        float scv = sc[e];
        unsigned sel = 0;
        float tw[4]; int ti[4];
#pragma unroll
        for (int kk = 0; kk < 4; ++kk) {
            float cand = ((sel >> e) & 1u) ? -1e30f : scv;
            float mx = cand;
            mx = fmaxf(mx, __shfl_xor(mx, 1));
            mx = fmaxf(mx, __shfl_xor(mx, 2));
            mx = fmaxf(mx, __shfl_xor(mx, 4));
            mx = fmaxf(mx, __shfl_xor(mx, 8));
            unsigned long long msk = __ballot(cand == mx);
            int bi = (__ffsll(msk) - 1) & 15;
            tw[kk] = mx; ti[kk] = bi;
            sel |= 1u << bi;
        }
        if (lane == 0) {
            float inv = 1.f / (tw[0] + tw[1] + tw[2] + tw[3]);
            toke[t] = make_int4(ti[0], ti[1], ti[2], ti[3]);
            tokw[t] = make_float4(tw[0] * inv, tw[1] * inv, tw[2] * inv, tw[3] * inv);
        }
    }
}

// ---------------- standalone MFMA GEMM (f32 out): used for dq ----------------
__global__ __launch_bounds__(512)
void k_mgemm0(const short* __restrict__ A, const short* __restrict__ BT,
              float* __restrict__ C, int N, int K) {
    __shared__ __align__(16) short As[64 * 64];
    __shared__ __align__(16) short Bs[64 * 64];
    int tid = threadIdx.x;
    int w = tid >> 6, l = tid & 63, g = l >> 4, li = l & 15;
    int wm = w >> 1, wn = w & 1;
    int m0 = blockIdx.y * 64, n0 = blockIdx.x * 64;
    f32x4 acc[2] = {};
    for (int k0 = 0; k0 < K; k0 += 64) {
        __syncthreads();
        {
            int row = tid >> 3, ch = tid & 7;
            *(int4*)&As[row * 64 + ((ch ^ (row & 7)) * 8)] =
                *(const int4*)(A + (size_t)(m0 + row) * K + k0 + 8 * ch);
            int4 v = {0, 0, 0, 0};
            if (n0 + row < N) v = *(const int4*)(BT + (size_t)(n0 + row) * K + k0 + 8 * ch);
            *(int4*)&Bs[row * 64 + ((ch ^ (row & 7)) * 8)] = v;
        }
        __syncthreads();
#pragma unroll
        for (int kc = 0; kc < 2; ++kc) {
            int row = wm * 16 + li;
            s16x8 af = *(const s16x8*)&As[row * 64 + (((4 * kc + g) ^ (li & 7)) * 8)];
#pragma unroll
            for (int nt = 0; nt < 2; ++nt) {
                int n = wn * 32 + nt * 16 + li;
                s16x8 bf = *(const s16x8*)&Bs[n * 64 + (((4 * kc + g) ^ (li & 7)) * 8)];
                acc[nt] = __builtin_amdgcn_mfma_f32_16x16x32_bf16(af, bf, acc[nt], 0, 0, 0);
            }
        }
    }
#pragma unroll
    for (int nt = 0; nt < 2; ++nt)
#pragma unroll
        for (int r = 0; r < 4; ++r) {
            int gm = m0 + wm * 16 + 4 * g + r;
            int gn = n0 + wn * 32 + nt * 16 + li;
            if (gn < N) C[(size_t)gm * N + gn] = acc[nt][r];
        }
}

// ---------------- merged up-projections: uq w/ in-register RoPE (bx<12) || ukv (bx>=12) --------
// uq epilogue: each thread holds the rope pair (fi, fi+16) in acc[0][r]/acc[1][r] because every
// rope section (cols h*96+64..h*96+95) occupies exactly one 32-col wn-half of a 64-col tile.
__global__ __launch_bounds__(512)
void k_upproj(const short* __restrict__ cqnb, const short* __restrict__ wuqT,
              short* __restrict__ qb,
              const short* __restrict__ ckvnb, const short* __restrict__ wukvT,
              short* __restrict__ kb, short* __restrict__ vbt) {
    __shared__ __align__(16) short As[64 * 64];
    __shared__ __align__(16) short Bs[64 * 64];
    int tid = threadIdx.x;
    int w = tid >> 6, l = tid & 63, g = l >> 4, li = l & 15;
    int wm = w >> 1, wn = w & 1;
    bool isQ = blockIdx.x < 12;
    const short* A  = isQ ? cqnb : ckvnb;
    const short* BT = isQ ? wuqT : wukvT;
    int N = isQ ? 768 : 1024;
    int K = isQ ? 256 : 128;
    int n0 = (isQ ? blockIdx.x : blockIdx.x - 12) * 64;
    int m0 = blockIdx.y * 64;
    f32x4 acc[2] = {};
    for (int k0 = 0; k0 < K; k0 += 64) {
        __syncthreads();
        {
            int row = tid >> 3, ch = tid & 7;
            *(int4*)&As[row * 64 + ((ch ^ (row & 7)) * 8)] =
                *(const int4*)(A + (size_t)(m0 + row) * K + k0 + 8 * ch);
            int4 v = {0, 0, 0, 0};
            if (n0 + row < N) v = *(const int4*)(BT + (size_t)(n0 + row) * K + k0 + 8 * ch);
            *(int4*)&Bs[row * 64 + ((ch ^ (row & 7)) * 8)] = v;
        }
        __syncthreads();
#pragma unroll
        for (int kc = 0; kc < 2; ++kc) {
            int row = wm * 16 + li;
            s16x8 af = *(const s16x8*)&As[row * 64 + (((4 * kc + g) ^ (li & 7)) * 8)];
#pragma unroll
            for (int nt = 0; nt < 2; ++nt) {
                int n = wn * 32 + nt * 16 + li;
                s16x8 bf = *(const s16x8*)&Bs[n * 64 + (((4 * kc + g) ^ (li & 7)) * 8)];
                acc[nt] = __builtin_amdgcn_mfma_f32_16x16x32_bf16(af, bf, acc[nt], 0, 0, 0);
            }
        }
    }
    const float scale = 0.14724389f;  // log2(e)/sqrt(96)
#pragma unroll
    for (int r = 0; r < 4; ++r) {
        int gm = m0 + wm * 16 + 4 * g + r;
        int b = gm >> 11, srow = gm & 2047;
        int c0 = n0 + wn * 32 + li;          // nt=0 column; nt=1 column = c0+16
        float v0 = acc[0][r], v1 = acc[1][r];
        if (isQ) {
            int h = c0 / 96, dd0 = c0 - h * 96;
            int bh = b * 8 + h;
            size_t qoff = ((size_t)(bh * 2048 + srow)) * 96;
            if (dd0 >= 64) {
                // rope pair: fi = dd0-64 in [0,16)
                int fi = dd0 - 64;
                float ang = (float)srow * __expf(-((float)(2 * fi) / 32.f) * 9.210340371976184f);
                float s, c; __sincosf(ang, &s, &c);
                qb[qoff + 64 + fi] = f2b((v0 * c - v1 * s) * scale);
                qb[qoff + 80 + fi] = f2b((v1 * c + v0 * s) * scale);
            } else {
                // both columns are copy columns of the same head (dd0, dd0+16 < 64)
                qb[qoff + dd0]      = f2b(v0 * scale);
                qb[qoff + dd0 + 16] = f2b(v1 * scale);
            }
        } else {
#pragma unroll
            for (int nt = 0; nt < 2; ++nt) {
                int gn = c0 + nt * 16;
                float v = nt ? v1 : v0;
                int h = gn >> 7, dd = gn & 127;
                int bh = b * 8 + h;
                if (dd < 64)
                    kb[((size_t)(bh * 2048 + srow)) * 96 + dd] = f2b(v);
                else
                    vbt[(size_t)bh * 64 * 2048 + (size_t)(dd - 64) * 2048 + srow] = f2b(v);
            }
        }
    }
}

// ---------------- wo projection fused with attention partial combine ----------------
__global__ __launch_bounds__(512)
void k_wo_gemm(const short* __restrict__ po, const float* __restrict__ pl,
               const short* __restrict__ BT, float* __restrict__ C,
               const float* __restrict__ add) {
    constexpr int N = 512, K = 512;
    __shared__ __align__(16) short As[64 * 64];
    __shared__ __align__(16) short Bs[64 * 64];
    int tid = threadIdx.x;
    int w = tid >> 6, l = tid & 63, g = l >> 4, li = l & 15;
    int wm = w >> 1, wn = w & 1;
    int m0 = blockIdx.y * 64, n0 = blockIdx.x * 64;
    int row = tid >> 3, ch = tid & 7;
    int t = m0 + row;
    int b = t >> 11, q = t & 2047;
    f32x4 acc[2] = {};
    for (int k0 = 0; k0 < K; k0 += 64) {
        int h = k0 >> 6;
        int bhq = (b * 8 + h) * 2048 + q;
        size_t pb = (size_t)bhq * 256 + 8 * ch;
        float4 l4 = *(const float4*)(pl + (size_t)bhq * 4);
        float inv = 1.f / (l4.x + l4.y + l4.z + l4.w);
        union { int4 v; short s[8]; } p0, p1, p2, p3, ov;
        p0.v = *(const int4*)(po + pb);
        p1.v = *(const int4*)(po + pb + 64);
        p2.v = *(const int4*)(po + pb + 128);
        p3.v = *(const int4*)(po + pb + 192);
#pragma unroll
        for (int i = 0; i < 8; ++i) {
            float os = b2f(p0.s[i]) + b2f(p1.s[i]) + b2f(p2.s[i]) + b2f(p3.s[i]);
            ov.s[i] = f2b(os * inv);
        }
        int4 bv = *(const int4*)(BT + (size_t)(n0 + row) * K + k0 + 8 * ch);
        __syncthreads();
        *(int4*)&As[row * 64 + ((ch ^ (row & 7)) * 8)] = ov.v;
        *(int4*)&Bs[row * 64 + ((ch ^ (row & 7)) * 8)] = bv;
        __syncthreads();
#pragma unroll
        for (int kc = 0; kc < 2; ++kc) {
            int rr = wm * 16 + li;
            s16x8 af = *(const s16x8*)&As[rr * 64 + (((4 * kc + g) ^ (li & 7)) * 8)];
#pragma unroll
            for (int nt = 0; nt < 2; ++nt) {
                int n = wn * 32 + nt * 16 + li;
                s16x8 bf = *(const s16x8*)&Bs[n * 64 + (((4 * kc + g) ^ (li & 7)) * 8)];
                acc[nt] = __builtin_amdgcn_mfma_f32_16x16x32_bf16(af, bf, acc[nt], 0, 0, 0);
            }
        }
    }
#pragma unroll
    for (int nt = 0; nt < 2; ++nt)
#pragma unroll
        for (int r = 0; r < 4; ++r) {
            int gm = m0 + wm * 16 + 4 * g + r;
            int gn = n0 + wn * 32 + nt * 16 + li;
            C[(size_t)gm * N + gn] = acc[nt][r] + add[(size_t)gm * N + gn];
        }
}

// ---------------- K-split(4) MFMA flash attention, 32 q/wave, MFMA denominator ----------------
__global__ __launch_bounds__(256)
void k_attn(const short* __restrict__ qb, const short* __restrict__ kb,
            const short* __restrict__ vbt, short* __restrict__ po, float* __restrict__ pl) {
    __shared__ __align__(16) short Ks[64 * 100];
    __shared__ __align__(16) short Vs[80 * 64];
    int tid = threadIdx.x;
    int w = tid >> 6, l = tid & 63, g = l >> 4, li = l & 15;
    int blk = blockIdx.x;
    int bh = blk >> 6, rem = blk & 63;
    int qt = rem >> 2, ks = rem & 3;
    int qc0 = qt * 128 + w * 32;

    {
        const short one = 0x3F80;  // bf16 1.0
        for (int i = tid; i < 16 * 64; i += 256)
            Vs[64 * 64 + i] = (i < 64) ? one : (short)0;
    }

    s16x8 qf[2][3];
#pragma unroll
    for (int j = 0; j < 2; ++j) {
        const short* qp = qb + (size_t)(bh * 2048 + qc0 + j * 16 + li) * 96;
#pragma unroll
        for (int c = 0; c < 3; ++c) qf[j][c] = *(const s16x8*)(qp + 32 * c + 8 * g);
    }

    f32x4 o[2][5] = {};
    const short* kbase = kb + (size_t)bh * 2048 * 96;
    const short* vbase = vbt + (size_t)bh * 64 * 2048;

    for (int t = 0; t < 8; ++t) {
        int koff = ks * 512 + t * 64;
        __syncthreads();
#pragma unroll
        for (int p = 0; p < 3; ++p) {
            int flat = p * 256 + tid;
            int key = flat / 12, u = flat % 12;
            *(int4*)&Ks[key * 100 + 8 * u] = *(const int4*)(kbase + (size_t)(koff + key) * 96 + 8 * u);
        }
#pragma unroll
        for (int p = 0; p < 2; ++p) {
            int flat = p * 256 + tid;
            int dim = flat >> 3, kc8 = flat & 7;
            int4 v = *(const int4*)(vbase + (size_t)dim * 2048 + koff + 8 * kc8);
            int sw = dim & 15;
            *(int2*)&Vs[dim * 64 + (((2 * kc8) ^ sw) * 4)]     = make_int2(v.x, v.y);
            *(int2*)&Vs[dim * 64 + (((2 * kc8 + 1) ^ sw) * 4)] = make_int2(v.z, v.w);
        }
        __syncthreads();

        f32x4 s[2][4];
#pragma unroll
        for (int kt = 0; kt < 4; ++kt) {
            f32x4 a0 = {}, a1 = {};
#pragma unroll
            for (int c = 0; c < 3; ++c) {
                s16x8 kf = *(const s16x8*)&Ks[(kt * 16 + li) * 100 + 32 * c + 8 * g];
                a0 = __builtin_amdgcn_mfma_f32_16x16x32_bf16(kf, qf[0][c], a0, 0, 0, 0);
                a1 = __builtin_amdgcn_mfma_f32_16x16x32_bf16(kf, qf[1][c], a1, 0, 0, 0);
            }
            s[0][kt] = a0; s[1][kt] = a1;
        }
#pragma unroll
        for (int j = 0; j < 2; ++j)
#pragma unroll
            for (int kt = 0; kt < 4; ++kt)
#pragma unroll
                for (int r = 0; r < 4; ++r) s[j][kt][r] = exp2f(s[j][kt][r]);
        s16x8 pf[2][2];
#pragma unroll
        for (int j = 0; j < 2; ++j)
#pragma unroll
            for (int kc = 0; kc < 2; ++kc) {
                s16x8 tt;
#pragma unroll
                for (int r = 0; r < 4; ++r) { tt[r] = f2b(s[j][2 * kc][r]); tt[4 + r] = f2b(s[j][2 * kc + 1][r]); }
                pf[j][kc] = tt;
            }
#pragma unroll
        for (int dt = 0; dt < 5; ++dt) {
            int dim = dt * 16 + li;
#pragma unroll
            for (int kc = 0; kc < 2; ++kc) {
                int2 a0 = *(const int2*)&Vs[dim * 64 + (((8 * kc + g) ^ li) * 4)];
                int2 a1 = *(const int2*)&Vs[dim * 64 + (((8 * kc + 4 + g) ^ li) * 4)];
                union { s16x8 v; int i[4]; } vf;
                vf.i[0] = a0.x; vf.i[1] = a0.y; vf.i[2] = a1.x; vf.i[3] = a1.y;
                o[0][dt] = __builtin_amdgcn_mfma_f32_16x16x32_bf16(vf.v, pf[0][kc], o[0][dt], 0, 0, 0);
                o[1][dt] = __builtin_amdgcn_mfma_f32_16x16x32_bf16(vf.v, pf[1][kc], o[1][dt], 0, 0, 0);
            }
        }
    }
#pragma unroll
    for (int j = 0; j < 2; ++j) {
        int qcol = qc0 + j * 16 + li;
        size_t qbase = ((size_t)(bh * 2048 + qcol) * 4 + ks) * 64;
#pragma unroll
        for (int dt = 0; dt < 4; ++dt) {
            union { short s[4]; int2 v; } pk;
#pragma unroll
            for (int r = 0; r < 4; ++r) pk.s[r] = f2b(o[j][dt][r]);
            *(int2*)(po + qbase + dt * 16 + 4 * g) = pk.v;
        }
        if (g == 0) pl[(size_t)(bh * 2048 + qcol) * 4 + ks] = o[j][4][0];
    }
}

// ---------------- merged: shared expert (blocks 0..255) || scatter (blocks 256..271) ------------
__global__ __launch_bounds__(512)
void k_shexp_scatter(const short* __restrict__ X, const short* __restrict__ WGt,
                     const short* __restrict__ WUt, short* __restrict__ gact,
                     const int4* __restrict__ toke, const float4* __restrict__ tokw,
                     float* __restrict__ ewt, int* __restrict__ ecnt, int* __restrict__ etok) {
    __shared__ __align__(16) short As[64 * 64];
    __shared__ __align__(16) short Bg[64 * 64];
    __shared__ __align__(16) short Bu[64 * 64];
    __shared__ int lcnt[16];
    __shared__ int lbase[16];
    int bid = blockIdx.x, tid = threadIdx.x;
    if (bid < 256) {
        int w = tid >> 6, l = tid & 63, g = l >> 4, li = l & 15;
        int wm = w >> 1, wn = w & 1;
        int m0 = (bid & 63) * 64, n0 = (bid >> 6) * 64;
        f32x4 ag[2] = {}, au[2] = {};
        for (int k0 = 0; k0 < 512; k0 += 64) {
            __syncthreads();
            {
                int row = tid >> 3, ch = tid & 7;
                *(int4*)&As[row * 64 + ((ch ^ (row & 7)) * 8)] =
                    *(const int4*)(X + (size_t)(m0 + row) * 512 + k0 + 8 * ch);
                *(int4*)&Bg[row * 64 + ((ch ^ (row & 7)) * 8)] =
                    *(const int4*)(WGt + (size_t)(n0 + row) * 512 + k0 + 8 * ch);
                *(int4*)&Bu[row * 64 + ((ch ^ (row & 7)) * 8)] =
                    *(const int4*)(WUt + (size_t)(n0 + row) * 512 + k0 + 8 * ch);
            }
            __syncthreads();
#pragma unroll
            for (int kc = 0; kc < 2; ++kc) {
                int row = wm * 16 + li;
                s16x8 af = *(const s16x8*)&As[row * 64 + (((4 * kc + g) ^ (li & 7)) * 8)];
#pragma unroll
                for (int nt = 0; nt < 2; ++nt) {
                    int n = wn * 32 + nt * 16 + li;
                    s16x8 bg = *(const s16x8*)&Bg[n * 64 + (((4 * kc + g) ^ (li & 7)) * 8)];
                    s16x8 bu = *(const s16x8*)&Bu[n * 64 + (((4 * kc + g) ^ (li & 7)) * 8)];
                    ag[nt] = __builtin_amdgcn_mfma_f32_16x16x32_bf16(af, bg, ag[nt], 0, 0, 0);
                    au[nt] = __builtin_amdgcn_mfma_f32_16x16x32_bf16(af, bu, au[nt], 0, 0, 0);
                }
            }
        }
#pragma unroll
        for (int nt = 0; nt < 2; ++nt)
#pragma unroll
            for (int r = 0; r < 4; ++r) {
                int gm = m0 + (tid >> 6 >> 1) * 16 + 4 * ((tid & 63) >> 4) + r;
                int gn = n0 + ((tid >> 6) & 1) * 32 + nt * 16 + (tid & 15);
                float gv = ag[nt][r], uv = au[nt][r];
                gact[(size_t)gm * 256 + gn] = f2b(gv / (1.f + __expf(-gv)) * uv);
            }
    } else {
        int sb = bid - 256;
        bool act = tid < 256;
        int t = sb * 256 + (tid & 255);
        if (tid < 16) lcnt[tid] = 0;
        __syncthreads();
        int es[4]; float wv[4]; int ls[4] = {0, 0, 0, 0};
        if (act) {
            int4 e4 = toke[t];
            float4 w4 = tokw[t];
            es[0] = e4.x; es[1] = e4.y; es[2] = e4.z; es[3] = e4.w;
            wv[0] = w4.x; wv[1] = w4.y; wv[2] = w4.z; wv[3] = w4.w;
#pragma unroll
            for (int kk = 0; kk < 4; ++kk) ls[kk] = atomicAdd(&lcnt[es[kk]], 1);
        }
        __syncthreads();
        if (tid < 16) lbase[tid] = atomicAdd(&ecnt[tid], lcnt[tid]);
        __syncthreads();
        if (act) {
#pragma unroll
            for (int kk = 0; kk < 4; ++kk) {
                int slot = lbase[es[kk]] + ls[kk];
                etok[es[kk] * 4096 + slot] = t * 4 + kk;
                ewt[es[kk] * 4096 + slot] = wv[kk];
            }
        }
    }
}

// ---------------- merged: shared-down GEMM (blocks 0..511) || MoE1 (blocks 512..1087) -----------
__global__ __launch_bounds__(512)
void k_shd_moe1(const short* __restrict__ gact, const short* __restrict__ shwdT,
                float* __restrict__ outF, const float* __restrict__ r2,
                const short* __restrict__ X, const short* __restrict__ WGt,
                const short* __restrict__ WUt,
                const int* __restrict__ ecnt, const int* __restrict__ etok,
                short* __restrict__ eact) {
    __shared__ __align__(16) short smem[16384];   // 32 KB carve
    __shared__ int toks[128];
    __shared__ int ecs[16];
    int bid = blockIdx.x, tid = threadIdx.x;
    int w = tid >> 6, l = tid & 63, g = l >> 4, li = l & 15;
    int wm = w >> 1, wn = w & 1;
    if (bid < 512) {
        short* As = smem;
        short* Bs = smem + 4096;
        constexpr int N = 512, K = 256;
        int n0 = (bid & 7) * 64, m0 = (bid >> 3) * 64;
        f32x4 acc[2] = {};
        for (int k0 = 0; k0 < K; k0 += 64) {
            __syncthreads();
            {
                int row = tid >> 3, ch = tid & 7;
                *(int4*)&As[row * 64 + ((ch ^ (row & 7)) * 8)] =
                    *(const int4*)(gact + (size_t)(m0 + row) * K + k0 + 8 * ch);
                *(int4*)&Bs[row * 64 + ((ch ^ (row & 7)) * 8)] =
                    *(const int4*)(shwdT + (size_t)(n0 + row) * K + k0 + 8 * ch);
            }
            __syncthreads();
#pragma unroll
            for (int kc = 0; kc < 2; ++kc) {
                int row = wm * 16 + li;
                s16x8 af = *(const s16x8*)&As[row * 64 + (((4 * kc + g) ^ (li & 7)) * 8)];
#pragma unroll
                for (int nt = 0; nt < 2; ++nt) {
                    int n = wn * 32 + nt * 16 + li;
                    s16x8 bf = *(const s16x8*)&Bs[n * 64 + (((4 * kc + g) ^ (li & 7)) * 8)];
                    acc[nt] = __builtin_amdgcn_mfma_f32_16x16x32_bf16(af, bf, acc[nt], 0, 0, 0);
                }
            }
        }
#pragma unroll
        for (int nt = 0; nt < 2; ++nt)
#pragma unroll
            for (int r = 0; r < 4; ++r) {
                int gm = m0 + wm * 16 + 4 * g + r;
                int gn = n0 + wn * 32 + nt * 16 + li;
                outF[(size_t)gm * N + gn] = acc[nt][r] + r2[(size_t)gm * N + gn];
            }
    } else {
        short* As = smem;
        short* Bg = smem + 8192;
        short* Bu = smem + 12288;
        if (tid < 16) ecs[tid] = ecnt[tid];
        __syncthreads();
        int lin = bid - 512;
        int virt = (lin & 7) * 72 + (lin >> 3);
        int tb = virt >> 2;
        int n0 = (virt & 3) * 64;
        int e = 0;
        for (; e < 16; ++e) { int n = (ecs[e] + 127) >> 7; if (tb < n) break; tb -= n; }
        if (e >= 16) return;
        int base = tb << 7;
        int rows = min(128, ecs[e] - base);
        if (tid < 128) toks[tid] = (tid < rows) ? etok[e * 4096 + base + tid] : -1;
        __syncthreads();
        const short* wgp = WGt + (size_t)e * 256 * 512;
        const short* wup = WUt + (size_t)e * 256 * 512;
        f32x4 ag[2][2] = {}, au[2][2] = {};
        for (int k0 = 0; k0 < 512; k0 += 64) {
            __syncthreads();
#pragma unroll
            for (int p = 0; p < 2; ++p) {
                int flat = p * 512 + tid;
                int row = flat >> 3, ch = flat & 7;
                int tk = toks[row];
                int4 v = {0, 0, 0, 0};
                if (tk >= 0) v = *(const int4*)(X + (size_t)(tk >> 2) * 512 + k0 + 8 * ch);
                *(int4*)&As[row * 64 + ((ch ^ (row & 7)) * 8)] = v;
            }
            {
                int n = tid >> 3, ch = tid & 7;
                *(int4*)&Bg[n * 64 + ((ch ^ (n & 7)) * 8)] = *(const int4*)(wgp + (size_t)(n0 + n) * 512 + k0 + 8 * ch);
                *(int4*)&Bu[n * 64 + ((ch ^ (n & 7)) * 8)] = *(const int4*)(wup + (size_t)(n0 + n) * 512 + k0 + 8 * ch);
            }
            __syncthreads();
#pragma unroll
            for (int kc = 0; kc < 2; ++kc) {
                s16x8 af[2], bg[2], bu[2];
#pragma unroll
                for (int mt = 0; mt < 2; ++mt) {
                    int row = wm * 32 + mt * 16 + li;
                    af[mt] = *(const s16x8*)&As[row * 64 + (((4 * kc + g) ^ (li & 7)) * 8)];
                }
#pragma unroll
                for (int nt = 0; nt < 2; ++nt) {
                    int n = wn * 32 + nt * 16 + li;
                    bg[nt] = *(const s16x8*)&Bg[n * 64 + (((4 * kc + g) ^ (li & 7)) * 8)];
                    bu[nt] = *(const s16x8*)&Bu[n * 64 + (((4 * kc + g) ^ (li & 7)) * 8)];
                }
#pragma unroll
                for (int mt = 0; mt < 2; ++mt)
#pragma unroll
                    for (int nt = 0; nt < 2; ++nt) {
                        ag[mt][nt] = __builtin_amdgcn_mfma_f32_16x16x32_bf16(af[mt], bg[nt], ag[mt][nt], 0, 0, 0);
                        au[mt][nt] = __builtin_amdgcn_mfma_f32_16x16x32_bf16(af[mt], bu[nt], au[mt][nt], 0, 0, 0);
                    }
            }
        }
#pragma unroll
        for (int mt = 0; mt < 2; ++mt)
#pragma unroll
            for (int nt = 0; nt < 2; ++nt)
#pragma unroll
                for (int r = 0; r < 4; ++r) {
                    int local = wm * 32 + mt * 16 + 4 * g + r;
                    if (local < rows) {
                        int entry = toks[local];
                        int gn = n0 + wn * 32 + nt * 16 + li;
                        float gv = ag[mt][nt][r], uv = au[mt][nt][r];
                        eact[(size_t)entry * 256 + gn] = f2b(gv / (1.f + __expf(-gv)) * uv);
                    }
                }
    }
}

// ---------------- MoE stage 2 (MFMA, 8 waves, inline tile-scan, XCD swizzle) --------------------
__global__ __launch_bounds__(512)
void k_moe2m(const short* __restrict__ EA, const short* __restrict__ WDt,
             const int* __restrict__ ecnt, const int* __restrict__ etok,
             const float* __restrict__ ewt, float* __restrict__ oacc) {
    __shared__ int ecs[16];
    __shared__ __align__(16) short As[128 * 64];
    __shared__ __align__(16) short Bs[64 * 64];
    __shared__ int toks[128];
    __shared__ float wts[128];
    int tid = threadIdx.x;
    if (tid < 16) ecs[tid] = ecnt[tid];
    __syncthreads();
    int lin = blockIdx.x + 144 * blockIdx.y;
    int virt = (lin & 7) * 144 + (lin >> 3);
    int bid = virt >> 3;
    int n0 = (virt & 7) * 64;
    int e = 0;
    for (; e < 16; ++e) { int n = (ecs[e] + 127) >> 7; if (bid < n) break; bid -= n; }
    if (e >= 16) return;
    int base = bid << 7;
    int rows = min(128, ecs[e] - base);
    if (tid < 128) {
        toks[tid] = (tid < rows) ? etok[e * 4096 + base + tid] : -1;
        wts[tid]  = (tid < rows) ? ewt[e * 4096 + base + tid] : 0.f;
    }
    __syncthreads();
    int w = tid >> 6, l = tid & 63, g = l >> 4, li = l & 15;
    int wm = w >> 1, wn = w & 1;
    const short* wdp = WDt + (size_t)e * 512 * 256;
    f32x4 acc[2][2] = {};
    for (int k0 = 0; k0 < 256; k0 += 64) {
        __syncthreads();
#pragma unroll
        for (int p = 0; p < 2; ++p) {
            int flat = p * 512 + tid;
            int row = flat >> 3, ch = flat & 7;
            int tk = toks[row];
            int4 v = {0, 0, 0, 0};
            if (tk >= 0) v = *(const int4*)(EA + (size_t)tk * 256 + k0 + 8 * ch);
            *(int4*)&As[row * 64 + ((ch ^ (row & 7)) * 8)] = v;
        }
        {
            int n = tid >> 3, ch = tid & 7;
            *(int4*)&Bs[n * 64 + ((ch ^ (n & 7)) * 8)] = *(const int4*)(wdp + (size_t)(n0 + n) * 256 + k0 + 8 * ch);
        }
        __syncthreads();
#pragma unroll
        for (int kc = 0; kc < 2; ++kc) {
            s16x8 af[2], bf[2];
#pragma unroll
            for (int mt = 0; mt < 2; ++mt) {
                int row = wm * 32 + mt * 16 + li;
                af[mt] = *(const s16x8*)&As[row * 64 + (((4 * kc + g) ^ (li & 7)) * 8)];
            }
#pragma unroll
            for (int nt = 0; nt < 2; ++nt) {
                int n = wn * 32 + nt * 16 + li;
                bf[nt] = *(const s16x8*)&Bs[n * 64 + (((4 * kc + g) ^ (li & 7)) * 8)];
            }
#pragma unroll
            for (int mt = 0; mt < 2; ++mt)
#pragma unroll
                for (int nt = 0; nt < 2; ++nt)
                    acc[mt][nt] = __builtin_amdgcn_mfma_f32_16x16x32_bf16(af[mt], bf[nt], acc[mt][nt], 0, 0, 0);
        }
    }
#pragma unroll
    for (int mt = 0; mt < 2; ++mt)
#pragma unroll
        for (int nt = 0; nt < 2; ++nt)
#pragma unroll
            for (int r = 0; r < 4; ++r) {
                int local = wm * 32 + mt * 16 + 4 * g + r;
                if (local < rows) {
                    int tok = toks[local] >> 2;
                    int gn = n0 + wn * 32 + nt * 16 + li;
                    atomicAdd(&oacc[(size_t)tok * 512 + gn], acc[mt][nt][r] * wts[local]);
                }
            }
}

// ---------------- host launcher ----------------
extern "C" void kernel_launch(void* const* d_in, const int* in_sizes, int n_in,
                              void* d_out, int out_size, void* d_ws, size_t ws_size,
                              hipStream_t stream) {
    const float* hs       = (const float*)d_in[0];
    const float* w_innorm = (const float*)d_in[1];
    const float* w_dq     = (const float*)d_in[2];
    const float* w_qnorm  = (const float*)d_in[3];
    const float* w_uq     = (const float*)d_in[4];
    const float* w_dkv    = (const float*)d_in[5];
    const float* w_kvnorm = (const float*)d_in[6];
    const float* w_ukv    = (const float*)d_in[7];
    const float* w_o      = (const float*)d_in[8];
    const float* w_post   = (const float*)d_in[9];
    const float* w_gate   = (const float*)d_in[10];
    const float* sh_wg    = (const float*)d_in[11];
    const float* sh_wu    = (const float*)d_in[12];
    const float* sh_wd    = (const float*)d_in[13];
    const float* r_wg     = (const float*)d_in[14];
    const float* r_wu     = (const float*)d_in[15];
    const float* r_wd     = (const float*)d_in[16];

    float* ws   = (float*)d_ws;
    float* cqkv = ws + OFF_CQKV;
    float* r2   = ws + OFF_R2;
    short* po   = (short*)(ws + OFF_PO);
    float* pl   = ws + OFF_PL;
    int4*  toke = (int4*)(ws + OFF_TOKE);
    float4* tokw = (float4*)(ws + OFF_TOKW);
    float* ewt  = ws + OFF_EWT;
    int*   ecnt = (int*)(ws + OFF_ECNT);
    int*   etok = (int*)(ws + OFF_ETOK);
    short* xnb   = (short*)(ws + OFF_XNB);
    short* cqnb  = (short*)(ws + OFF_CQNB);
    short* ckvnb = (short*)(ws + OFF_CKVNB);
    short* qb    = (short*)(ws + OFF_QB);
    short* kb    = (short*)(ws + OFF_KB);
    short* vbt   = (short*)(ws + OFF_VBT);
    short* xn2b  = (short*)(ws + OFF_XN2B);
    short* gact  = (short*)(ws + OFF_GACT);
    short* eact  = (short*)(ws + OFF_EACT);
    short* wqkvT = (short*)(ws + OFF_WQKVT);
    short* wuqT  = (short*)(ws + OFF_WUQT);
    short* wukvT = (short*)(ws + OFF_WUKVT);
    short* woT   = (short*)(ws + OFF_WOT);
    short* shwgT = (short*)(ws + OFF_SHWGT);
    short* shwuT = (short*)(ws + OFF_SHWUT);
    short* shwdT = (short*)(ws + OFF_SHWDT);
    short* rwgT  = (short*)(ws + OFF_RWGT);
    short* rwuT  = (short*)(ws + OFF_RWUT);
    short* rwdT  = (short*)(ws + OFF_RWDT);

    float* outF = (float*)d_out;

    // 0+1. merged: weight convert+transpose || input RMSNorm (zeroes ecnt)
    CvtTab tab;
    const float* srcs[11] = { w_dq, w_dkv, w_uq, w_ukv, w_o, sh_wg, sh_wu, sh_wd, r_wg, r_wu, r_wd };
    short* dsts[11] = { wqkvT, wqkvT + (size_t)256 * 512, wuqT, wukvT, woT, shwgT, shwuT, shwdT, rwgT, rwuT, rwdT };
    int Ks_[11] = { 512, 512, 256, 128, 512, 512, 512, 256, 512, 512, 256 };
    int Ns_[11] = { 256, 160, 768, 1024, 512, 256, 256, 512, 256, 256, 512 };
    int Es_[11] = { 1, 1, 1, 1, 1, 1, 1, 1, 16, 16, 16 };
    int cum = 0;
    for (int i = 0; i < 11; ++i) {
        tab.src[i] = srcs[i]; tab.dst[i] = dsts[i];
        tab.K[i] = Ks_[i]; tab.N[i] = Ns_[i];
        cum += Es_[i] * (Ks_[i] >> 5) * (Ns_[i] >> 5);
        tab.end[i] = cum;
    }
    k_cvt_rms<<<CVT_BLOCKS + Tt, 256, 0, stream>>>(tab, hs, w_innorm, xnb, ecnt);

    // 2. fused down-projection (dq|dkv), N=416, f32 out
    k_mgemm0<<<dim3(7, 64), 512, 0, stream>>>(xnb, wqkvT, cqkv, 416, 512);
    // 3. merged: fused latent norms || k-rope build (from cqkv)
    k_rms2<<<2 * Tt + 4096, 256, 0, stream>>>(cqkv, w_qnorm, cqnb, w_kvnorm, ckvnb, kb);
    // 4. merged up-projections (uq with in-register RoPE -> qb || ukv scatter -> kb,vbt)
    k_upproj<<<dim3(28, 64), 512, 0, stream>>>(cqnb, wuqT, qb, ckvnb, wukvT, kb, vbt);
    // 5. K-split(4) MFMA flash attention
    k_attn<<<1024, 256, 0, stream>>>(qb, kb, vbt, po, pl);
    // 6. wo projection fused with partial combine + residual
    k_wo_gemm<<<dim3(8, 64), 512, 0, stream>>>(po, pl, woT, r2, hs);
    // 7. fused post-norm + router
    k_rms_router<<<Tt, 256, 0, stream>>>(r2, w_post, w_gate, xn2b, toke, tokw);
    // 8. merged: shared-expert up || scatter
    k_shexp_scatter<<<272, 512, 0, stream>>>(xn2b, shwgT, shwuT, gact, toke, tokw, ewt, ecnt, etok);
    // 9. merged: shared-expert down (into d_out) || MoE1
    k_shd_moe1<<<1088, 512, 0, stream>>>(gact, shwdT, outF, r2, xn2b, rwgT, rwuT, ecnt, etok, eact);
    // 10. MoE2 (atomic accumulate into d_out)
    k_moe2m<<<dim3(144, 8), 512, 0, stream>>>(eact, rwdT, ecnt, etok, ewt, outF);
}